// Round 2
// baseline (6745.967 us; speedup 1.0000x reference)
//
#include <hip/hip_runtime.h>
#include <cmath>

#define NN 50000
#define EE 500000
#define GG 256
#define FA 92
#define FB 41
#define DD 64
#define HH 128
#define CQdim 16
#define NL 3
#define EPSBN 1e-5f

// ---------- helpers ----------
__device__ __forceinline__ float sp1(float x) {
    return fmaxf(x, 0.0f) + log1pf(expf(-fabsf(x)));
}
__device__ __forceinline__ float4 sp4(float4 v) {
    return make_float4(sp1(v.x), sp1(v.y), sp1(v.z), sp1(v.w));
}
__device__ __forceinline__ void atomAddF(float* p, float v) {
    unsafeAtomicAdd(p, v);   // hw global_atomic_add_f32
}

// acc[i][c] += sum_k U[(r0+i)*LD + k] * W[k*64 + c0+c]
template<int K, int LD>
__device__ __forceinline__ void mm_tile(float4 acc[4], const float* __restrict__ Ubuf, int r0,
                                        const float* __restrict__ W, int c0)
{
#pragma unroll
    for (int k0 = 0; k0 < K; k0 += 4) {
        float4 w0 = *(const float4*)&W[(k0+0)*64 + c0];
        float4 w1 = *(const float4*)&W[(k0+1)*64 + c0];
        float4 w2 = *(const float4*)&W[(k0+2)*64 + c0];
        float4 w3 = *(const float4*)&W[(k0+3)*64 + c0];
#pragma unroll
        for (int i = 0; i < 4; ++i) {
            float4 u = *(const float4*)&Ubuf[(r0+i)*LD + k0];
            acc[i].x += u.x*w0.x + u.y*w1.x + u.z*w2.x + u.w*w3.x;
            acc[i].y += u.x*w0.y + u.y*w1.y + u.z*w2.y + u.w*w3.y;
            acc[i].z += u.x*w0.z + u.y*w1.z + u.z*w2.z + u.w*w3.z;
            acc[i].w += u.x*w0.w + u.y*w1.w + u.z*w2.w + u.w*w3.w;
        }
    }
}

// ---------- counting sort of edges by col ----------
__global__ __launch_bounds__(256) void hist_kernel(const int* __restrict__ coli, int* __restrict__ cnt)
{
    int e = blockIdx.x*256 + threadIdx.x;
    if (e < EE) atomicAdd(&cnt[coli[e]], 1);
}

__global__ __launch_bounds__(1024) void scan_kernel(const int* __restrict__ cnt, int* __restrict__ off)
{
    __shared__ int buf[1024];
    __shared__ int carry;
    if (threadIdx.x == 0) carry = 0;
    __syncthreads();
    for (int base = 0; base < NN; base += 1024) {
        int i = base + threadIdx.x;
        int v = (i < NN) ? cnt[i] : 0;
        buf[threadIdx.x] = v;
        __syncthreads();
#pragma unroll
        for (int ofs = 1; ofs < 1024; ofs <<= 1) {
            int t = 0;
            if (threadIdx.x >= ofs) t = buf[threadIdx.x - ofs];
            __syncthreads();
            if (threadIdx.x >= ofs) buf[threadIdx.x] += t;
            __syncthreads();
        }
        if (i < NN) off[i] = carry + buf[threadIdx.x] - v;   // exclusive
        __syncthreads();
        if (threadIdx.x == 0) carry += buf[1023];
        __syncthreads();
    }
}

__global__ __launch_bounds__(256) void scatter_kernel(
    const int* __restrict__ rowi, const int* __restrict__ coli, int* __restrict__ off,
    int* __restrict__ perm, int* __restrict__ rowp, int* __restrict__ colp)
{
    int e = blockIdx.x*256 + threadIdx.x;
    if (e >= EE) return;
    int c = coli[e];
    int p = atomicAdd(&off[c], 1);
    perm[p] = e; rowp[p] = rowi[e]; colp[p] = c;
}

// ---------- node embedding ----------
__global__ __launch_bounds__(256) void embed_node_kernel(
    const float* __restrict__ x, const int* __restrict__ batch,
    const float* __restrict__ charge, const float* __restrict__ Wc,
    const float* __restrict__ bc, const float* __restrict__ Wa,
    const float* __restrict__ ba, float* __restrict__ h)
{
    const int K = FA + CQdim; // 108
    __shared__ float sW[108*64];
    __shared__ float sX[64*108];
    for (int i = threadIdx.x; i < K*64; i += 256) sW[i] = Wa[i];
    const int fg = threadIdx.x & 15, ng = threadIdx.x >> 4, c0 = fg*4;
    for (int tb = blockIdx.x*64; tb < NN; tb += gridDim.x*64) {
        __syncthreads();
        for (int i = threadIdx.x; i < 64*K; i += 256) {
            int n = i / K, c = i % K;
            int node = tb + n;
            float v = 0.f;
            if (node < NN) {
                if (c < FA) v = x[(size_t)node*FA + c];
                else { int q = c - FA; int g = batch[node]; v = charge[g]*Wc[q] + bc[q]; }
            }
            sX[n*K + c] = v;
        }
        __syncthreads();
        float4 acc[4];
        float4 bb = *(const float4*)&ba[c0];
#pragma unroll
        for (int i = 0; i < 4; ++i) acc[i] = bb;
        mm_tile<108,108>(acc, sX, ng*4, sW, c0);
#pragma unroll
        for (int i = 0; i < 4; ++i) {
            int node = tb + ng*4 + i;
            if (node < NN) *(float4*)&h[(size_t)node*64 + c0] = acc[i];
        }
    }
}

// ---------- edge embedding (PERMUTED output: ea[p] = embed(edge_attr[perm[p]])) ----------
__global__ __launch_bounds__(256) void embed_edge_kernel(
    const float* __restrict__ eattr, const int* __restrict__ perm,
    const float* __restrict__ Wb, const float* __restrict__ bbond, float* __restrict__ ea)
{
    const int K = 44; // 41 padded to 44
    __shared__ float sW[44*64];
    __shared__ float sX[64*44];
    for (int i = threadIdx.x; i < K*64; i += 256) {
        int r = i >> 6, c = i & 63;
        sW[i] = (r < FB) ? Wb[r*64 + c] : 0.f;
    }
    const int fg = threadIdx.x & 15, ng = threadIdx.x >> 4, c0 = fg*4;
    for (int tb = blockIdx.x*64; tb < EE; tb += gridDim.x*64) {
        __syncthreads();
        for (int i = threadIdx.x; i < 64*K; i += 256) {
            int n = i / K, c = i % K;
            int p = tb + n;
            float v = 0.f;
            if (p < EE && c < FB) {
                int e = perm[p];
                v = eattr[(size_t)e*FB + c];
            }
            sX[n*K + c] = v;
        }
        __syncthreads();
        float4 acc[4];
        float4 bv = *(const float4*)&bbond[c0];
#pragma unroll
        for (int i = 0; i < 4; ++i) acc[i] = bv;
        mm_tile<44,44>(acc, sX, ng*4, sW, c0);
#pragma unroll
        for (int i = 0; i < 4; ++i) {
            int p = tb + ng*4 + i;
            if (p < EE) *(float4*)&ea[(size_t)p*64 + c0] = acc[i];
        }
    }
}

// ---------- per-layer node precompute ----------
__global__ __launch_bounds__(256) void precompute_kernel(
    const float* __restrict__ h,
    const float* __restrict__ W1, const float* __restrict__ W2, const float* __restrict__ W3,
    const float* __restrict__ b1, const float* __restrict__ b3,
    float* __restrict__ P1, float* __restrict__ P2, float* __restrict__ P3)
{
    __shared__ float sW1[4096], sW2[4096], sW3[4096];
    __shared__ float sH[64*68];
    for (int i = threadIdx.x; i < 4096; i += 256) { sW1[i]=W1[i]; sW2[i]=W2[i]; sW3[i]=W3[i]; }
    const int fg = threadIdx.x & 15, ng = threadIdx.x >> 4, c0 = fg*4;
    for (int tb = blockIdx.x*64; tb < NN; tb += gridDim.x*64) {
        __syncthreads();
        for (int i = threadIdx.x; i < 4096; i += 256) {
            int n = i >> 6, c = i & 63;
            int node = tb + n;
            sH[n*68 + c] = (node < NN) ? h[(size_t)node*64 + c] : 0.f;
        }
        __syncthreads();
        float4 a1[4], a2[4], a3[4];
        float4 v1 = *(const float4*)&b1[c0];
        float4 v3 = *(const float4*)&b3[c0];
#pragma unroll
        for (int i = 0; i < 4; ++i) { a1[i]=v1; a2[i]=make_float4(0,0,0,0); a3[i]=v3; }
        mm_tile<64,68>(a1, sH, ng*4, sW1, c0);
        mm_tile<64,68>(a2, sH, ng*4, sW2, c0);
        mm_tile<64,68>(a3, sH, ng*4, sW3, c0);
#pragma unroll
        for (int i = 0; i < 4; ++i) {
            int node = tb + ng*4 + i;
            if (node < NN) {
                *(float4*)&P1[(size_t)node*64+c0] = a1[i];
                *(float4*)&P2[(size_t)node*64+c0] = a2[i];
                *(float4*)&P3[(size_t)node*64+c0] = a3[i];
            }
        }
    }
}

// ---------- fused per-edge kernel over col-sorted edges ----------
__global__ __launch_bounds__(512, 2) void layer_edge_kernel(
    float* __restrict__ ea,
    const float* __restrict__ P1, const float* __restrict__ P2, const float* __restrict__ P3,
    float* __restrict__ h_new,
    const int* __restrict__ rowp, const int* __restrict__ colp,
    const float* __restrict__ WA, const float* __restrict__ WB,
    const float* __restrict__ WC, const float* __restrict__ WD,
    const float* __restrict__ eb2, const float* __restrict__ nb2)
{
    __shared__ float sWA[4096], sWB[4096], sWC[4096], sWD[4096];
    __shared__ float sU[8][16*68];
    __shared__ float sT[8][16*68];
    for (int i = threadIdx.x; i < 4096; i += 512) {
        sWA[i]=WA[i]; sWB[i]=WB[i]; sWC[i]=WC[i]; sWD[i]=WD[i];
    }
    __syncthreads();
    const int wave = threadIdx.x >> 6;
    const int lane = threadIdx.x & 63;
    const int fg = lane & 15, eg = lane >> 4, c0 = fg*4;
    float* U = sU[wave];
    float* T = sT[wave];
    const int numTiles = EE >> 4;
    for (int tile = blockIdx.x*8 + wave; tile < numTiles; tile += gridDim.x*8) {
        const int base = tile << 4;
        int rid[4], cid[4];
#pragma unroll
        for (int i = 0; i < 4; ++i) {
            int e = base + eg*4 + i;
            rid[i] = rowp[e]; cid[i] = colp[e];
        }
        float4 g1[4], g2[4], g3[4];
#pragma unroll
        for (int i = 0; i < 4; ++i) {
            g1[i] = *(const float4*)&P1[(size_t)rid[i]*64 + c0];
            g2[i] = *(const float4*)&P2[(size_t)cid[i]*64 + c0];
            g3[i] = *(const float4*)&P3[(size_t)rid[i]*64 + c0];
        }
#pragma unroll
        for (int j = 0; j < 4; ++j) {
            int i = lane + 64*j;
            int r = i >> 4, cc = (i & 15) << 2;
            float4 v = *(const float4*)&ea[(size_t)(base+r)*64 + cc];
            *(float4*)&U[r*68 + cc] = v;
        }
        __builtin_amdgcn_wave_barrier();
        // phase 1: t1 = sp(P1[row]+P2[col]+ea@WA)
        float4 acc[4];
#pragma unroll
        for (int i = 0; i < 4; ++i)
            acc[i] = make_float4(g1[i].x+g2[i].x, g1[i].y+g2[i].y, g1[i].z+g2[i].z, g1[i].w+g2[i].w);
        mm_tile<64,68>(acc, U, eg*4, sWA, c0);
#pragma unroll
        for (int i = 0; i < 4; ++i) *(float4*)&T[(eg*4+i)*68 + c0] = sp4(acc[i]);
        __builtin_amdgcn_wave_barrier();
        // phase 2: ea' = t1@WB + eb2
        float4 bv = *(const float4*)&eb2[c0];
#pragma unroll
        for (int i = 0; i < 4; ++i) acc[i] = bv;
        mm_tile<64,68>(acc, T, eg*4, sWB, c0);
#pragma unroll
        for (int i = 0; i < 4; ++i) {
            int er = eg*4 + i;
            *(float4*)&ea[(size_t)(base+er)*64 + c0] = acc[i];
            *(float4*)&U[er*68 + c0] = acc[i];
        }
        __builtin_amdgcn_wave_barrier();
        // phase 3: t2 = sp(P3[row] + ea'@WC)
#pragma unroll
        for (int i = 0; i < 4; ++i) acc[i] = g3[i];
        mm_tile<64,68>(acc, U, eg*4, sWC, c0);
#pragma unroll
        for (int i = 0; i < 4; ++i) *(float4*)&T[(eg*4+i)*68 + c0] = sp4(acc[i]);
        __builtin_amdgcn_wave_barrier();
        // phase 4: msg = t2@WD + nb2, scatter with run-merge (cols sorted)
        float4 nv = *(const float4*)&nb2[c0];
#pragma unroll
        for (int i = 0; i < 4; ++i) acc[i] = nv;
        mm_tile<64,68>(acc, T, eg*4, sWD, c0);
        {
            float4 s = acc[0]; int cur = cid[0];
#pragma unroll
            for (int i = 1; i < 4; ++i) {
                if (cid[i] == cur) {
                    s.x += acc[i].x; s.y += acc[i].y; s.z += acc[i].z; s.w += acc[i].w;
                } else {
                    float* dst = &h_new[(size_t)cur*64 + c0];
                    atomAddF(dst+0, s.x); atomAddF(dst+1, s.y);
                    atomAddF(dst+2, s.z); atomAddF(dst+3, s.w);
                    cur = cid[i]; s = acc[i];
                }
            }
            float* dst = &h_new[(size_t)cur*64 + c0];
            atomAddF(dst+0, s.x); atomAddF(dst+1, s.y);
            atomAddF(dst+2, s.z); atomAddF(dst+3, s.w);
        }
        __builtin_amdgcn_wave_barrier();
    }
}

// ---------- batchnorm statistics ----------
__global__ __launch_bounds__(256) void bn_stat_kernel(const float* __restrict__ hn, float* __restrict__ stats)
{
    const int col = threadIdx.x & 63, rg = threadIdx.x >> 6;
    float s = 0.f, ss = 0.f;
    for (int n = blockIdx.x*4 + rg; n < NN; n += gridDim.x*4) {
        float v = hn[(size_t)n*64 + col];
        s += v; ss += v*v;
    }
    __shared__ float Ss[4][64], Sq[4][64];
    Ss[rg][col] = s; Sq[rg][col] = ss;
    __syncthreads();
    if (threadIdx.x < 64) {
        float a = Ss[0][col]+Ss[1][col]+Ss[2][col]+Ss[3][col];
        float b = Sq[0][col]+Sq[1][col]+Sq[2][col]+Sq[3][col];
        atomAddF(&stats[col], a);
        atomAddF(&stats[64+col], b);
    }
}

// ---------- bn apply + softplus + residual ----------
__global__ __launch_bounds__(256) void bn_apply_kernel(
    const float* __restrict__ hn, float* __restrict__ h,
    const float* __restrict__ stats, const float* __restrict__ gamma, const float* __restrict__ beta)
{
    size_t idx = (size_t)blockIdx.x*256 + threadIdx.x;
    if (idx >= (size_t)NN*16) return;
    int c0 = (int)(idx & 15) << 2;
    float4 v = ((const float4*)hn)[idx];
    float4 r = ((const float4*)h)[idx];
    float vv[4] = {v.x, v.y, v.z, v.w};
    float rr[4] = {r.x, r.y, r.z, r.w};
    float oo[4];
    const float invN = 1.0f / (float)NN;
#pragma unroll
    for (int c = 0; c < 4; ++c) {
        int col = c0 + c;
        float mu  = stats[col] * invN;
        float var = stats[64+col] * invN - mu*mu;
        float is  = rsqrtf(var + EPSBN);
        float nv  = (vv[c] - mu) * is * gamma[col] + beta[col];
        oo[c] = sp1(nv) + rr[c];
    }
    ((float4*)h)[idx] = make_float4(oo[0], oo[1], oo[2], oo[3]);
}

// ---------- global mean pool: batch is sorted -> run-accumulate ----------
__global__ __launch_bounds__(256) void pool_kernel(
    const float* __restrict__ h, const int* __restrict__ batch,
    float* __restrict__ gsum, float* __restrict__ gcnt)
{
    const int col = threadIdx.x & 63, rg = threadIdx.x >> 6;
    int n0 = blockIdx.x*1024 + rg*256;
    if (n0 >= NN) return;
    int n1 = n0 + 256; if (n1 > NN) n1 = NN;
    float s = 0.f;
    int cur = batch[n0];
    int cnt = 0;
    for (int n = n0; n < n1; ++n) {
        int g = batch[n];
        if (g != cur) {
            atomAddF(&gsum[cur*64 + col], s);
            if (col == 0) atomAddF(&gcnt[cur], (float)cnt);
            s = 0.f; cnt = 0; cur = g;
        }
        s += h[(size_t)n*64 + col];
        ++cnt;
    }
    atomAddF(&gsum[cur*64 + col], s);
    if (col == 0) atomAddF(&gcnt[cur], (float)cnt);
}

// ---------- predictor MLP ----------
__global__ __launch_bounds__(128) void predictor_kernel(
    const float* __restrict__ gsum, const float* __restrict__ gcnt,
    const float* __restrict__ W1, const float* __restrict__ b1,
    const float* __restrict__ W2, const float* __restrict__ b2,
    const float* __restrict__ W3, const float* __restrict__ b3,
    float* __restrict__ out)
{
    int g = blockIdx.x, t = threadIdx.x;
    __shared__ float gr[64];
    __shared__ float z1[128];
    __shared__ float z2[128];
    __shared__ float red[128];
    if (t < 64) gr[t] = gsum[g*64 + t] / fmaxf(gcnt[g], 1.0f);
    __syncthreads();
    float s = b1[t];
    for (int k = 0; k < 64; ++k) s += gr[k] * W1[k*128 + t];
    z1[t] = sp1(s);
    __syncthreads();
    s = b2[t];
    for (int k = 0; k < 128; ++k) s += z1[k] * W2[k*128 + t];
    z2[t] = sp1(s);
    __syncthreads();
    red[t] = z2[t] * W3[t];
    __syncthreads();
    for (int off = 64; off > 0; off >>= 1) {
        if (t < off) red[t] += red[t + off];
        __syncthreads();
    }
    if (t == 0) out[g] = red[0] + b3[0];
}

// ---------- launch ----------
extern "C" void kernel_launch(void* const* d_in, const int* in_sizes, int n_in,
                              void* d_out, int out_size, void* d_ws, size_t ws_size,
                              hipStream_t stream)
{
    const float* x         = (const float*)d_in[0];
    const float* edge_attr = (const float*)d_in[1];
    const float* charge    = (const float*)d_in[2];
    const int*   edge_index= (const int*)d_in[3];
    const int*   batch     = (const int*)d_in[4];
    const float* W_charge  = (const float*)d_in[5];
    const float* b_charge  = (const float*)d_in[6];
    const float* W_atom    = (const float*)d_in[7];
    const float* b_atom    = (const float*)d_in[8];
    const float* W_bond    = (const float*)d_in[9];
    const float* b_bond    = (const float*)d_in[10];
    const float* nu_W1     = (const float*)d_in[11];
    const float* nu_b1     = (const float*)d_in[12];
    const float* nu_W2     = (const float*)d_in[13];
    const float* nu_b2     = (const float*)d_in[14];
    const float* eu_W1     = (const float*)d_in[15];
    const float* eu_b1     = (const float*)d_in[16];
    const float* eu_W2     = (const float*)d_in[17];
    const float* eu_b2     = (const float*)d_in[18];
    const float* bn_gamma  = (const float*)d_in[19];
    const float* bn_beta   = (const float*)d_in[20];
    const float* p_W1      = (const float*)d_in[21];
    const float* p_b1      = (const float*)d_in[22];
    const float* p_W2      = (const float*)d_in[23];
    const float* p_b2      = (const float*)d_in[24];
    const float* p_W3      = (const float*)d_in[25];
    const float* p_b3      = (const float*)d_in[26];

    const int* rowi = edge_index;
    const int* coli = edge_index + EE;

    char* ws = (char*)d_ws;
    float* ea    = (float*)ws;                 ws += (size_t)EE*64*4;
    float* h     = (float*)ws;                 ws += (size_t)NN*64*4;
    float* P1    = (float*)ws;                 ws += (size_t)NN*64*4;
    float* P2    = (float*)ws;                 ws += (size_t)NN*64*4;
    float* P3    = (float*)ws;                 ws += (size_t)NN*64*4;
    float* h_new = (float*)ws;                 ws += (size_t)NN*64*4;
    float* gsum  = (float*)ws;                 ws += (size_t)GG*64*4;
    float* gcnt  = (float*)ws;                 ws += (size_t)GG*4;
    float* stats = (float*)ws;                 ws += 128*4;
    int*   cnt   = (int*)ws;                   ws += (size_t)NN*4;
    int*   offi  = (int*)ws;                   ws += (size_t)NN*4;
    int*   perm  = (int*)ws;                   ws += (size_t)EE*4;
    int*   rowp  = (int*)ws;                   ws += (size_t)EE*4;
    int*   colp  = (int*)ws;                   ws += (size_t)EE*4;

    float* out = (float*)d_out;

    // --- counting sort of edges by destination (col) ---
    hipMemsetAsync(cnt, 0, (size_t)NN*4, stream);
    hist_kernel<<<(EE + 255)/256, 256, 0, stream>>>(coli, cnt);
    scan_kernel<<<1, 1024, 0, stream>>>(cnt, offi);
    scatter_kernel<<<(EE + 255)/256, 256, 0, stream>>>(rowi, coli, offi, perm, rowp, colp);

    embed_node_kernel<<<512, 256, 0, stream>>>(x, batch, charge, W_charge, b_charge, W_atom, b_atom, h);
    embed_edge_kernel<<<1024, 256, 0, stream>>>(edge_attr, perm, W_bond, b_bond, ea);
    hipMemsetAsync(gsum, 0, (size_t)(GG*64 + GG)*4, stream);

    for (int l = 0; l < NL; ++l) {
        const float* euW1 = eu_W1 + (size_t)l*192*64;
        const float* nuW1 = nu_W1 + (size_t)l*128*64;
        precompute_kernel<<<512, 256, 0, stream>>>(
            h, euW1, euW1 + 64*64, nuW1,
            eu_b1 + l*64, nu_b1 + l*64, P1, P2, P3);
        hipMemsetAsync(h_new, 0, (size_t)NN*64*4, stream);
        hipMemsetAsync(stats, 0, 128*4, stream);
        layer_edge_kernel<<<256, 512, 0, stream>>>(
            ea, P1, P2, P3, h_new, rowp, colp,
            euW1 + 128*64, eu_W2 + (size_t)l*64*64,
            nuW1 + 64*64,  nu_W2 + (size_t)l*64*64,
            eu_b2 + l*64, nu_b2 + l*64);
        bn_stat_kernel<<<256, 256, 0, stream>>>(h_new, stats);
        bn_apply_kernel<<<(NN*16 + 255)/256, 256, 0, stream>>>(
            h_new, h, stats, bn_gamma + l*64, bn_beta + l*64);
    }

    pool_kernel<<<(NN + 1023)/1024, 256, 0, stream>>>(h, batch, gsum, gcnt);
    predictor_kernel<<<GG, 128, 0, stream>>>(gsum, gcnt, p_W1, p_b1, p_W2, p_b2, p_W3, p_b3, out);
}

// Round 3
// 3684.911 us; speedup vs baseline: 1.8307x; 1.8307x over previous
//
#include <hip/hip_runtime.h>
#include <cmath>

#define NN 50000
#define EE 500000
#define GG 256
#define FA 92
#define FB 41
#define DD 64
#define HH 128
#define CQdim 16
#define NL 3
#define EPSBN 1e-5f

typedef __attribute__((ext_vector_type(8))) short short8;
typedef __attribute__((ext_vector_type(4))) float f32x4;

// ---------- helpers ----------
__device__ __forceinline__ float sp1(float x) {
    return fmaxf(x, 0.0f) + log1pf(expf(-fabsf(x)));
}
__device__ __forceinline__ void atomAddF(float* p, float v) {
    unsafeAtomicAdd(p, v);
}
__device__ __forceinline__ unsigned short f2bf(float f) {
    unsigned int u = __float_as_uint(f);
    unsigned int r = u + 0x7FFFu + ((u >> 16) & 1u);
    return (unsigned short)(r >> 16);
}
__device__ __forceinline__ float bf2f(unsigned short s) {
    return __uint_as_float(((unsigned int)s) << 16);
}

// fp32 tile matmul used by embed/precompute kernels
template<int K, int LD>
__device__ __forceinline__ void mm_tile(float4 acc[4], const float* __restrict__ Ubuf, int r0,
                                        const float* __restrict__ W, int c0)
{
#pragma unroll
    for (int k0 = 0; k0 < K; k0 += 4) {
        float4 w0 = *(const float4*)&W[(k0+0)*64 + c0];
        float4 w1 = *(const float4*)&W[(k0+1)*64 + c0];
        float4 w2 = *(const float4*)&W[(k0+2)*64 + c0];
        float4 w3 = *(const float4*)&W[(k0+3)*64 + c0];
#pragma unroll
        for (int i = 0; i < 4; ++i) {
            float4 u = *(const float4*)&Ubuf[(r0+i)*LD + k0];
            acc[i].x += u.x*w0.x + u.y*w1.x + u.z*w2.x + u.w*w3.x;
            acc[i].y += u.x*w0.y + u.y*w1.y + u.z*w2.y + u.w*w3.y;
            acc[i].z += u.x*w0.z + u.y*w1.z + u.z*w2.z + u.w*w3.z;
            acc[i].w += u.x*w0.w + u.y*w1.w + u.z*w2.w + u.w*w3.w;
        }
    }
}

// ---------- counting sort of edges by col ----------
__global__ __launch_bounds__(256) void hist_kernel(const int* __restrict__ coli, int* __restrict__ cnt)
{
    int e = blockIdx.x*256 + threadIdx.x;
    if (e < EE) atomicAdd(&cnt[coli[e]], 1);
}

__global__ __launch_bounds__(1024) void scan_kernel(const int* __restrict__ cnt, int* __restrict__ off)
{
    __shared__ int buf[1024];
    __shared__ int carry;
    if (threadIdx.x == 0) carry = 0;
    __syncthreads();
    for (int base = 0; base < NN; base += 1024) {
        int i = base + threadIdx.x;
        int v = (i < NN) ? cnt[i] : 0;
        buf[threadIdx.x] = v;
        __syncthreads();
#pragma unroll
        for (int ofs = 1; ofs < 1024; ofs <<= 1) {
            int t = 0;
            if (threadIdx.x >= ofs) t = buf[threadIdx.x - ofs];
            __syncthreads();
            if (threadIdx.x >= ofs) buf[threadIdx.x] += t;
            __syncthreads();
        }
        if (i < NN) off[i] = carry + buf[threadIdx.x] - v;   // exclusive
        __syncthreads();
        if (threadIdx.x == 0) carry += buf[1023];
        __syncthreads();
    }
}

__global__ __launch_bounds__(256) void scatter_kernel(
    const int* __restrict__ rowi, const int* __restrict__ coli, int* __restrict__ off,
    int* __restrict__ perm, int* __restrict__ rowp, int* __restrict__ colp)
{
    int e = blockIdx.x*256 + threadIdx.x;
    if (e >= EE) return;
    int c = coli[e];
    int p = atomicAdd(&off[c], 1);
    perm[p] = e; rowp[p] = rowi[e]; colp[p] = c;
}

// ---------- node embedding ----------
__global__ __launch_bounds__(256) void embed_node_kernel(
    const float* __restrict__ x, const int* __restrict__ batch,
    const float* __restrict__ charge, const float* __restrict__ Wc,
    const float* __restrict__ bc, const float* __restrict__ Wa,
    const float* __restrict__ ba, float* __restrict__ h)
{
    const int K = FA + CQdim; // 108
    __shared__ float sW[108*64];
    __shared__ float sX[64*108];
    for (int i = threadIdx.x; i < K*64; i += 256) sW[i] = Wa[i];
    const int fg = threadIdx.x & 15, ng = threadIdx.x >> 4, c0 = fg*4;
    for (int tb = blockIdx.x*64; tb < NN; tb += gridDim.x*64) {
        __syncthreads();
        for (int i = threadIdx.x; i < 64*K; i += 256) {
            int n = i / K, c = i % K;
            int node = tb + n;
            float v = 0.f;
            if (node < NN) {
                if (c < FA) v = x[(size_t)node*FA + c];
                else { int q = c - FA; int g = batch[node]; v = charge[g]*Wc[q] + bc[q]; }
            }
            sX[n*K + c] = v;
        }
        __syncthreads();
        float4 acc[4];
        float4 bb = *(const float4*)&ba[c0];
#pragma unroll
        for (int i = 0; i < 4; ++i) acc[i] = bb;
        mm_tile<108,108>(acc, sX, ng*4, sW, c0);
#pragma unroll
        for (int i = 0; i < 4; ++i) {
            int node = tb + ng*4 + i;
            if (node < NN) *(float4*)&h[(size_t)node*64 + c0] = acc[i];
        }
    }
}

// ---------- edge embedding (permuted, bf16 output) ----------
__global__ __launch_bounds__(256) void embed_edge_kernel(
    const float* __restrict__ eattr, const int* __restrict__ perm,
    const float* __restrict__ Wb, const float* __restrict__ bbond,
    unsigned short* __restrict__ ea)
{
    const int K = 44;
    __shared__ float sW[44*64];
    __shared__ float sX[64*44];
    for (int i = threadIdx.x; i < K*64; i += 256) {
        int r = i >> 6, c = i & 63;
        sW[i] = (r < FB) ? Wb[r*64 + c] : 0.f;
    }
    const int fg = threadIdx.x & 15, ng = threadIdx.x >> 4, c0 = fg*4;
    for (int tb = blockIdx.x*64; tb < EE; tb += gridDim.x*64) {
        __syncthreads();
        for (int i = threadIdx.x; i < 64*K; i += 256) {
            int n = i / K, c = i % K;
            int p = tb + n;
            float v = 0.f;
            if (p < EE && c < FB) {
                int e = perm[p];
                v = eattr[(size_t)e*FB + c];
            }
            sX[n*K + c] = v;
        }
        __syncthreads();
        float4 acc[4];
        float4 bv = *(const float4*)&bbond[c0];
#pragma unroll
        for (int i = 0; i < 4; ++i) acc[i] = bv;
        mm_tile<44,44>(acc, sX, ng*4, sW, c0);
#pragma unroll
        for (int i = 0; i < 4; ++i) {
            int p = tb + ng*4 + i;
            if (p < EE) {
                ushort4 o;
                o.x = f2bf(acc[i].x); o.y = f2bf(acc[i].y);
                o.z = f2bf(acc[i].z); o.w = f2bf(acc[i].w);
                *(ushort4*)&ea[(size_t)p*64 + c0] = o;
            }
        }
    }
}

// ---------- per-layer node precompute ----------
__global__ __launch_bounds__(256) void precompute_kernel(
    const float* __restrict__ h,
    const float* __restrict__ W1, const float* __restrict__ W2, const float* __restrict__ W3,
    const float* __restrict__ b1, const float* __restrict__ b3,
    float* __restrict__ P1, float* __restrict__ P2, float* __restrict__ P3)
{
    __shared__ float sW1[4096], sW2[4096], sW3[4096];
    __shared__ float sH[64*68];
    for (int i = threadIdx.x; i < 4096; i += 256) { sW1[i]=W1[i]; sW2[i]=W2[i]; sW3[i]=W3[i]; }
    const int fg = threadIdx.x & 15, ng = threadIdx.x >> 4, c0 = fg*4;
    for (int tb = blockIdx.x*64; tb < NN; tb += gridDim.x*64) {
        __syncthreads();
        for (int i = threadIdx.x; i < 4096; i += 256) {
            int n = i >> 6, c = i & 63;
            int node = tb + n;
            sH[n*68 + c] = (node < NN) ? h[(size_t)node*64 + c] : 0.f;
        }
        __syncthreads();
        float4 a1[4], a2[4], a3[4];
        float4 v1 = *(const float4*)&b1[c0];
        float4 v3 = *(const float4*)&b3[c0];
#pragma unroll
        for (int i = 0; i < 4; ++i) { a1[i]=v1; a2[i]=make_float4(0,0,0,0); a3[i]=v3; }
        mm_tile<64,68>(a1, sH, ng*4, sW1, c0);
        mm_tile<64,68>(a2, sH, ng*4, sW2, c0);
        mm_tile<64,68>(a3, sH, ng*4, sW3, c0);
#pragma unroll
        for (int i = 0; i < 4; ++i) {
            int node = tb + ng*4 + i;
            if (node < NN) {
                *(float4*)&P1[(size_t)node*64+c0] = a1[i];
                *(float4*)&P2[(size_t)node*64+c0] = a2[i];
                *(float4*)&P3[(size_t)node*64+c0] = a3[i];
            }
        }
    }
}

// ---------- MFMA fused per-edge kernel over col-sorted edges ----------
// phase1: t1 = sp(P1[row]+P2[col] + ea@WA)
// phase2: ea' = t1@WB + eb2              -> global (bf16) + LDS
// phase3: t2 = sp(P3[row] + ea'@WC)
// phase4: msg = t2@WD + nb2              -> global (bf16, col-sorted order)
__global__ __launch_bounds__(512, 2) void layer_edge_kernel(
    unsigned short* __restrict__ ea,
    const float* __restrict__ P1, const float* __restrict__ P2, const float* __restrict__ P3,
    unsigned short* __restrict__ msg,
    const int* __restrict__ rowp, const int* __restrict__ colp,
    const float* __restrict__ WA, const float* __restrict__ WB,
    const float* __restrict__ WC, const float* __restrict__ WD,
    const float* __restrict__ eb2, const float* __restrict__ nb2)
{
    // B-fragment-swizzled bf16 weights: sB[((mat*2+kb)*64 + n)*40 + q8]
    __shared__ unsigned short sB[20480];          // 40 KB
    __shared__ unsigned short sU[8][16*72];       // 18 KB, per-wave tiles
    for (int idx = threadIdx.x; idx < 4*64*64; idx += 512) {
        int mat = idx >> 12;
        int rem = idx & 4095;
        int k = rem >> 6, n = rem & 63;
        int kb = k >> 5, q8 = k & 31;
        const float* W = (mat==0) ? WA : (mat==1) ? WB : (mat==2) ? WC : WD;
        sB[((mat*2 + kb)*64 + n)*40 + q8] = f2bf(W[k*64 + n]);
    }
    __syncthreads();   // only block-wide sync; waves independent after this

    const int lane = threadIdx.x & 63;
    const int wave = threadIdx.x >> 6;
    const int n16  = lane & 15;
    const int quad = lane >> 4;
    unsigned short* U = sU[wave];

    float eb2v[4], nb2v[4];
#pragma unroll
    for (int nt = 0; nt < 4; ++nt) { eb2v[nt] = eb2[nt*16 + n16]; nb2v[nt] = nb2[nt*16 + n16]; }

    const int sr = lane >> 2;       // staging row 0..15
    const int sseg = lane & 3;      // staging k-segment

    const int numTiles = EE >> 4;
    for (int tile = blockIdx.x*8 + wave; tile < numTiles; tile += gridDim.x*8) {
        const int base = tile << 4;
        int rid[4], cid[4];
#pragma unroll
        for (int r = 0; r < 4; ++r) {
            rid[r] = rowp[base + quad*4 + r];
            cid[r] = colp[base + quad*4 + r];
        }
        // g12[r][nt] = P1[rid][col] + P2[cid][col]  (needed end of phase1)
        float g12[4][4];
#pragma unroll
        for (int r = 0; r < 4; ++r)
#pragma unroll
            for (int nt = 0; nt < 4; ++nt) {
                int c = nt*16 + n16;
                g12[r][nt] = P1[(size_t)rid[r]*64 + c] + P2[(size_t)cid[r]*64 + c];
            }
        // stage ea tile (bf16 copy) into U
        {
            const unsigned short* src = &ea[(size_t)(base + sr)*64 + sseg*16];
            uint4 q0 = *(const uint4*)(src);
            uint4 q1 = *(const uint4*)(src + 8);
            *(uint4*)&U[sr*72 + sseg*16]     = q0;
            *(uint4*)&U[sr*72 + sseg*16 + 8] = q1;
        }
        __builtin_amdgcn_wave_barrier();

        f32x4 zero = {0.f, 0.f, 0.f, 0.f};

#define RUN_MM(MAT, ACC)                                                          \
        {                                                                         \
            short8 a0 = *(const short8*)&U[n16*72 + 0*32 + quad*8];               \
            short8 a1 = *(const short8*)&U[n16*72 + 1*32 + quad*8];               \
            _Pragma("unroll")                                                     \
            for (int nt = 0; nt < 4; ++nt) {                                      \
                short8 b0 = *(const short8*)&sB[(((MAT)*2+0)*64 + nt*16 + n16)*40 + quad*8]; \
                short8 b1 = *(const short8*)&sB[(((MAT)*2+1)*64 + nt*16 + n16)*40 + quad*8]; \
                ACC[nt] = __builtin_amdgcn_mfma_f32_16x16x32_bf16(a0, b0, ACC[nt], 0,0,0);   \
                ACC[nt] = __builtin_amdgcn_mfma_f32_16x16x32_bf16(a1, b1, ACC[nt], 0,0,0);   \
            }                                                                     \
        }

        // ---- phase 1 ----
        f32x4 acc[4];
#pragma unroll
        for (int nt = 0; nt < 4; ++nt) acc[nt] = zero;
        RUN_MM(0, acc);
#pragma unroll
        for (int nt = 0; nt < 4; ++nt)
#pragma unroll
            for (int r = 0; r < 4; ++r) {
                float t = sp1(acc[nt][r] + g12[r][nt]);
                U[(quad*4 + r)*72 + nt*16 + n16] = f2bf(t);
            }
        __builtin_amdgcn_wave_barrier();

        // ---- phase 2 ----
#pragma unroll
        for (int nt = 0; nt < 4; ++nt) acc[nt] = zero;
        RUN_MM(1, acc);
#pragma unroll
        for (int nt = 0; nt < 4; ++nt)
#pragma unroll
            for (int r = 0; r < 4; ++r) {
                float v = acc[nt][r] + eb2v[nt];
                unsigned short bv = f2bf(v);
                ea[(size_t)(base + quad*4 + r)*64 + nt*16 + n16] = bv;
                U[(quad*4 + r)*72 + nt*16 + n16] = bv;
            }
        // P3 gathers (overlap with phase3 frag loads)
        float g3[4][4];
#pragma unroll
        for (int r = 0; r < 4; ++r)
#pragma unroll
            for (int nt = 0; nt < 4; ++nt)
                g3[r][nt] = P3[(size_t)rid[r]*64 + nt*16 + n16];
        __builtin_amdgcn_wave_barrier();

        // ---- phase 3 ----
#pragma unroll
        for (int nt = 0; nt < 4; ++nt) acc[nt] = zero;
        RUN_MM(2, acc);
#pragma unroll
        for (int nt = 0; nt < 4; ++nt)
#pragma unroll
            for (int r = 0; r < 4; ++r) {
                float t = sp1(acc[nt][r] + g3[r][nt]);
                U[(quad*4 + r)*72 + nt*16 + n16] = f2bf(t);
            }
        __builtin_amdgcn_wave_barrier();

        // ---- phase 4 ----
#pragma unroll
        for (int nt = 0; nt < 4; ++nt) acc[nt] = zero;
        RUN_MM(3, acc);
#pragma unroll
        for (int nt = 0; nt < 4; ++nt)
#pragma unroll
            for (int r = 0; r < 4; ++r) {
                float v = acc[nt][r] + nb2v[nt];
                msg[(size_t)(base + quad*4 + r)*64 + nt*16 + n16] = f2bf(v);
            }
        __builtin_amdgcn_wave_barrier();
#undef RUN_MM
    }
}

// ---------- CSR segment-sum of msg -> h_new, fused BN statistics ----------
__global__ __launch_bounds__(256) void reduce_kernel(
    const unsigned short* __restrict__ msg, const int* __restrict__ offi,
    float* __restrict__ h_new, float* __restrict__ stats)
{
    const int t = threadIdx.x;
    const int nl = t >> 4;               // node within block 0..15
    const int n  = blockIdx.x*16 + nl;
    const int c0 = (t & 15)*4;
    float a0=0.f, a1=0.f, a2=0.f, a3=0.f;
    if (n < NN) {
        int s = (n == 0) ? 0 : offi[n-1];
        int e = offi[n];
        for (int p = s; p < e; ++p) {
            uint2 q = *(const uint2*)&msg[(size_t)p*64 + c0];
            a0 += bf2f((unsigned short)(q.x & 0xffff));
            a1 += bf2f((unsigned short)(q.x >> 16));
            a2 += bf2f((unsigned short)(q.y & 0xffff));
            a3 += bf2f((unsigned short)(q.y >> 16));
        }
        *(float4*)&h_new[(size_t)n*64 + c0] = make_float4(a0,a1,a2,a3);
    }
    // fused BN stats
    __shared__ float Ss[16][64];
    __shared__ float Sq[16][64];
    Ss[nl][c0+0]=a0; Ss[nl][c0+1]=a1; Ss[nl][c0+2]=a2; Ss[nl][c0+3]=a3;
    Sq[nl][c0+0]=a0*a0; Sq[nl][c0+1]=a1*a1; Sq[nl][c0+2]=a2*a2; Sq[nl][c0+3]=a3*a3;
    __syncthreads();
    if (t < 64) {
        float s = 0.f, q = 0.f;
#pragma unroll
        for (int r = 0; r < 16; ++r) { s += Ss[r][t]; q += Sq[r][t]; }
        atomAddF(&stats[t], s);
        atomAddF(&stats[64 + t], q);
    }
}

// ---------- bn apply + softplus + residual ----------
__global__ __launch_bounds__(256) void bn_apply_kernel(
    const float* __restrict__ hn, float* __restrict__ h,
    const float* __restrict__ stats, const float* __restrict__ gamma, const float* __restrict__ beta)
{
    size_t idx = (size_t)blockIdx.x*256 + threadIdx.x;
    if (idx >= (size_t)NN*16) return;
    int c0 = (int)(idx & 15) << 2;
    float4 v = ((const float4*)hn)[idx];
    float4 r = ((const float4*)h)[idx];
    float vv[4] = {v.x, v.y, v.z, v.w};
    float rr[4] = {r.x, r.y, r.z, r.w};
    float oo[4];
    const float invN = 1.0f / (float)NN;
#pragma unroll
    for (int c = 0; c < 4; ++c) {
        int col = c0 + c;
        float mu  = stats[col] * invN;
        float var = stats[64+col] * invN - mu*mu;
        float is  = rsqrtf(var + EPSBN);
        float nv  = (vv[c] - mu) * is * gamma[col] + beta[col];
        oo[c] = sp1(nv) + rr[c];
    }
    ((float4*)h)[idx] = make_float4(oo[0], oo[1], oo[2], oo[3]);
}

// ---------- global mean pool (batch sorted -> run-accumulate) ----------
__global__ __launch_bounds__(256) void pool_kernel(
    const float* __restrict__ h, const int* __restrict__ batch,
    float* __restrict__ gsum, float* __restrict__ gcnt)
{
    const int col = threadIdx.x & 63, rg = threadIdx.x >> 6;
    int n0 = blockIdx.x*1024 + rg*256;
    if (n0 >= NN) return;
    int n1 = n0 + 256; if (n1 > NN) n1 = NN;
    float s = 0.f;
    int cur = batch[n0];
    int cnt = 0;
    for (int n = n0; n < n1; ++n) {
        int g = batch[n];
        if (g != cur) {
            atomAddF(&gsum[cur*64 + col], s);
            if (col == 0) atomAddF(&gcnt[cur], (float)cnt);
            s = 0.f; cnt = 0; cur = g;
        }
        s += h[(size_t)n*64 + col];
        ++cnt;
    }
    atomAddF(&gsum[cur*64 + col], s);
    if (col == 0) atomAddF(&gcnt[cur], (float)cnt);
}

// ---------- predictor MLP ----------
__global__ __launch_bounds__(128) void predictor_kernel(
    const float* __restrict__ gsum, const float* __restrict__ gcnt,
    const float* __restrict__ W1, const float* __restrict__ b1,
    const float* __restrict__ W2, const float* __restrict__ b2,
    const float* __restrict__ W3, const float* __restrict__ b3,
    float* __restrict__ out)
{
    int g = blockIdx.x, t = threadIdx.x;
    __shared__ float gr[64];
    __shared__ float z1[128];
    __shared__ float z2[128];
    __shared__ float red[128];
    if (t < 64) gr[t] = gsum[g*64 + t] / fmaxf(gcnt[g], 1.0f);
    __syncthreads();
    float s = b1[t];
    for (int k = 0; k < 64; ++k) s += gr[k] * W1[k*128 + t];
    z1[t] = sp1(s);
    __syncthreads();
    s = b2[t];
    for (int k = 0; k < 128; ++k) s += z1[k] * W2[k*128 + t];
    z2[t] = sp1(s);
    __syncthreads();
    red[t] = z2[t] * W3[t];
    __syncthreads();
    for (int off = 64; off > 0; off >>= 1) {
        if (t < off) red[t] += red[t + off];
        __syncthreads();
    }
    if (t == 0) out[g] = red[0] + b3[0];
}

// ---------- launch ----------
extern "C" void kernel_launch(void* const* d_in, const int* in_sizes, int n_in,
                              void* d_out, int out_size, void* d_ws, size_t ws_size,
                              hipStream_t stream)
{
    const float* x         = (const float*)d_in[0];
    const float* edge_attr = (const float*)d_in[1];
    const float* charge    = (const float*)d_in[2];
    const int*   edge_index= (const int*)d_in[3];
    const int*   batch     = (const int*)d_in[4];
    const float* W_charge  = (const float*)d_in[5];
    const float* b_charge  = (const float*)d_in[6];
    const float* W_atom    = (const float*)d_in[7];
    const float* b_atom    = (const float*)d_in[8];
    const float* W_bond    = (const float*)d_in[9];
    const float* b_bond    = (const float*)d_in[10];
    const float* nu_W1     = (const float*)d_in[11];
    const float* nu_b1     = (const float*)d_in[12];
    const float* nu_W2     = (const float*)d_in[13];
    const float* nu_b2     = (const float*)d_in[14];
    const float* eu_W1     = (const float*)d_in[15];
    const float* eu_b1     = (const float*)d_in[16];
    const float* eu_W2     = (const float*)d_in[17];
    const float* eu_b2     = (const float*)d_in[18];
    const float* bn_gamma  = (const float*)d_in[19];
    const float* bn_beta   = (const float*)d_in[20];
    const float* p_W1      = (const float*)d_in[21];
    const float* p_b1      = (const float*)d_in[22];
    const float* p_W2      = (const float*)d_in[23];
    const float* p_b2      = (const float*)d_in[24];
    const float* p_W3      = (const float*)d_in[25];
    const float* p_b3      = (const float*)d_in[26];

    const int* rowi = edge_index;
    const int* coli = edge_index + EE;

    char* ws = (char*)d_ws;
    unsigned short* ea  = (unsigned short*)ws;  ws += (size_t)EE*64*2;   // 64 MB bf16
    unsigned short* msg = (unsigned short*)ws;  ws += (size_t)EE*64*2;   // 64 MB bf16
    float* h     = (float*)ws;                  ws += (size_t)NN*64*4;
    float* P1    = (float*)ws;                  ws += (size_t)NN*64*4;
    float* P2    = (float*)ws;                  ws += (size_t)NN*64*4;
    float* P3    = (float*)ws;                  ws += (size_t)NN*64*4;
    float* h_new = (float*)ws;                  ws += (size_t)NN*64*4;
    float* gsum  = (float*)ws;                  ws += (size_t)GG*64*4;
    float* gcnt  = (float*)ws;                  ws += (size_t)GG*4;
    float* stats = (float*)ws;                  ws += 128*4;
    int*   cnt   = (int*)ws;                    ws += (size_t)NN*4;
    int*   offi  = (int*)ws;                    ws += (size_t)NN*4;
    int*   perm  = (int*)ws;                    ws += (size_t)EE*4;
    int*   rowp  = (int*)ws;                    ws += (size_t)EE*4;
    int*   colp  = (int*)ws;                    ws += (size_t)EE*4;

    float* out = (float*)d_out;

    // counting sort of edges by destination
    hipMemsetAsync(cnt, 0, (size_t)NN*4, stream);
    hist_kernel<<<(EE + 255)/256, 256, 0, stream>>>(coli, cnt);
    scan_kernel<<<1, 1024, 0, stream>>>(cnt, offi);
    scatter_kernel<<<(EE + 255)/256, 256, 0, stream>>>(rowi, coli, offi, perm, rowp, colp);

    embed_node_kernel<<<512, 256, 0, stream>>>(x, batch, charge, W_charge, b_charge, W_atom, b_atom, h);
    embed_edge_kernel<<<1024, 256, 0, stream>>>(edge_attr, perm, W_bond, b_bond, ea);
    hipMemsetAsync(gsum, 0, (size_t)(GG*64 + GG)*4, stream);

    for (int l = 0; l < NL; ++l) {
        const float* euW1 = eu_W1 + (size_t)l*192*64;
        const float* nuW1 = nu_W1 + (size_t)l*128*64;
        precompute_kernel<<<512, 256, 0, stream>>>(
            h, euW1, euW1 + 64*64, nuW1,
            eu_b1 + l*64, nu_b1 + l*64, P1, P2, P3);
        hipMemsetAsync(stats, 0, 128*4, stream);
        layer_edge_kernel<<<512, 512, 0, stream>>>(
            ea, P1, P2, P3, msg, rowp, colp,
            euW1 + 128*64, eu_W2 + (size_t)l*64*64,
            nuW1 + 64*64,  nu_W2 + (size_t)l*64*64,
            eu_b2 + l*64, nu_b2 + l*64);
        reduce_kernel<<<(NN + 15)/16, 256, 0, stream>>>(msg, offi, h_new, stats);
        bn_apply_kernel<<<(NN*16 + 255)/256, 256, 0, stream>>>(
            h_new, h, stats, bn_gamma + l*64, bn_beta + l*64);
    }

    pool_kernel<<<(NN + 1023)/1024, 256, 0, stream>>>(h, batch, gsum, gcnt);
    predictor_kernel<<<GG, 128, 0, stream>>>(gsum, gcnt, p_W1, p_b1, p_W2, p_b2, p_W3, p_b3, out);
}

// Round 4
// 2145.929 us; speedup vs baseline: 3.1436x; 1.7172x over previous
//
#include <hip/hip_runtime.h>
#include <cmath>

#define NN 50000
#define EE 500000
#define GG 256
#define FA 92
#define FB 41
#define DD 64
#define HH 128
#define CQdim 16
#define NL 3
#define EPSBN 1e-5f

typedef __attribute__((ext_vector_type(8))) short short8;
typedef __attribute__((ext_vector_type(4))) float f32x4;

// ---------- helpers ----------
__device__ __forceinline__ float sp1(float x) {
    return fmaxf(x, 0.0f) + log1pf(expf(-fabsf(x)));
}
__device__ __forceinline__ void atomAddF(float* p, float v) {
    unsafeAtomicAdd(p, v);
}
__device__ __forceinline__ unsigned short f2bf(float f) {
    unsigned int u = __float_as_uint(f);
    unsigned int r = u + 0x7FFFu + ((u >> 16) & 1u);
    return (unsigned short)(r >> 16);
}
__device__ __forceinline__ float bf2f(unsigned short s) {
    return __uint_as_float(((unsigned int)s) << 16);
}

// fp32 tile matmul used by embed kernels
template<int K, int LD>
__device__ __forceinline__ void mm_tile(float4 acc[4], const float* __restrict__ Ubuf, int r0,
                                        const float* __restrict__ W, int c0)
{
#pragma unroll
    for (int k0 = 0; k0 < K; k0 += 4) {
        float4 w0 = *(const float4*)&W[(k0+0)*64 + c0];
        float4 w1 = *(const float4*)&W[(k0+1)*64 + c0];
        float4 w2 = *(const float4*)&W[(k0+2)*64 + c0];
        float4 w3 = *(const float4*)&W[(k0+3)*64 + c0];
#pragma unroll
        for (int i = 0; i < 4; ++i) {
            float4 u = *(const float4*)&Ubuf[(r0+i)*LD + k0];
            acc[i].x += u.x*w0.x + u.y*w1.x + u.z*w2.x + u.w*w3.x;
            acc[i].y += u.x*w0.y + u.y*w1.y + u.z*w2.y + u.w*w3.y;
            acc[i].z += u.x*w0.z + u.y*w1.z + u.z*w2.z + u.w*w3.z;
            acc[i].w += u.x*w0.w + u.y*w1.w + u.z*w2.w + u.w*w3.w;
        }
    }
}

// ---------- counting sort of edges by col ----------
__global__ __launch_bounds__(256) void hist_kernel(const int* __restrict__ coli, int* __restrict__ cnt)
{
    int e = blockIdx.x*256 + threadIdx.x;
    if (e < EE) atomicAdd(&cnt[coli[e]], 1);
}

__global__ __launch_bounds__(1024) void scan_kernel(const int* __restrict__ cnt, int* __restrict__ off)
{
    __shared__ int buf[1024];
    __shared__ int carry;
    if (threadIdx.x == 0) carry = 0;
    __syncthreads();
    for (int base = 0; base < NN; base += 1024) {
        int i = base + threadIdx.x;
        int v = (i < NN) ? cnt[i] : 0;
        buf[threadIdx.x] = v;
        __syncthreads();
#pragma unroll
        for (int ofs = 1; ofs < 1024; ofs <<= 1) {
            int t = 0;
            if (threadIdx.x >= ofs) t = buf[threadIdx.x - ofs];
            __syncthreads();
            if (threadIdx.x >= ofs) buf[threadIdx.x] += t;
            __syncthreads();
        }
        if (i < NN) off[i] = carry + buf[threadIdx.x] - v;   // exclusive
        __syncthreads();
        if (threadIdx.x == 0) carry += buf[1023];
        __syncthreads();
    }
}

__global__ __launch_bounds__(256) void scatter_kernel(
    const int* __restrict__ rowi, const int* __restrict__ coli, int* __restrict__ off,
    int* __restrict__ perm, int* __restrict__ rowp, int* __restrict__ colp)
{
    int e = blockIdx.x*256 + threadIdx.x;
    if (e >= EE) return;
    int c = coli[e];
    int p = atomicAdd(&off[c], 1);
    perm[p] = e; rowp[p] = rowi[e]; colp[p] = c;
}

// ---------- node embedding ----------
__global__ __launch_bounds__(256) void embed_node_kernel(
    const float* __restrict__ x, const int* __restrict__ batch,
    const float* __restrict__ charge, const float* __restrict__ Wc,
    const float* __restrict__ bc, const float* __restrict__ Wa,
    const float* __restrict__ ba, float* __restrict__ h)
{
    const int K = FA + CQdim; // 108
    __shared__ float sW[108*64];
    __shared__ float sX[64*108];
    for (int i = threadIdx.x; i < K*64; i += 256) sW[i] = Wa[i];
    const int fg = threadIdx.x & 15, ng = threadIdx.x >> 4, c0 = fg*4;
    for (int tb = blockIdx.x*64; tb < NN; tb += gridDim.x*64) {
        __syncthreads();
        for (int i = threadIdx.x; i < 64*K; i += 256) {
            int n = i / K, c = i % K;
            int node = tb + n;
            float v = 0.f;
            if (node < NN) {
                if (c < FA) v = x[(size_t)node*FA + c];
                else { int q = c - FA; int g = batch[node]; v = charge[g]*Wc[q] + bc[q]; }
            }
            sX[n*K + c] = v;
        }
        __syncthreads();
        float4 acc[4];
        float4 bb = *(const float4*)&ba[c0];
#pragma unroll
        for (int i = 0; i < 4; ++i) acc[i] = bb;
        mm_tile<108,108>(acc, sX, ng*4, sW, c0);
#pragma unroll
        for (int i = 0; i < 4; ++i) {
            int node = tb + ng*4 + i;
            if (node < NN) *(float4*)&h[(size_t)node*64 + c0] = acc[i];
        }
    }
}

// ---------- edge embedding (permuted, bf16 output) ----------
__global__ __launch_bounds__(256) void embed_edge_kernel(
    const float* __restrict__ eattr, const int* __restrict__ perm,
    const float* __restrict__ Wb, const float* __restrict__ bbond,
    unsigned short* __restrict__ ea)
{
    const int K = 44;
    __shared__ float sW[44*64];
    __shared__ float sX[64*44];
    for (int i = threadIdx.x; i < K*64; i += 256) {
        int r = i >> 6, c = i & 63;
        sW[i] = (r < FB) ? Wb[r*64 + c] : 0.f;
    }
    const int fg = threadIdx.x & 15, ng = threadIdx.x >> 4, c0 = fg*4;
    for (int tb = blockIdx.x*64; tb < EE; tb += gridDim.x*64) {
        __syncthreads();
        for (int i = threadIdx.x; i < 64*K; i += 256) {
            int n = i / K, c = i % K;
            int p = tb + n;
            float v = 0.f;
            if (p < EE && c < FB) {
                int e = perm[p];
                v = eattr[(size_t)e*FB + c];
            }
            sX[n*K + c] = v;
        }
        __syncthreads();
        float4 acc[4];
        float4 bv = *(const float4*)&bbond[c0];
#pragma unroll
        for (int i = 0; i < 4; ++i) acc[i] = bv;
        mm_tile<44,44>(acc, sX, ng*4, sW, c0);
#pragma unroll
        for (int i = 0; i < 4; ++i) {
            int p = tb + ng*4 + i;
            if (p < EE) {
                ushort4 o;
                o.x = f2bf(acc[i].x); o.y = f2bf(acc[i].y);
                o.z = f2bf(acc[i].z); o.w = f2bf(acc[i].w);
                *(ushort4*)&ea[(size_t)p*64 + c0] = o;
            }
        }
    }
}

// ---------- per-layer node precompute via MFMA ----------
// P1 = h@W1 + b1 ; P2 = h@W2 ; P3 = h@W3 + b3
// Same fragment layouts as layer_edge_kernel (validated).
__global__ __launch_bounds__(256) void precompute_kernel(
    const float* __restrict__ h,
    const float* __restrict__ W1, const float* __restrict__ W2, const float* __restrict__ W3,
    const float* __restrict__ b1, const float* __restrict__ b3,
    float* __restrict__ P1, float* __restrict__ P2, float* __restrict__ P3)
{
    // bf16 B-fragment-swizzled weights: sB[((mat*2+kb)*64 + n)*40 + q8]
    __shared__ unsigned short sB[3*2*64*40];     // 30 KB
    __shared__ unsigned short sU[4][16*72];      // 9 KB, per-wave node tiles
    for (int idx = threadIdx.x; idx < 3*64*64; idx += 256) {
        int mat = idx >> 12;
        int rem = idx & 4095;
        int k = rem >> 6, n = rem & 63;
        int kb = k >> 5, q8 = k & 31;
        const float* W = (mat==0) ? W1 : (mat==1) ? W2 : W3;
        sB[((mat*2 + kb)*64 + n)*40 + q8] = f2bf(W[k*64 + n]);
    }
    __syncthreads();   // waves independent after this

    const int lane = threadIdx.x & 63;
    const int wave = threadIdx.x >> 6;
    const int n16  = lane & 15;
    const int quad = lane >> 4;
    unsigned short* U = sU[wave];

    float b1v[4], b3v[4];
#pragma unroll
    for (int nt = 0; nt < 4; ++nt) { b1v[nt] = b1[nt*16 + n16]; b3v[nt] = b3[nt*16 + n16]; }

    const int sr = lane >> 2;   // staging row 0..15
    const int sseg = lane & 3;  // 16-float segment

    const int numTiles = NN >> 4;   // 50000/16 = 3125 exactly
    for (int tile = blockIdx.x*4 + wave; tile < numTiles; tile += gridDim.x*4) {
        const int base = tile << 4;
        // stage 16x64 fp32 h tile -> bf16 U
        {
            const float* src = &h[(size_t)(base + sr)*64 + sseg*16];
            float4 f0 = *(const float4*)(src);
            float4 f1 = *(const float4*)(src + 4);
            float4 f2 = *(const float4*)(src + 8);
            float4 f3 = *(const float4*)(src + 12);
            unsigned short* dst = &U[sr*72 + sseg*16];
            ushort4 o0 = { f2bf(f0.x), f2bf(f0.y), f2bf(f0.z), f2bf(f0.w) };
            ushort4 o1 = { f2bf(f1.x), f2bf(f1.y), f2bf(f1.z), f2bf(f1.w) };
            ushort4 o2 = { f2bf(f2.x), f2bf(f2.y), f2bf(f2.z), f2bf(f2.w) };
            ushort4 o3 = { f2bf(f3.x), f2bf(f3.y), f2bf(f3.z), f2bf(f3.w) };
            *(ushort4*)(dst + 0)  = o0;
            *(ushort4*)(dst + 4)  = o1;
            *(ushort4*)(dst + 8)  = o2;
            *(ushort4*)(dst + 12) = o3;
        }
        __builtin_amdgcn_wave_barrier();

        short8 a0 = *(const short8*)&U[n16*72 + 0*32 + quad*8];
        short8 a1 = *(const short8*)&U[n16*72 + 1*32 + quad*8];
        f32x4 zero = {0.f, 0.f, 0.f, 0.f};

#pragma unroll
        for (int mat = 0; mat < 3; ++mat) {
            f32x4 acc[4];
#pragma unroll
            for (int nt = 0; nt < 4; ++nt) acc[nt] = zero;
#pragma unroll
            for (int nt = 0; nt < 4; ++nt) {
                short8 b0 = *(const short8*)&sB[((mat*2 + 0)*64 + nt*16 + n16)*40 + quad*8];
                short8 bq = *(const short8*)&sB[((mat*2 + 1)*64 + nt*16 + n16)*40 + quad*8];
                acc[nt] = __builtin_amdgcn_mfma_f32_16x16x32_bf16(a0, b0, acc[nt], 0,0,0);
                acc[nt] = __builtin_amdgcn_mfma_f32_16x16x32_bf16(a1, bq, acc[nt], 0,0,0);
            }
            float* P = (mat==0) ? P1 : (mat==1) ? P2 : P3;
#pragma unroll
            for (int nt = 0; nt < 4; ++nt) {
                float bias = (mat==0) ? b1v[nt] : (mat==2) ? b3v[nt] : 0.f;
#pragma unroll
                for (int r = 0; r < 4; ++r)
                    P[(size_t)(base + quad*4 + r)*64 + nt*16 + n16] = acc[nt][r] + bias;
            }
        }
        __builtin_amdgcn_wave_barrier();
    }
}

// ---------- MFMA fused per-edge kernel over col-sorted edges ----------
__global__ __launch_bounds__(512, 2) void layer_edge_kernel(
    unsigned short* __restrict__ ea,
    const float* __restrict__ P1, const float* __restrict__ P2, const float* __restrict__ P3,
    unsigned short* __restrict__ msg,
    const int* __restrict__ rowp, const int* __restrict__ colp,
    const float* __restrict__ WA, const float* __restrict__ WB,
    const float* __restrict__ WC, const float* __restrict__ WD,
    const float* __restrict__ eb2, const float* __restrict__ nb2)
{
    __shared__ unsigned short sB[20480];          // 40 KB
    __shared__ unsigned short sU[8][16*72];       // 18 KB
    for (int idx = threadIdx.x; idx < 4*64*64; idx += 512) {
        int mat = idx >> 12;
        int rem = idx & 4095;
        int k = rem >> 6, n = rem & 63;
        int kb = k >> 5, q8 = k & 31;
        const float* W = (mat==0) ? WA : (mat==1) ? WB : (mat==2) ? WC : WD;
        sB[((mat*2 + kb)*64 + n)*40 + q8] = f2bf(W[k*64 + n]);
    }
    __syncthreads();

    const int lane = threadIdx.x & 63;
    const int wave = threadIdx.x >> 6;
    const int n16  = lane & 15;
    const int quad = lane >> 4;
    unsigned short* U = sU[wave];

    float eb2v[4], nb2v[4];
#pragma unroll
    for (int nt = 0; nt < 4; ++nt) { eb2v[nt] = eb2[nt*16 + n16]; nb2v[nt] = nb2[nt*16 + n16]; }

    const int sr = lane >> 2;
    const int sseg = lane & 3;

    const int numTiles = EE >> 4;
    for (int tile = blockIdx.x*8 + wave; tile < numTiles; tile += gridDim.x*8) {
        const int base = tile << 4;
        int rid[4], cid[4];
#pragma unroll
        for (int r = 0; r < 4; ++r) {
            rid[r] = rowp[base + quad*4 + r];
            cid[r] = colp[base + quad*4 + r];
        }
        float g12[4][4];
#pragma unroll
        for (int r = 0; r < 4; ++r)
#pragma unroll
            for (int nt = 0; nt < 4; ++nt) {
                int c = nt*16 + n16;
                g12[r][nt] = P1[(size_t)rid[r]*64 + c] + P2[(size_t)cid[r]*64 + c];
            }
        {
            const unsigned short* src = &ea[(size_t)(base + sr)*64 + sseg*16];
            uint4 q0 = *(const uint4*)(src);
            uint4 q1 = *(const uint4*)(src + 8);
            *(uint4*)&U[sr*72 + sseg*16]     = q0;
            *(uint4*)&U[sr*72 + sseg*16 + 8] = q1;
        }
        __builtin_amdgcn_wave_barrier();

        f32x4 zero = {0.f, 0.f, 0.f, 0.f};

#define RUN_MM(MAT, ACC)                                                          \
        {                                                                         \
            short8 a0 = *(const short8*)&U[n16*72 + 0*32 + quad*8];               \
            short8 a1 = *(const short8*)&U[n16*72 + 1*32 + quad*8];               \
            _Pragma("unroll")                                                     \
            for (int nt = 0; nt < 4; ++nt) {                                      \
                short8 b0 = *(const short8*)&sB[(((MAT)*2+0)*64 + nt*16 + n16)*40 + quad*8]; \
                short8 b1 = *(const short8*)&sB[(((MAT)*2+1)*64 + nt*16 + n16)*40 + quad*8]; \
                ACC[nt] = __builtin_amdgcn_mfma_f32_16x16x32_bf16(a0, b0, ACC[nt], 0,0,0);   \
                ACC[nt] = __builtin_amdgcn_mfma_f32_16x16x32_bf16(a1, b1, ACC[nt], 0,0,0);   \
            }                                                                     \
        }

        // ---- phase 1 ----
        f32x4 acc[4];
#pragma unroll
        for (int nt = 0; nt < 4; ++nt) acc[nt] = zero;
        RUN_MM(0, acc);
#pragma unroll
        for (int nt = 0; nt < 4; ++nt)
#pragma unroll
            for (int r = 0; r < 4; ++r) {
                float t = sp1(acc[nt][r] + g12[r][nt]);
                U[(quad*4 + r)*72 + nt*16 + n16] = f2bf(t);
            }
        __builtin_amdgcn_wave_barrier();

        // ---- phase 2 ----
#pragma unroll
        for (int nt = 0; nt < 4; ++nt) acc[nt] = zero;
        RUN_MM(1, acc);
#pragma unroll
        for (int nt = 0; nt < 4; ++nt)
#pragma unroll
            for (int r = 0; r < 4; ++r) {
                float v = acc[nt][r] + eb2v[nt];
                unsigned short bv = f2bf(v);
                ea[(size_t)(base + quad*4 + r)*64 + nt*16 + n16] = bv;
                U[(quad*4 + r)*72 + nt*16 + n16] = bv;
            }
        float g3[4][4];
#pragma unroll
        for (int r = 0; r < 4; ++r)
#pragma unroll
            for (int nt = 0; nt < 4; ++nt)
                g3[r][nt] = P3[(size_t)rid[r]*64 + nt*16 + n16];
        __builtin_amdgcn_wave_barrier();

        // ---- phase 3 ----
#pragma unroll
        for (int nt = 0; nt < 4; ++nt) acc[nt] = zero;
        RUN_MM(2, acc);
#pragma unroll
        for (int nt = 0; nt < 4; ++nt)
#pragma unroll
            for (int r = 0; r < 4; ++r) {
                float t = sp1(acc[nt][r] + g3[r][nt]);
                U[(quad*4 + r)*72 + nt*16 + n16] = f2bf(t);
            }
        __builtin_amdgcn_wave_barrier();

        // ---- phase 4 ----
#pragma unroll
        for (int nt = 0; nt < 4; ++nt) acc[nt] = zero;
        RUN_MM(3, acc);
#pragma unroll
        for (int nt = 0; nt < 4; ++nt)
#pragma unroll
            for (int r = 0; r < 4; ++r) {
                float v = acc[nt][r] + nb2v[nt];
                msg[(size_t)(base + quad*4 + r)*64 + nt*16 + n16] = f2bf(v);
            }
        __builtin_amdgcn_wave_barrier();
#undef RUN_MM
    }
}

// ---------- CSR segment-sum of msg -> h_new, fused BN statistics ----------
__global__ __launch_bounds__(256) void reduce_kernel(
    const unsigned short* __restrict__ msg, const int* __restrict__ offi,
    float* __restrict__ h_new, float* __restrict__ stats)
{
    const int t = threadIdx.x;
    const int nl = t >> 4;
    const int n  = blockIdx.x*16 + nl;
    const int c0 = (t & 15)*4;
    float a0=0.f, a1=0.f, a2=0.f, a3=0.f;
    if (n < NN) {
        int s = (n == 0) ? 0 : offi[n-1];
        int e = offi[n];
        for (int p = s; p < e; ++p) {
            uint2 q = *(const uint2*)&msg[(size_t)p*64 + c0];
            a0 += bf2f((unsigned short)(q.x & 0xffff));
            a1 += bf2f((unsigned short)(q.x >> 16));
            a2 += bf2f((unsigned short)(q.y & 0xffff));
            a3 += bf2f((unsigned short)(q.y >> 16));
        }
        *(float4*)&h_new[(size_t)n*64 + c0] = make_float4(a0,a1,a2,a3);
    }
    __shared__ float Ss[16][64];
    __shared__ float Sq[16][64];
    Ss[nl][c0+0]=a0; Ss[nl][c0+1]=a1; Ss[nl][c0+2]=a2; Ss[nl][c0+3]=a3;
    Sq[nl][c0+0]=a0*a0; Sq[nl][c0+1]=a1*a1; Sq[nl][c0+2]=a2*a2; Sq[nl][c0+3]=a3*a3;
    __syncthreads();
    if (t < 64) {
        float s = 0.f, q = 0.f;
#pragma unroll
        for (int r = 0; r < 16; ++r) { s += Ss[r][t]; q += Sq[r][t]; }
        atomAddF(&stats[t], s);
        atomAddF(&stats[64 + t], q);
    }
}

// ---------- bn apply + softplus + residual ----------
__global__ __launch_bounds__(256) void bn_apply_kernel(
    const float* __restrict__ hn, float* __restrict__ h,
    const float* __restrict__ stats, const float* __restrict__ gamma, const float* __restrict__ beta)
{
    size_t idx = (size_t)blockIdx.x*256 + threadIdx.x;
    if (idx >= (size_t)NN*16) return;
    int c0 = (int)(idx & 15) << 2;
    float4 v = ((const float4*)hn)[idx];
    float4 r = ((const float4*)h)[idx];
    float vv[4] = {v.x, v.y, v.z, v.w};
    float rr[4] = {r.x, r.y, r.z, r.w};
    float oo[4];
    const float invN = 1.0f / (float)NN;
#pragma unroll
    for (int c = 0; c < 4; ++c) {
        int col = c0 + c;
        float mu  = stats[col] * invN;
        float var = stats[64+col] * invN - mu*mu;
        float is  = rsqrtf(var + EPSBN);
        float nv  = (vv[c] - mu) * is * gamma[col] + beta[col];
        oo[c] = sp1(nv) + rr[c];
    }
    ((float4*)h)[idx] = make_float4(oo[0], oo[1], oo[2], oo[3]);
}

// ---------- global mean pool (batch sorted -> run-accumulate) ----------
__global__ __launch_bounds__(256) void pool_kernel(
    const float* __restrict__ h, const int* __restrict__ batch,
    float* __restrict__ gsum, float* __restrict__ gcnt)
{
    const int col = threadIdx.x & 63, rg = threadIdx.x >> 6;
    int n0 = blockIdx.x*1024 + rg*256;
    if (n0 >= NN) return;
    int n1 = n0 + 256; if (n1 > NN) n1 = NN;
    float s = 0.f;
    int cur = batch[n0];
    int cnt = 0;
    for (int n = n0; n < n1; ++n) {
        int g = batch[n];
        if (g != cur) {
            atomAddF(&gsum[cur*64 + col], s);
            if (col == 0) atomAddF(&gcnt[cur], (float)cnt);
            s = 0.f; cnt = 0; cur = g;
        }
        s += h[(size_t)n*64 + col];
        ++cnt;
    }
    atomAddF(&gsum[cur*64 + col], s);
    if (col == 0) atomAddF(&gcnt[cur], (float)cnt);
}

// ---------- predictor MLP ----------
__global__ __launch_bounds__(128) void predictor_kernel(
    const float* __restrict__ gsum, const float* __restrict__ gcnt,
    const float* __restrict__ W1, const float* __restrict__ b1,
    const float* __restrict__ W2, const float* __restrict__ b2,
    const float* __restrict__ W3, const float* __restrict__ b3,
    float* __restrict__ out)
{
    int g = blockIdx.x, t = threadIdx.x;
    __shared__ float gr[64];
    __shared__ float z1[128];
    __shared__ float z2[128];
    __shared__ float red[128];
    if (t < 64) gr[t] = gsum[g*64 + t] / fmaxf(gcnt[g], 1.0f);
    __syncthreads();
    float s = b1[t];
    for (int k = 0; k < 64; ++k) s += gr[k] * W1[k*128 + t];
    z1[t] = sp1(s);
    __syncthreads();
    s = b2[t];
    for (int k = 0; k < 128; ++k) s += z1[k] * W2[k*128 + t];
    z2[t] = sp1(s);
    __syncthreads();
    red[t] = z2[t] * W3[t];
    __syncthreads();
    for (int off = 64; off > 0; off >>= 1) {
        if (t < off) red[t] += red[t + off];
        __syncthreads();
    }
    if (t == 0) out[g] = red[0] + b3[0];
}

// ---------- launch ----------
extern "C" void kernel_launch(void* const* d_in, const int* in_sizes, int n_in,
                              void* d_out, int out_size, void* d_ws, size_t ws_size,
                              hipStream_t stream)
{
    const float* x         = (const float*)d_in[0];
    const float* edge_attr = (const float*)d_in[1];
    const float* charge    = (const float*)d_in[2];
    const int*   edge_index= (const int*)d_in[3];
    const int*   batch     = (const int*)d_in[4];
    const float* W_charge  = (const float*)d_in[5];
    const float* b_charge  = (const float*)d_in[6];
    const float* W_atom    = (const float*)d_in[7];
    const float* b_atom    = (const float*)d_in[8];
    const float* W_bond    = (const float*)d_in[9];
    const float* b_bond    = (const float*)d_in[10];
    const float* nu_W1     = (const float*)d_in[11];
    const float* nu_b1     = (const float*)d_in[12];
    const float* nu_W2     = (const float*)d_in[13];
    const float* nu_b2     = (const float*)d_in[14];
    const float* eu_W1     = (const float*)d_in[15];
    const float* eu_b1     = (const float*)d_in[16];
    const float* eu_W2     = (const float*)d_in[17];
    const float* eu_b2     = (const float*)d_in[18];
    const float* bn_gamma  = (const float*)d_in[19];
    const float* bn_beta   = (const float*)d_in[20];
    const float* p_W1      = (const float*)d_in[21];
    const float* p_b1      = (const float*)d_in[22];
    const float* p_W2      = (const float*)d_in[23];
    const float* p_b2      = (const float*)d_in[24];
    const float* p_W3      = (const float*)d_in[25];
    const float* p_b3      = (const float*)d_in[26];

    const int* rowi = edge_index;
    const int* coli = edge_index + EE;

    char* ws = (char*)d_ws;
    unsigned short* ea  = (unsigned short*)ws;  ws += (size_t)EE*64*2;
    unsigned short* msg = (unsigned short*)ws;  ws += (size_t)EE*64*2;
    float* h     = (float*)ws;                  ws += (size_t)NN*64*4;
    float* P1    = (float*)ws;                  ws += (size_t)NN*64*4;
    float* P2    = (float*)ws;                  ws += (size_t)NN*64*4;
    float* P3    = (float*)ws;                  ws += (size_t)NN*64*4;
    float* h_new = (float*)ws;                  ws += (size_t)NN*64*4;
    float* gsum  = (float*)ws;                  ws += (size_t)GG*64*4;
    float* gcnt  = (float*)ws;                  ws += (size_t)GG*4;
    float* stats = (float*)ws;                  ws += 128*4;
    int*   cnt   = (int*)ws;                    ws += (size_t)NN*4;
    int*   offi  = (int*)ws;                    ws += (size_t)NN*4;
    int*   perm  = (int*)ws;                    ws += (size_t)EE*4;
    int*   rowp  = (int*)ws;                    ws += (size_t)EE*4;
    int*   colp  = (int*)ws;                    ws += (size_t)EE*4;

    float* out = (float*)d_out;

    hipMemsetAsync(cnt, 0, (size_t)NN*4, stream);
    hist_kernel<<<(EE + 255)/256, 256, 0, stream>>>(coli, cnt);
    scan_kernel<<<1, 1024, 0, stream>>>(cnt, offi);
    scatter_kernel<<<(EE + 255)/256, 256, 0, stream>>>(rowi, coli, offi, perm, rowp, colp);

    embed_node_kernel<<<512, 256, 0, stream>>>(x, batch, charge, W_charge, b_charge, W_atom, b_atom, h);
    embed_edge_kernel<<<1024, 256, 0, stream>>>(edge_attr, perm, W_bond, b_bond, ea);
    hipMemsetAsync(gsum, 0, (size_t)(GG*64 + GG)*4, stream);

    for (int l = 0; l < NL; ++l) {
        const float* euW1 = eu_W1 + (size_t)l*192*64;
        const float* nuW1 = nu_W1 + (size_t)l*128*64;
        precompute_kernel<<<256, 256, 0, stream>>>(
            h, euW1, euW1 + 64*64, nuW1,
            eu_b1 + l*64, nu_b1 + l*64, P1, P2, P3);
        hipMemsetAsync(stats, 0, 128*4, stream);
        layer_edge_kernel<<<512, 512, 0, stream>>>(
            ea, P1, P2, P3, msg, rowp, colp,
            euW1 + 128*64, eu_W2 + (size_t)l*64*64,
            nuW1 + 64*64,  nu_W2 + (size_t)l*64*64,
            eu_b2 + l*64, nu_b2 + l*64);
        reduce_kernel<<<(NN + 15)/16, 256, 0, stream>>>(msg, offi, h_new, stats);
        bn_apply_kernel<<<(NN*16 + 255)/256, 256, 0, stream>>>(
            h_new, h, stats, bn_gamma + l*64, bn_beta + l*64);
    }

    pool_kernel<<<(NN + 1023)/1024, 256, 0, stream>>>(h, batch, gsum, gcnt);
    predictor_kernel<<<GG, 128, 0, stream>>>(gsum, gcnt, p_W1, p_b1, p_W2, p_b2, p_W3, p_b3, out);
}

// Round 5
// 1519.017 us; speedup vs baseline: 4.4410x; 1.4127x over previous
//
#include <hip/hip_runtime.h>
#include <cmath>

#define NN 50000
#define EE 500000
#define GG 256
#define FA 92
#define FB 41
#define DD 64
#define HH 128
#define CQdim 16
#define NL 3
#define EPSBN 1e-5f

typedef __attribute__((ext_vector_type(8))) short short8;
typedef __attribute__((ext_vector_type(4))) float f32x4;

// ---------- helpers ----------
__device__ __forceinline__ float sp1(float x) {
    return fmaxf(x, 0.0f) + log1pf(expf(-fabsf(x)));
}
__device__ __forceinline__ void atomAddF(float* p, float v) {
    unsafeAtomicAdd(p, v);
}
__device__ __forceinline__ unsigned short f2bf(float f) {
    unsigned int u = __float_as_uint(f);
    unsigned int r = u + 0x7FFFu + ((u >> 16) & 1u);
    return (unsigned short)(r >> 16);
}
__device__ __forceinline__ float bf2f(unsigned short s) {
    return __uint_as_float(((unsigned int)s) << 16);
}

// ---------- counting sort of edges by col ----------
__global__ __launch_bounds__(256) void hist_kernel(const int* __restrict__ coli, int* __restrict__ cnt)
{
    int e = blockIdx.x*256 + threadIdx.x;
    if (e < EE) atomicAdd(&cnt[coli[e]], 1);
}

__global__ __launch_bounds__(1024) void scan_kernel(const int* __restrict__ cnt, int* __restrict__ off)
{
    __shared__ int buf[1024];
    __shared__ int carry;
    if (threadIdx.x == 0) carry = 0;
    __syncthreads();
    for (int base = 0; base < NN; base += 1024) {
        int i = base + threadIdx.x;
        int v = (i < NN) ? cnt[i] : 0;
        buf[threadIdx.x] = v;
        __syncthreads();
#pragma unroll
        for (int ofs = 1; ofs < 1024; ofs <<= 1) {
            int t = 0;
            if (threadIdx.x >= ofs) t = buf[threadIdx.x - ofs];
            __syncthreads();
            if (threadIdx.x >= ofs) buf[threadIdx.x] += t;
            __syncthreads();
        }
        if (i < NN) off[i] = carry + buf[threadIdx.x] - v;   // exclusive
        __syncthreads();
        if (threadIdx.x == 0) carry += buf[1023];
        __syncthreads();
    }
}

__global__ __launch_bounds__(256) void scatter_kernel(
    const int* __restrict__ rowi, const int* __restrict__ coli, int* __restrict__ off,
    int* __restrict__ perm, int* __restrict__ rowp, int* __restrict__ colp)
{
    int e = blockIdx.x*256 + threadIdx.x;
    if (e >= EE) return;
    int c = coli[e];
    int p = atomicAdd(&off[c], 1);
    perm[p] = e; rowp[p] = rowi[e]; colp[p] = c;
}

// ---------- per-graph charge table: Q[g] = (charge[g]*Wc + bc) @ Wa[92:108] + ba ----------
__global__ __launch_bounds__(256) void qfeat_kernel(
    const float* __restrict__ charge, const float* __restrict__ Wc, const float* __restrict__ bc,
    const float* __restrict__ Wa, const float* __restrict__ ba, float* __restrict__ Q)
{
    int idx = blockIdx.x*256 + threadIdx.x;
    if (idx >= GG*64) return;
    int g = idx >> 6, c = idx & 63;
    float ch = charge[g];
    float acc = ba[c];
#pragma unroll
    for (int q = 0; q < CQdim; ++q) {
        float cf = ch*Wc[q] + bc[q];
        acc += cf * Wa[(FA + q)*64 + c];
    }
    Q[idx] = acc;
}

// ---------- node embedding via MFMA: h = x @ Wa[0:92] + Q[batch] ----------
__global__ __launch_bounds__(256) void embed_node_kernel(
    const float* __restrict__ x, const int* __restrict__ batch,
    const float* __restrict__ Wa, const float* __restrict__ Q,
    float* __restrict__ h)
{
    // K = 96 (92 real + 4 zero), 3 k-blocks of 32
    __shared__ unsigned short sB[3*64*40];    // 15 KB
    __shared__ unsigned short sU[4][16*104];  // 13 KB
    for (int idx = threadIdx.x; idx < 96*64; idx += 256) {
        int k = idx >> 6, n = idx & 63;
        int kb = k >> 5, q8 = k & 31;
        sB[(kb*64 + n)*40 + q8] = f2bf((k < FA) ? Wa[k*64 + n] : 0.f);
    }
    __syncthreads();

    const int lane = threadIdx.x & 63;
    const int wave = threadIdx.x >> 6;
    const int n16  = lane & 15;
    const int quad = lane >> 4;
    unsigned short* U = sU[wave];

    const int sr = lane >> 2;    // node row 0..15
    const int sseg = lane & 3;   // 24-float segment

    const int numTiles = NN >> 4;   // 3125 exactly
    for (int tile = blockIdx.x*4 + wave; tile < numTiles; tile += gridDim.x*4) {
        const int base = tile << 4;
        // stage 16x92 fp32 x rows -> bf16 U (pad to 96)
        {
            const float* src = &x[(size_t)(base + sr)*FA];
#pragma unroll
            for (int j = 0; j < 6; ++j) {
                int c0 = sseg*24 + j*4;
                ushort4 o = {0,0,0,0};
                if (c0 + 4 <= FA) {
                    float4 f = *(const float4*)&src[c0];
                    o.x = f2bf(f.x); o.y = f2bf(f.y); o.z = f2bf(f.z); o.w = f2bf(f.w);
                }
                *(ushort4*)&U[sr*104 + c0] = o;
            }
        }
        __builtin_amdgcn_wave_barrier();

        short8 a0 = *(const short8*)&U[n16*104 + 0*32 + quad*8];
        short8 a1 = *(const short8*)&U[n16*104 + 1*32 + quad*8];
        short8 a2 = *(const short8*)&U[n16*104 + 2*32 + quad*8];

        int bnode[4];
#pragma unroll
        for (int r = 0; r < 4; ++r) bnode[r] = batch[base + quad*4 + r];

        f32x4 zero = {0.f, 0.f, 0.f, 0.f};
#pragma unroll
        for (int nt = 0; nt < 4; ++nt) {
            f32x4 acc = zero;
            short8 b0 = *(const short8*)&sB[(0*64 + nt*16 + n16)*40 + quad*8];
            short8 b1 = *(const short8*)&sB[(1*64 + nt*16 + n16)*40 + quad*8];
            short8 b2 = *(const short8*)&sB[(2*64 + nt*16 + n16)*40 + quad*8];
            acc = __builtin_amdgcn_mfma_f32_16x16x32_bf16(a0, b0, acc, 0,0,0);
            acc = __builtin_amdgcn_mfma_f32_16x16x32_bf16(a1, b1, acc, 0,0,0);
            acc = __builtin_amdgcn_mfma_f32_16x16x32_bf16(a2, b2, acc, 0,0,0);
#pragma unroll
            for (int r = 0; r < 4; ++r) {
                int c = nt*16 + n16;
                h[(size_t)(base + quad*4 + r)*64 + c] = acc[r] + Q[bnode[r]*64 + c];
            }
        }
        __builtin_amdgcn_wave_barrier();
    }
}

// ---------- edge embedding via MFMA (permuted gather, bf16 output) ----------
__global__ __launch_bounds__(256) void embed_edge_kernel(
    const float* __restrict__ eattr, const int* __restrict__ perm,
    const float* __restrict__ Wb, const float* __restrict__ bbond,
    unsigned short* __restrict__ ea)
{
    // K = 64 (41 real + 23 zero), 2 k-blocks
    __shared__ unsigned short sB[2*64*40];   // 10 KB
    __shared__ unsigned short sU[4][16*72];  // 9 KB
    for (int idx = threadIdx.x; idx < 64*64; idx += 256) {
        int k = idx >> 6, n = idx & 63;
        int kb = k >> 5, q8 = k & 31;
        sB[(kb*64 + n)*40 + q8] = f2bf((k < FB) ? Wb[k*64 + n] : 0.f);
    }
    __syncthreads();

    const int lane = threadIdx.x & 63;
    const int wave = threadIdx.x >> 6;
    const int n16  = lane & 15;
    const int quad = lane >> 4;
    unsigned short* U = sU[wave];

    float bbv[4];
#pragma unroll
    for (int nt = 0; nt < 4; ++nt) bbv[nt] = bbond[nt*16 + n16];

    const int sr = lane >> 2;
    const int sseg = lane & 3;

    const int numTiles = EE >> 4;
    for (int tile = blockIdx.x*4 + wave; tile < numTiles; tile += gridDim.x*4) {
        const int base = tile << 4;
        int e = perm[base + sr];
        const float* srcrow = &eattr[(size_t)e*FB];
#pragma unroll
        for (int j = 0; j < 4; ++j) {
            int c0 = sseg*16 + j*4;
            ushort4 o = {0,0,0,0};
            if (c0 < FB) {
                o.x = f2bf(srcrow[c0]);
                if (c0+1 < FB) o.y = f2bf(srcrow[c0+1]);
                if (c0+2 < FB) o.z = f2bf(srcrow[c0+2]);
                if (c0+3 < FB) o.w = f2bf(srcrow[c0+3]);
            }
            *(ushort4*)&U[sr*72 + c0] = o;
        }
        __builtin_amdgcn_wave_barrier();

        short8 a0 = *(const short8*)&U[n16*72 + 0*32 + quad*8];
        short8 a1 = *(const short8*)&U[n16*72 + 1*32 + quad*8];
        f32x4 zero = {0.f, 0.f, 0.f, 0.f};
#pragma unroll
        for (int nt = 0; nt < 4; ++nt) {
            f32x4 acc = zero;
            short8 b0 = *(const short8*)&sB[(0*64 + nt*16 + n16)*40 + quad*8];
            short8 b1 = *(const short8*)&sB[(1*64 + nt*16 + n16)*40 + quad*8];
            acc = __builtin_amdgcn_mfma_f32_16x16x32_bf16(a0, b0, acc, 0,0,0);
            acc = __builtin_amdgcn_mfma_f32_16x16x32_bf16(a1, b1, acc, 0,0,0);
#pragma unroll
            for (int r = 0; r < 4; ++r)
                ea[(size_t)(base + quad*4 + r)*64 + nt*16 + n16] = f2bf(acc[r] + bbv[nt]);
        }
        __builtin_amdgcn_wave_barrier();
    }
}

// ---------- per-layer node precompute via MFMA ----------
__global__ __launch_bounds__(256) void precompute_kernel(
    const float* __restrict__ h,
    const float* __restrict__ W1, const float* __restrict__ W2, const float* __restrict__ W3,
    const float* __restrict__ b1, const float* __restrict__ b3,
    float* __restrict__ P1, float* __restrict__ P2, float* __restrict__ P3)
{
    __shared__ unsigned short sB[3*2*64*40];     // 30 KB
    __shared__ unsigned short sU[4][16*72];      // 9 KB
    for (int idx = threadIdx.x; idx < 3*64*64; idx += 256) {
        int mat = idx >> 12;
        int rem = idx & 4095;
        int k = rem >> 6, n = rem & 63;
        int kb = k >> 5, q8 = k & 31;
        const float* W = (mat==0) ? W1 : (mat==1) ? W2 : W3;
        sB[((mat*2 + kb)*64 + n)*40 + q8] = f2bf(W[k*64 + n]);
    }
    __syncthreads();

    const int lane = threadIdx.x & 63;
    const int wave = threadIdx.x >> 6;
    const int n16  = lane & 15;
    const int quad = lane >> 4;
    unsigned short* U = sU[wave];

    float b1v[4], b3v[4];
#pragma unroll
    for (int nt = 0; nt < 4; ++nt) { b1v[nt] = b1[nt*16 + n16]; b3v[nt] = b3[nt*16 + n16]; }

    const int sr = lane >> 2;
    const int sseg = lane & 3;

    const int numTiles = NN >> 4;
    for (int tile = blockIdx.x*4 + wave; tile < numTiles; tile += gridDim.x*4) {
        const int base = tile << 4;
        {
            const float* src = &h[(size_t)(base + sr)*64 + sseg*16];
            float4 f0 = *(const float4*)(src);
            float4 f1 = *(const float4*)(src + 4);
            float4 f2 = *(const float4*)(src + 8);
            float4 f3 = *(const float4*)(src + 12);
            unsigned short* dst = &U[sr*72 + sseg*16];
            ushort4 o0 = { f2bf(f0.x), f2bf(f0.y), f2bf(f0.z), f2bf(f0.w) };
            ushort4 o1 = { f2bf(f1.x), f2bf(f1.y), f2bf(f1.z), f2bf(f1.w) };
            ushort4 o2 = { f2bf(f2.x), f2bf(f2.y), f2bf(f2.z), f2bf(f2.w) };
            ushort4 o3 = { f2bf(f3.x), f2bf(f3.y), f2bf(f3.z), f2bf(f3.w) };
            *(ushort4*)(dst + 0)  = o0;
            *(ushort4*)(dst + 4)  = o1;
            *(ushort4*)(dst + 8)  = o2;
            *(ushort4*)(dst + 12) = o3;
        }
        __builtin_amdgcn_wave_barrier();

        short8 a0 = *(const short8*)&U[n16*72 + 0*32 + quad*8];
        short8 a1 = *(const short8*)&U[n16*72 + 1*32 + quad*8];
        f32x4 zero = {0.f, 0.f, 0.f, 0.f};

#pragma unroll
        for (int mat = 0; mat < 3; ++mat) {
            f32x4 acc[4];
#pragma unroll
            for (int nt = 0; nt < 4; ++nt) acc[nt] = zero;
#pragma unroll
            for (int nt = 0; nt < 4; ++nt) {
                short8 b0 = *(const short8*)&sB[((mat*2 + 0)*64 + nt*16 + n16)*40 + quad*8];
                short8 bq = *(const short8*)&sB[((mat*2 + 1)*64 + nt*16 + n16)*40 + quad*8];
                acc[nt] = __builtin_amdgcn_mfma_f32_16x16x32_bf16(a0, b0, acc[nt], 0,0,0);
                acc[nt] = __builtin_amdgcn_mfma_f32_16x16x32_bf16(a1, bq, acc[nt], 0,0,0);
            }
            float* P = (mat==0) ? P1 : (mat==1) ? P2 : P3;
#pragma unroll
            for (int nt = 0; nt < 4; ++nt) {
                float bias = (mat==0) ? b1v[nt] : (mat==2) ? b3v[nt] : 0.f;
#pragma unroll
                for (int r = 0; r < 4; ++r)
                    P[(size_t)(base + quad*4 + r)*64 + nt*16 + n16] = acc[nt][r] + bias;
            }
        }
        __builtin_amdgcn_wave_barrier();
    }
}

// ---------- MFMA fused per-edge kernel over col-sorted edges ----------
__global__ __launch_bounds__(512, 2) void layer_edge_kernel(
    unsigned short* __restrict__ ea,
    const float* __restrict__ P1, const float* __restrict__ P2, const float* __restrict__ P3,
    unsigned short* __restrict__ msg,
    const int* __restrict__ rowp, const int* __restrict__ colp,
    const float* __restrict__ WA, const float* __restrict__ WB,
    const float* __restrict__ WC, const float* __restrict__ WD,
    const float* __restrict__ eb2, const float* __restrict__ nb2)
{
    __shared__ unsigned short sB[20480];          // 40 KB
    __shared__ unsigned short sU[8][16*72];       // 18 KB
    for (int idx = threadIdx.x; idx < 4*64*64; idx += 512) {
        int mat = idx >> 12;
        int rem = idx & 4095;
        int k = rem >> 6, n = rem & 63;
        int kb = k >> 5, q8 = k & 31;
        const float* W = (mat==0) ? WA : (mat==1) ? WB : (mat==2) ? WC : WD;
        sB[((mat*2 + kb)*64 + n)*40 + q8] = f2bf(W[k*64 + n]);
    }
    __syncthreads();

    const int lane = threadIdx.x & 63;
    const int wave = threadIdx.x >> 6;
    const int n16  = lane & 15;
    const int quad = lane >> 4;
    unsigned short* U = sU[wave];

    float eb2v[4], nb2v[4];
#pragma unroll
    for (int nt = 0; nt < 4; ++nt) { eb2v[nt] = eb2[nt*16 + n16]; nb2v[nt] = nb2[nt*16 + n16]; }

    const int sr = lane >> 2;
    const int sseg = lane & 3;

    const int numTiles = EE >> 4;
    for (int tile = blockIdx.x*8 + wave; tile < numTiles; tile += gridDim.x*8) {
        const int base = tile << 4;
        int rid[4], cid[4];
#pragma unroll
        for (int r = 0; r < 4; ++r) {
            rid[r] = rowp[base + quad*4 + r];
            cid[r] = colp[base + quad*4 + r];
        }
        float g12[4][4];
#pragma unroll
        for (int r = 0; r < 4; ++r)
#pragma unroll
            for (int nt = 0; nt < 4; ++nt) {
                int c = nt*16 + n16;
                g12[r][nt] = P1[(size_t)rid[r]*64 + c] + P2[(size_t)cid[r]*64 + c];
            }
        {
            const unsigned short* src = &ea[(size_t)(base + sr)*64 + sseg*16];
            uint4 q0 = *(const uint4*)(src);
            uint4 q1 = *(const uint4*)(src + 8);
            *(uint4*)&U[sr*72 + sseg*16]     = q0;
            *(uint4*)&U[sr*72 + sseg*16 + 8] = q1;
        }
        __builtin_amdgcn_wave_barrier();

        f32x4 zero = {0.f, 0.f, 0.f, 0.f};

#define RUN_MM(MAT, ACC)                                                          \
        {                                                                         \
            short8 a0 = *(const short8*)&U[n16*72 + 0*32 + quad*8];               \
            short8 a1 = *(const short8*)&U[n16*72 + 1*32 + quad*8];               \
            _Pragma("unroll")                                                     \
            for (int nt = 0; nt < 4; ++nt) {                                      \
                short8 b0 = *(const short8*)&sB[(((MAT)*2+0)*64 + nt*16 + n16)*40 + quad*8]; \
                short8 b1 = *(const short8*)&sB[(((MAT)*2+1)*64 + nt*16 + n16)*40 + quad*8]; \
                ACC[nt] = __builtin_amdgcn_mfma_f32_16x16x32_bf16(a0, b0, ACC[nt], 0,0,0);   \
                ACC[nt] = __builtin_amdgcn_mfma_f32_16x16x32_bf16(a1, b1, ACC[nt], 0,0,0);   \
            }                                                                     \
        }

        // ---- phase 1 ----
        f32x4 acc[4];
#pragma unroll
        for (int nt = 0; nt < 4; ++nt) acc[nt] = zero;
        RUN_MM(0, acc);
#pragma unroll
        for (int nt = 0; nt < 4; ++nt)
#pragma unroll
            for (int r = 0; r < 4; ++r) {
                float t = sp1(acc[nt][r] + g12[r][nt]);
                U[(quad*4 + r)*72 + nt*16 + n16] = f2bf(t);
            }
        __builtin_amdgcn_wave_barrier();

        // ---- phase 2 ----
#pragma unroll
        for (int nt = 0; nt < 4; ++nt) acc[nt] = zero;
        RUN_MM(1, acc);
#pragma unroll
        for (int nt = 0; nt < 4; ++nt)
#pragma unroll
            for (int r = 0; r < 4; ++r) {
                float v = acc[nt][r] + eb2v[nt];
                unsigned short bv = f2bf(v);
                ea[(size_t)(base + quad*4 + r)*64 + nt*16 + n16] = bv;
                U[(quad*4 + r)*72 + nt*16 + n16] = bv;
            }
        float g3[4][4];
#pragma unroll
        for (int r = 0; r < 4; ++r)
#pragma unroll
            for (int nt = 0; nt < 4; ++nt)
                g3[r][nt] = P3[(size_t)rid[r]*64 + nt*16 + n16];
        __builtin_amdgcn_wave_barrier();

        // ---- phase 3 ----
#pragma unroll
        for (int nt = 0; nt < 4; ++nt) acc[nt] = zero;
        RUN_MM(2, acc);
#pragma unroll
        for (int nt = 0; nt < 4; ++nt)
#pragma unroll
            for (int r = 0; r < 4; ++r) {
                float t = sp1(acc[nt][r] + g3[r][nt]);
                U[(quad*4 + r)*72 + nt*16 + n16] = f2bf(t);
            }
        __builtin_amdgcn_wave_barrier();

        // ---- phase 4 ----
#pragma unroll
        for (int nt = 0; nt < 4; ++nt) acc[nt] = zero;
        RUN_MM(3, acc);
#pragma unroll
        for (int nt = 0; nt < 4; ++nt)
#pragma unroll
            for (int r = 0; r < 4; ++r) {
                float v = acc[nt][r] + nb2v[nt];
                msg[(size_t)(base + quad*4 + r)*64 + nt*16 + n16] = f2bf(v);
            }
        __builtin_amdgcn_wave_barrier();
#undef RUN_MM
    }
}

// ---------- CSR segment-sum of msg -> h_new, fused BN statistics ----------
__global__ __launch_bounds__(256) void reduce_kernel(
    const unsigned short* __restrict__ msg, const int* __restrict__ offi,
    float* __restrict__ h_new, float* __restrict__ stats)
{
    const int t = threadIdx.x;
    const int nl = t >> 4;
    const int n  = blockIdx.x*16 + nl;
    const int c0 = (t & 15)*4;
    float a0=0.f, a1=0.f, a2=0.f, a3=0.f;
    if (n < NN) {
        int s = (n == 0) ? 0 : offi[n-1];
        int e = offi[n];
        for (int p = s; p < e; ++p) {
            uint2 q = *(const uint2*)&msg[(size_t)p*64 + c0];
            a0 += bf2f((unsigned short)(q.x & 0xffff));
            a1 += bf2f((unsigned short)(q.x >> 16));
            a2 += bf2f((unsigned short)(q.y & 0xffff));
            a3 += bf2f((unsigned short)(q.y >> 16));
        }
        *(float4*)&h_new[(size_t)n*64 + c0] = make_float4(a0,a1,a2,a3);
    }
    __shared__ float Ss[16][64];
    __shared__ float Sq[16][64];
    Ss[nl][c0+0]=a0; Ss[nl][c0+1]=a1; Ss[nl][c0+2]=a2; Ss[nl][c0+3]=a3;
    Sq[nl][c0+0]=a0*a0; Sq[nl][c0+1]=a1*a1; Sq[nl][c0+2]=a2*a2; Sq[nl][c0+3]=a3*a3;
    __syncthreads();
    if (t < 64) {
        float s = 0.f, q = 0.f;
#pragma unroll
        for (int r = 0; r < 16; ++r) { s += Ss[r][t]; q += Sq[r][t]; }
        atomAddF(&stats[t], s);
        atomAddF(&stats[64 + t], q);
    }
}

// ---------- bn apply + softplus + residual ----------
__global__ __launch_bounds__(256) void bn_apply_kernel(
    const float* __restrict__ hn, float* __restrict__ h,
    const float* __restrict__ stats, const float* __restrict__ gamma, const float* __restrict__ beta)
{
    size_t idx = (size_t)blockIdx.x*256 + threadIdx.x;
    if (idx >= (size_t)NN*16) return;
    int c0 = (int)(idx & 15) << 2;
    float4 v = ((const float4*)hn)[idx];
    float4 r = ((const float4*)h)[idx];
    float vv[4] = {v.x, v.y, v.z, v.w};
    float rr[4] = {r.x, r.y, r.z, r.w};
    float oo[4];
    const float invN = 1.0f / (float)NN;
#pragma unroll
    for (int c = 0; c < 4; ++c) {
        int col = c0 + c;
        float mu  = stats[col] * invN;
        float var = stats[64+col] * invN - mu*mu;
        float is  = rsqrtf(var + EPSBN);
        float nv  = (vv[c] - mu) * is * gamma[col] + beta[col];
        oo[c] = sp1(nv) + rr[c];
    }
    ((float4*)h)[idx] = make_float4(oo[0], oo[1], oo[2], oo[3]);
}

// ---------- global mean pool (batch sorted -> run-accumulate) ----------
__global__ __launch_bounds__(256) void pool_kernel(
    const float* __restrict__ h, const int* __restrict__ batch,
    float* __restrict__ gsum, float* __restrict__ gcnt)
{
    const int col = threadIdx.x & 63, rg = threadIdx.x >> 6;
    int n0 = blockIdx.x*1024 + rg*256;
    if (n0 >= NN) return;
    int n1 = n0 + 256; if (n1 > NN) n1 = NN;
    float s = 0.f;
    int cur = batch[n0];
    int cnt = 0;
    for (int n = n0; n < n1; ++n) {
        int g = batch[n];
        if (g != cur) {
            atomAddF(&gsum[cur*64 + col], s);
            if (col == 0) atomAddF(&gcnt[cur], (float)cnt);
            s = 0.f; cnt = 0; cur = g;
        }
        s += h[(size_t)n*64 + col];
        ++cnt;
    }
    atomAddF(&gsum[cur*64 + col], s);
    if (col == 0) atomAddF(&gcnt[cur], (float)cnt);
}

// ---------- predictor MLP ----------
__global__ __launch_bounds__(128) void predictor_kernel(
    const float* __restrict__ gsum, const float* __restrict__ gcnt,
    const float* __restrict__ W1, const float* __restrict__ b1,
    const float* __restrict__ W2, const float* __restrict__ b2,
    const float* __restrict__ W3, const float* __restrict__ b3,
    float* __restrict__ out)
{
    int g = blockIdx.x, t = threadIdx.x;
    __shared__ float gr[64];
    __shared__ float z1[128];
    __shared__ float z2[128];
    __shared__ float red[128];
    if (t < 64) gr[t] = gsum[g*64 + t] / fmaxf(gcnt[g], 1.0f);
    __syncthreads();
    float s = b1[t];
    for (int k = 0; k < 64; ++k) s += gr[k] * W1[k*128 + t];
    z1[t] = sp1(s);
    __syncthreads();
    s = b2[t];
    for (int k = 0; k < 128; ++k) s += z1[k] * W2[k*128 + t];
    z2[t] = sp1(s);
    __syncthreads();
    red[t] = z2[t] * W3[t];
    __syncthreads();
    for (int off = 64; off > 0; off >>= 1) {
        if (t < off) red[t] += red[t + off];
        __syncthreads();
    }
    if (t == 0) out[g] = red[0] + b3[0];
}

// ---------- launch ----------
extern "C" void kernel_launch(void* const* d_in, const int* in_sizes, int n_in,
                              void* d_out, int out_size, void* d_ws, size_t ws_size,
                              hipStream_t stream)
{
    const float* x         = (const float*)d_in[0];
    const float* edge_attr = (const float*)d_in[1];
    const float* charge    = (const float*)d_in[2];
    const int*   edge_index= (const int*)d_in[3];
    const int*   batch     = (const int*)d_in[4];
    const float* W_charge  = (const float*)d_in[5];
    const float* b_charge  = (const float*)d_in[6];
    const float* W_atom    = (const float*)d_in[7];
    const float* b_atom    = (const float*)d_in[8];
    const float* W_bond    = (const float*)d_in[9];
    const float* b_bond    = (const float*)d_in[10];
    const float* nu_W1     = (const float*)d_in[11];
    const float* nu_b1     = (const float*)d_in[12];
    const float* nu_W2     = (const float*)d_in[13];
    const float* nu_b2     = (const float*)d_in[14];
    const float* eu_W1     = (const float*)d_in[15];
    const float* eu_b1     = (const float*)d_in[16];
    const float* eu_W2     = (const float*)d_in[17];
    const float* eu_b2     = (const float*)d_in[18];
    const float* bn_gamma  = (const float*)d_in[19];
    const float* bn_beta   = (const float*)d_in[20];
    const float* p_W1      = (const float*)d_in[21];
    const float* p_b1      = (const float*)d_in[22];
    const float* p_W2      = (const float*)d_in[23];
    const float* p_b2      = (const float*)d_in[24];
    const float* p_W3      = (const float*)d_in[25];
    const float* p_b3      = (const float*)d_in[26];

    const int* rowi = edge_index;
    const int* coli = edge_index + EE;

    char* ws = (char*)d_ws;
    unsigned short* ea  = (unsigned short*)ws;  ws += (size_t)EE*64*2;
    unsigned short* msg = (unsigned short*)ws;  ws += (size_t)EE*64*2;
    float* h     = (float*)ws;                  ws += (size_t)NN*64*4;
    float* P1    = (float*)ws;                  ws += (size_t)NN*64*4;
    float* P2    = (float*)ws;                  ws += (size_t)NN*64*4;
    float* P3    = (float*)ws;                  ws += (size_t)NN*64*4;
    float* h_new = (float*)ws;                  ws += (size_t)NN*64*4;
    float* gsum  = (float*)ws;                  ws += (size_t)GG*64*4;
    float* gcnt  = (float*)ws;                  ws += (size_t)GG*4;
    float* stats = (float*)ws;                  ws += 128*4;
    float* Qtab  = (float*)ws;                  ws += (size_t)GG*64*4;
    int*   cnt   = (int*)ws;                    ws += (size_t)NN*4;
    int*   offi  = (int*)ws;                    ws += (size_t)NN*4;
    int*   perm  = (int*)ws;                    ws += (size_t)EE*4;
    int*   rowp  = (int*)ws;                    ws += (size_t)EE*4;
    int*   colp  = (int*)ws;                    ws += (size_t)EE*4;

    float* out = (float*)d_out;

    hipMemsetAsync(cnt, 0, (size_t)NN*4, stream);
    hist_kernel<<<(EE + 255)/256, 256, 0, stream>>>(coli, cnt);
    scan_kernel<<<1, 1024, 0, stream>>>(cnt, offi);
    scatter_kernel<<<(EE + 255)/256, 256, 0, stream>>>(rowi, coli, offi, perm, rowp, colp);

    qfeat_kernel<<<(GG*64 + 255)/256, 256, 0, stream>>>(charge, W_charge, b_charge, W_atom, b_atom, Qtab);
    embed_node_kernel<<<512, 256, 0, stream>>>(x, batch, W_atom, Qtab, h);
    embed_edge_kernel<<<512, 256, 0, stream>>>(edge_attr, perm, W_bond, b_bond, ea);
    hipMemsetAsync(gsum, 0, (size_t)(GG*64 + GG)*4, stream);

    for (int l = 0; l < NL; ++l) {
        const float* euW1 = eu_W1 + (size_t)l*192*64;
        const float* nuW1 = nu_W1 + (size_t)l*128*64;
        precompute_kernel<<<256, 256, 0, stream>>>(
            h, euW1, euW1 + 64*64, nuW1,
            eu_b1 + l*64, nu_b1 + l*64, P1, P2, P3);
        hipMemsetAsync(stats, 0, 128*4, stream);
        layer_edge_kernel<<<512, 512, 0, stream>>>(
            ea, P1, P2, P3, msg, rowp, colp,
            euW1 + 128*64, eu_W2 + (size_t)l*64*64,
            nuW1 + 64*64,  nu_W2 + (size_t)l*64*64,
            eu_b2 + l*64, nu_b2 + l*64);
        reduce_kernel<<<(NN + 15)/16, 256, 0, stream>>>(msg, offi, h_new, stats);
        bn_apply_kernel<<<(NN*16 + 255)/256, 256, 0, stream>>>(
            h_new, h, stats, bn_gamma + l*64, bn_beta + l*64);
    }

    pool_kernel<<<(NN + 1023)/1024, 256, 0, stream>>>(h, batch, gsum, gcnt);
    predictor_kernel<<<GG, 128, 0, stream>>>(gsum, gcnt, p_W1, p_b1, p_W2, p_b2, p_W3, p_b3, out);
}

// Round 6
// 1078.357 us; speedup vs baseline: 6.2558x; 1.4086x over previous
//
#include <hip/hip_runtime.h>
#include <cmath>

#define NN 50000
#define EE 500000
#define GG 256
#define FA 92
#define FB 41
#define DD 64
#define HH 128
#define CQdim 16
#define NL 3
#define EPSBN 1e-5f

// Global column permutation: activations stored with col' = PI(col).
// PI(c)  = (c&15)*4 + (c>>4)   : lane n16's 4 values (true cols n16+16*nt) are contiguous.
// PIINV(c') = (c'&3)*16 + (c'>>2)
#define PIINV(cp) ((((cp) & 3) << 4) | ((cp) >> 2))

typedef __attribute__((ext_vector_type(8))) short short8;
typedef __attribute__((ext_vector_type(4))) float f32x4;

// ---------- helpers ----------
__device__ __forceinline__ float sp1(float x) {
    // softplus with native exp/log (v_exp_f32 / v_log_f32)
    float e = __expf(-fabsf(x));
    return fmaxf(x, 0.0f) + __logf(1.0f + e);
}
__device__ __forceinline__ void atomAddF(float* p, float v) {
    unsafeAtomicAdd(p, v);
}
__device__ __forceinline__ unsigned short f2bf(float f) {
    unsigned int u = __float_as_uint(f);
    unsigned int r = u + 0x7FFFu + ((u >> 16) & 1u);
    return (unsigned short)(r >> 16);
}
__device__ __forceinline__ float bf2f(unsigned short s) {
    return __uint_as_float(((unsigned int)s) << 16);
}

// ---------- counting sort of edges by col ----------
__global__ __launch_bounds__(256) void hist_kernel(const int* __restrict__ coli, int* __restrict__ cnt)
{
    int e = blockIdx.x*256 + threadIdx.x;
    if (e < EE) atomicAdd(&cnt[coli[e]], 1);
}

__global__ __launch_bounds__(1024) void scan_kernel(const int* __restrict__ cnt, int* __restrict__ off)
{
    __shared__ int buf[1024];
    __shared__ int carry;
    if (threadIdx.x == 0) carry = 0;
    __syncthreads();
    for (int base = 0; base < NN; base += 1024) {
        int i = base + threadIdx.x;
        int v = (i < NN) ? cnt[i] : 0;
        buf[threadIdx.x] = v;
        __syncthreads();
#pragma unroll
        for (int ofs = 1; ofs < 1024; ofs <<= 1) {
            int t = 0;
            if (threadIdx.x >= ofs) t = buf[threadIdx.x - ofs];
            __syncthreads();
            if (threadIdx.x >= ofs) buf[threadIdx.x] += t;
            __syncthreads();
        }
        if (i < NN) off[i] = carry + buf[threadIdx.x] - v;   // exclusive
        __syncthreads();
        if (threadIdx.x == 0) carry += buf[1023];
        __syncthreads();
    }
}

__global__ __launch_bounds__(256) void scatter_kernel(
    const int* __restrict__ rowi, const int* __restrict__ coli, int* __restrict__ off,
    int* __restrict__ perm, int* __restrict__ rowp, int* __restrict__ colp)
{
    int e = blockIdx.x*256 + threadIdx.x;
    if (e >= EE) return;
    int c = coli[e];
    int p = atomicAdd(&off[c], 1);
    perm[p] = e; rowp[p] = rowi[e]; colp[p] = c;
}

// ---------- per-graph charge table (PI-stored): Q[g, PI(c)] = (charge[g]*Wc+bc)@Wa[92:108,c] + ba[c] ----------
__global__ __launch_bounds__(256) void qfeat_kernel(
    const float* __restrict__ charge, const float* __restrict__ Wc, const float* __restrict__ bc,
    const float* __restrict__ Wa, const float* __restrict__ ba, float* __restrict__ Q)
{
    int idx = blockIdx.x*256 + threadIdx.x;
    if (idx >= GG*64) return;
    int g = idx >> 6, cp = idx & 63;
    int c = PIINV(cp);
    float ch = charge[g];
    float acc = ba[c];
#pragma unroll
    for (int q = 0; q < CQdim; ++q) {
        float cf = ch*Wc[q] + bc[q];
        acc += cf * Wa[(FA + q)*64 + c];
    }
    Q[idx] = acc;
}

// ---------- node embedding via MFMA: h(PI) = x @ Wa[0:92] + Q[batch] ----------
__global__ __launch_bounds__(256) void embed_node_kernel(
    const float* __restrict__ x, const int* __restrict__ batch,
    const float* __restrict__ Wa, const float* __restrict__ Q,
    float* __restrict__ h)
{
    // K = 96 (92 real + 4 zero), raw input k (no remap)
    __shared__ unsigned short sB[3*64*40];    // 15 KB
    __shared__ unsigned short sU[4][16*104];  // 13 KB
    for (int idx = threadIdx.x; idx < 96*64; idx += 256) {
        int k = idx >> 6, n = idx & 63;
        int kb = k >> 5, q8 = k & 31;
        sB[(kb*64 + n)*40 + q8] = f2bf((k < FA) ? Wa[k*64 + n] : 0.f);
    }
    __syncthreads();

    const int lane = threadIdx.x & 63;
    const int wave = threadIdx.x >> 6;
    const int n16  = lane & 15;
    const int quad = lane >> 4;
    unsigned short* U = sU[wave];

    const int sr = lane >> 2;
    const int sseg = lane & 3;

    const int numTiles = NN >> 4;
    for (int tile = blockIdx.x*4 + wave; tile < numTiles; tile += gridDim.x*4) {
        const int base = tile << 4;
        {
            const float* src = &x[(size_t)(base + sr)*FA];
#pragma unroll
            for (int j = 0; j < 6; ++j) {
                int c0 = sseg*24 + j*4;
                ushort4 o = {0,0,0,0};
                if (c0 + 4 <= FA) {
                    float4 f = *(const float4*)&src[c0];
                    o.x = f2bf(f.x); o.y = f2bf(f.y); o.z = f2bf(f.z); o.w = f2bf(f.w);
                }
                *(ushort4*)&U[sr*104 + c0] = o;
            }
        }
        __builtin_amdgcn_wave_barrier();

        short8 a0 = *(const short8*)&U[n16*104 + 0*32 + quad*8];
        short8 a1 = *(const short8*)&U[n16*104 + 1*32 + quad*8];
        short8 a2 = *(const short8*)&U[n16*104 + 2*32 + quad*8];

        int bnode[4];
#pragma unroll
        for (int r = 0; r < 4; ++r) bnode[r] = batch[base + quad*4 + r];

        f32x4 zero = {0.f, 0.f, 0.f, 0.f};
        f32x4 accv[4];
#pragma unroll
        for (int nt = 0; nt < 4; ++nt) {
            f32x4 acc = zero;
            short8 b0 = *(const short8*)&sB[(0*64 + nt*16 + n16)*40 + quad*8];
            short8 b1 = *(const short8*)&sB[(1*64 + nt*16 + n16)*40 + quad*8];
            short8 b2 = *(const short8*)&sB[(2*64 + nt*16 + n16)*40 + quad*8];
            acc = __builtin_amdgcn_mfma_f32_16x16x32_bf16(a0, b0, acc, 0,0,0);
            acc = __builtin_amdgcn_mfma_f32_16x16x32_bf16(a1, b1, acc, 0,0,0);
            acc = __builtin_amdgcn_mfma_f32_16x16x32_bf16(a2, b2, acc, 0,0,0);
            accv[nt] = acc;
        }
#pragma unroll
        for (int r = 0; r < 4; ++r) {
            float4 qv = *(const float4*)&Q[bnode[r]*64 + n16*4];
            float4 o = make_float4(accv[0][r]+qv.x, accv[1][r]+qv.y, accv[2][r]+qv.z, accv[3][r]+qv.w);
            *(float4*)&h[(size_t)(base + quad*4 + r)*64 + n16*4] = o;
        }
        __builtin_amdgcn_wave_barrier();
    }
}

// ---------- edge embedding via MFMA (permuted gather, PI-stored bf16 output) ----------
__global__ __launch_bounds__(256) void embed_edge_kernel(
    const float* __restrict__ eattr, const int* __restrict__ perm,
    const float* __restrict__ Wb, const float* __restrict__ bbond,
    unsigned short* __restrict__ ea)
{
    __shared__ unsigned short sB[2*64*40];   // 10 KB
    __shared__ unsigned short sU[4][16*72];  // 9 KB
    for (int idx = threadIdx.x; idx < 64*64; idx += 256) {
        int k = idx >> 6, n = idx & 63;
        int kb = k >> 5, q8 = k & 31;
        sB[(kb*64 + n)*40 + q8] = f2bf((k < FB) ? Wb[k*64 + n] : 0.f);
    }
    __syncthreads();

    const int lane = threadIdx.x & 63;
    const int wave = threadIdx.x >> 6;
    const int n16  = lane & 15;
    const int quad = lane >> 4;
    unsigned short* U = sU[wave];

    float bbv[4];
#pragma unroll
    for (int nt = 0; nt < 4; ++nt) bbv[nt] = bbond[nt*16 + n16];

    const int sr = lane >> 2;
    const int sseg = lane & 3;

    const int numTiles = EE >> 4;
    for (int tile = blockIdx.x*4 + wave; tile < numTiles; tile += gridDim.x*4) {
        const int base = tile << 4;
        int e = perm[base + sr];
        const float* srcrow = &eattr[(size_t)e*FB];
#pragma unroll
        for (int j = 0; j < 4; ++j) {
            int c0 = sseg*16 + j*4;
            ushort4 o = {0,0,0,0};
            if (c0 < FB) {
                o.x = f2bf(srcrow[c0]);
                if (c0+1 < FB) o.y = f2bf(srcrow[c0+1]);
                if (c0+2 < FB) o.z = f2bf(srcrow[c0+2]);
                if (c0+3 < FB) o.w = f2bf(srcrow[c0+3]);
            }
            *(ushort4*)&U[sr*72 + c0] = o;
        }
        __builtin_amdgcn_wave_barrier();

        short8 a0 = *(const short8*)&U[n16*72 + 0*32 + quad*8];
        short8 a1 = *(const short8*)&U[n16*72 + 1*32 + quad*8];
        f32x4 zero = {0.f, 0.f, 0.f, 0.f};
        f32x4 accv[4];
#pragma unroll
        for (int nt = 0; nt < 4; ++nt) {
            f32x4 acc = zero;
            short8 b0 = *(const short8*)&sB[(0*64 + nt*16 + n16)*40 + quad*8];
            short8 b1 = *(const short8*)&sB[(1*64 + nt*16 + n16)*40 + quad*8];
            acc = __builtin_amdgcn_mfma_f32_16x16x32_bf16(a0, b0, acc, 0,0,0);
            acc = __builtin_amdgcn_mfma_f32_16x16x32_bf16(a1, b1, acc, 0,0,0);
            accv[nt] = acc;
        }
#pragma unroll
        for (int r = 0; r < 4; ++r) {
            ushort4 o;
            o.x = f2bf(accv[0][r] + bbv[0]);
            o.y = f2bf(accv[1][r] + bbv[1]);
            o.z = f2bf(accv[2][r] + bbv[2]);
            o.w = f2bf(accv[3][r] + bbv[3]);
            *(ushort4*)&ea[(size_t)(base + quad*4 + r)*64 + n16*4] = o;
        }
        __builtin_amdgcn_wave_barrier();
    }
}

// ---------- per-layer node precompute via MFMA (h PI-stored in, P PI-stored out) ----------
__global__ __launch_bounds__(256) void precompute_kernel(
    const float* __restrict__ h,
    const float* __restrict__ W1, const float* __restrict__ W2, const float* __restrict__ W3,
    const float* __restrict__ b1, const float* __restrict__ b3,
    float* __restrict__ P1, float* __restrict__ P2, float* __restrict__ P3)
{
    __shared__ unsigned short sB[3*2*64*40];     // 30 KB
    __shared__ unsigned short sU[4][16*72];      // 9 KB
    for (int idx = threadIdx.x; idx < 3*64*64; idx += 256) {
        int mat = idx >> 12;
        int rem = idx & 4095;
        int kp = rem >> 6, n = rem & 63;
        int kt = PIINV(kp);                      // input h is PI-stored
        int kb = kp >> 5, q8 = kp & 31;
        const float* W = (mat==0) ? W1 : (mat==1) ? W2 : W3;
        sB[((mat*2 + kb)*64 + n)*40 + q8] = f2bf(W[kt*64 + n]);
    }
    __syncthreads();

    const int lane = threadIdx.x & 63;
    const int wave = threadIdx.x >> 6;
    const int n16  = lane & 15;
    const int quad = lane >> 4;
    unsigned short* U = sU[wave];

    float b1v[4], b3v[4];
#pragma unroll
    for (int nt = 0; nt < 4; ++nt) { b1v[nt] = b1[nt*16 + n16]; b3v[nt] = b3[nt*16 + n16]; }

    const int sr = lane >> 2;
    const int sseg = lane & 3;

    const int numTiles = NN >> 4;
    for (int tile = blockIdx.x*4 + wave; tile < numTiles; tile += gridDim.x*4) {
        const int base = tile << 4;
        {
            const float* src = &h[(size_t)(base + sr)*64 + sseg*16];
            float4 f0 = *(const float4*)(src);
            float4 f1 = *(const float4*)(src + 4);
            float4 f2 = *(const float4*)(src + 8);
            float4 f3 = *(const float4*)(src + 12);
            unsigned short* dst = &U[sr*72 + sseg*16];
            ushort4 o0 = { f2bf(f0.x), f2bf(f0.y), f2bf(f0.z), f2bf(f0.w) };
            ushort4 o1 = { f2bf(f1.x), f2bf(f1.y), f2bf(f1.z), f2bf(f1.w) };
            ushort4 o2 = { f2bf(f2.x), f2bf(f2.y), f2bf(f2.z), f2bf(f2.w) };
            ushort4 o3 = { f2bf(f3.x), f2bf(f3.y), f2bf(f3.z), f2bf(f3.w) };
            *(ushort4*)(dst + 0)  = o0;
            *(ushort4*)(dst + 4)  = o1;
            *(ushort4*)(dst + 8)  = o2;
            *(ushort4*)(dst + 12) = o3;
        }
        __builtin_amdgcn_wave_barrier();

        short8 a0 = *(const short8*)&U[n16*72 + 0*32 + quad*8];
        short8 a1 = *(const short8*)&U[n16*72 + 1*32 + quad*8];
        f32x4 zero = {0.f, 0.f, 0.f, 0.f};

#pragma unroll
        for (int mat = 0; mat < 3; ++mat) {
            f32x4 acc[4];
#pragma unroll
            for (int nt = 0; nt < 4; ++nt) acc[nt] = zero;
#pragma unroll
            for (int nt = 0; nt < 4; ++nt) {
                short8 b0 = *(const short8*)&sB[((mat*2 + 0)*64 + nt*16 + n16)*40 + quad*8];
                short8 bq = *(const short8*)&sB[((mat*2 + 1)*64 + nt*16 + n16)*40 + quad*8];
                acc[nt] = __builtin_amdgcn_mfma_f32_16x16x32_bf16(a0, b0, acc[nt], 0,0,0);
                acc[nt] = __builtin_amdgcn_mfma_f32_16x16x32_bf16(a1, bq, acc[nt], 0,0,0);
            }
            float* P = (mat==0) ? P1 : (mat==1) ? P2 : P3;
#pragma unroll
            for (int r = 0; r < 4; ++r) {
                float4 o;
                if (mat==0)      o = make_float4(acc[0][r]+b1v[0], acc[1][r]+b1v[1], acc[2][r]+b1v[2], acc[3][r]+b1v[3]);
                else if (mat==2) o = make_float4(acc[0][r]+b3v[0], acc[1][r]+b3v[1], acc[2][r]+b3v[2], acc[3][r]+b3v[3]);
                else             o = make_float4(acc[0][r], acc[1][r], acc[2][r], acc[3][r]);
                *(float4*)&P[(size_t)(base + quad*4 + r)*64 + n16*4] = o;
            }
        }
        __builtin_amdgcn_wave_barrier();
    }
}

// ---------- MFMA fused per-edge kernel over col-sorted edges (all tensors PI-stored) ----------
__global__ __launch_bounds__(512, 2) void layer_edge_kernel(
    unsigned short* __restrict__ ea,
    const float* __restrict__ P1, const float* __restrict__ P2, const float* __restrict__ P3,
    unsigned short* __restrict__ msg,
    const int* __restrict__ rowp, const int* __restrict__ colp,
    const float* __restrict__ WA, const float* __restrict__ WB,
    const float* __restrict__ WC, const float* __restrict__ WD,
    const float* __restrict__ eb2, const float* __restrict__ nb2)
{
    __shared__ unsigned short sB[20480];          // 40 KB
    __shared__ unsigned short sU[8][16*72];       // 18 KB
    for (int idx = threadIdx.x; idx < 4*64*64; idx += 512) {
        int mat = idx >> 12;
        int rem = idx & 4095;
        int kp = rem >> 6, n = rem & 63;
        int kt = PIINV(kp);                       // all inputs PI-stored
        int kb = kp >> 5, q8 = kp & 31;
        const float* W = (mat==0) ? WA : (mat==1) ? WB : (mat==2) ? WC : WD;
        sB[((mat*2 + kb)*64 + n)*40 + q8] = f2bf(W[kt*64 + n]);
    }
    __syncthreads();

    const int lane = threadIdx.x & 63;
    const int wave = threadIdx.x >> 6;
    const int n16  = lane & 15;
    const int quad = lane >> 4;
    unsigned short* U = sU[wave];

    float eb2v[4], nb2v[4];
#pragma unroll
    for (int nt = 0; nt < 4; ++nt) { eb2v[nt] = eb2[nt*16 + n16]; nb2v[nt] = nb2[nt*16 + n16]; }

    const int sr = lane >> 2;
    const int sseg = lane & 3;

    const int numTiles = EE >> 4;
    for (int tile = blockIdx.x*8 + wave; tile < numTiles; tile += gridDim.x*8) {
        const int base = tile << 4;
        int rid[4], cid[4];
#pragma unroll
        for (int r = 0; r < 4; ++r) {
            rid[r] = rowp[base + quad*4 + r];
            cid[r] = colp[base + quad*4 + r];
        }
        // PI layout: lane's 4 bias values are one float4
        float4 g12v[4];
#pragma unroll
        for (int r = 0; r < 4; ++r) {
            float4 a = *(const float4*)&P1[(size_t)rid[r]*64 + n16*4];
            float4 b = *(const float4*)&P2[(size_t)cid[r]*64 + n16*4];
            g12v[r] = make_float4(a.x+b.x, a.y+b.y, a.z+b.z, a.w+b.w);
        }
        {
            const unsigned short* src = &ea[(size_t)(base + sr)*64 + sseg*16];
            uint4 q0 = *(const uint4*)(src);
            uint4 q1 = *(const uint4*)(src + 8);
            *(uint4*)&U[sr*72 + sseg*16]     = q0;
            *(uint4*)&U[sr*72 + sseg*16 + 8] = q1;
        }
        __builtin_amdgcn_wave_barrier();

        f32x4 zero = {0.f, 0.f, 0.f, 0.f};

#define RUN_MM(MAT, ACC)                                                          \
        {                                                                         \
            short8 a0 = *(const short8*)&U[n16*72 + 0*32 + quad*8];               \
            short8 a1 = *(const short8*)&U[n16*72 + 1*32 + quad*8];               \
            _Pragma("unroll")                                                     \
            for (int nt = 0; nt < 4; ++nt) {                                      \
                short8 b0 = *(const short8*)&sB[(((MAT)*2+0)*64 + nt*16 + n16)*40 + quad*8]; \
                short8 b1 = *(const short8*)&sB[(((MAT)*2+1)*64 + nt*16 + n16)*40 + quad*8]; \
                ACC[nt] = __builtin_amdgcn_mfma_f32_16x16x32_bf16(a0, b0, ACC[nt], 0,0,0);   \
                ACC[nt] = __builtin_amdgcn_mfma_f32_16x16x32_bf16(a1, b1, ACC[nt], 0,0,0);   \
            }                                                                     \
        }

        // ---- phase 1: t1 = sp(P1[row]+P2[col] + ea@WA) ----
        f32x4 acc[4];
#pragma unroll
        for (int nt = 0; nt < 4; ++nt) acc[nt] = zero;
        RUN_MM(0, acc);
#pragma unroll
        for (int r = 0; r < 4; ++r) {
            ushort4 o;
            o.x = f2bf(sp1(acc[0][r] + g12v[r].x));
            o.y = f2bf(sp1(acc[1][r] + g12v[r].y));
            o.z = f2bf(sp1(acc[2][r] + g12v[r].z));
            o.w = f2bf(sp1(acc[3][r] + g12v[r].w));
            *(ushort4*)&U[(quad*4 + r)*72 + n16*4] = o;
        }
        __builtin_amdgcn_wave_barrier();

        // ---- phase 2: ea' = t1@WB + eb2 ----
#pragma unroll
        for (int nt = 0; nt < 4; ++nt) acc[nt] = zero;
        RUN_MM(1, acc);
#pragma unroll
        for (int r = 0; r < 4; ++r) {
            ushort4 o;
            o.x = f2bf(acc[0][r] + eb2v[0]);
            o.y = f2bf(acc[1][r] + eb2v[1]);
            o.z = f2bf(acc[2][r] + eb2v[2]);
            o.w = f2bf(acc[3][r] + eb2v[3]);
            *(ushort4*)&ea[(size_t)(base + quad*4 + r)*64 + n16*4] = o;
            *(ushort4*)&U[(quad*4 + r)*72 + n16*4] = o;
        }
        float4 g3v[4];
#pragma unroll
        for (int r = 0; r < 4; ++r)
            g3v[r] = *(const float4*)&P3[(size_t)rid[r]*64 + n16*4];
        __builtin_amdgcn_wave_barrier();

        // ---- phase 3: t2 = sp(P3[row] + ea'@WC) ----
#pragma unroll
        for (int nt = 0; nt < 4; ++nt) acc[nt] = zero;
        RUN_MM(2, acc);
#pragma unroll
        for (int r = 0; r < 4; ++r) {
            ushort4 o;
            o.x = f2bf(sp1(acc[0][r] + g3v[r].x));
            o.y = f2bf(sp1(acc[1][r] + g3v[r].y));
            o.z = f2bf(sp1(acc[2][r] + g3v[r].z));
            o.w = f2bf(sp1(acc[3][r] + g3v[r].w));
            *(ushort4*)&U[(quad*4 + r)*72 + n16*4] = o;
        }
        __builtin_amdgcn_wave_barrier();

        // ---- phase 4: msg = t2@WD + nb2 ----
#pragma unroll
        for (int nt = 0; nt < 4; ++nt) acc[nt] = zero;
        RUN_MM(3, acc);
#pragma unroll
        for (int r = 0; r < 4; ++r) {
            ushort4 o;
            o.x = f2bf(acc[0][r] + nb2v[0]);
            o.y = f2bf(acc[1][r] + nb2v[1]);
            o.z = f2bf(acc[2][r] + nb2v[2]);
            o.w = f2bf(acc[3][r] + nb2v[3]);
            *(ushort4*)&msg[(size_t)(base + quad*4 + r)*64 + n16*4] = o;
        }
        __builtin_amdgcn_wave_barrier();
#undef RUN_MM
    }
}

// ---------- CSR segment-sum of msg -> h_new (PI cols), fused BN statistics ----------
__global__ __launch_bounds__(256) void reduce_kernel(
    const unsigned short* __restrict__ msg, const int* __restrict__ offi,
    float* __restrict__ h_new, float* __restrict__ stats)
{
    const int t = threadIdx.x;
    const int nl = t >> 4;
    const int n  = blockIdx.x*16 + nl;
    const int c0 = (t & 15)*4;
    float a0=0.f, a1=0.f, a2=0.f, a3=0.f;
    if (n < NN) {
        int s = (n == 0) ? 0 : offi[n-1];
        int e = offi[n];
        for (int p = s; p < e; ++p) {
            uint2 q = *(const uint2*)&msg[(size_t)p*64 + c0];
            a0 += bf2f((unsigned short)(q.x & 0xffff));
            a1 += bf2f((unsigned short)(q.x >> 16));
            a2 += bf2f((unsigned short)(q.y & 0xffff));
            a3 += bf2f((unsigned short)(q.y >> 16));
        }
        *(float4*)&h_new[(size_t)n*64 + c0] = make_float4(a0,a1,a2,a3);
    }
    __shared__ float Ss[16][64];
    __shared__ float Sq[16][64];
    Ss[nl][c0+0]=a0; Ss[nl][c0+1]=a1; Ss[nl][c0+2]=a2; Ss[nl][c0+3]=a3;
    Sq[nl][c0+0]=a0*a0; Sq[nl][c0+1]=a1*a1; Sq[nl][c0+2]=a2*a2; Sq[nl][c0+3]=a3*a3;
    __syncthreads();
    if (t < 64) {
        float s = 0.f, q = 0.f;
#pragma unroll
        for (int r = 0; r < 16; ++r) { s += Ss[r][t]; q += Sq[r][t]; }
        atomAddF(&stats[t], s);
        atomAddF(&stats[64 + t], q);
    }
}

// ---------- bn apply + softplus + residual (PI cols; gamma/beta remapped) ----------
__global__ __launch_bounds__(256) void bn_apply_kernel(
    const float* __restrict__ hn, float* __restrict__ h,
    const float* __restrict__ stats, const float* __restrict__ gamma, const float* __restrict__ beta)
{
    size_t idx = (size_t)blockIdx.x*256 + threadIdx.x;
    if (idx >= (size_t)NN*16) return;
    int c0 = (int)(idx & 15) << 2;
    float4 v = ((const float4*)hn)[idx];
    float4 r = ((const float4*)h)[idx];
    float vv[4] = {v.x, v.y, v.z, v.w};
    float rr[4] = {r.x, r.y, r.z, r.w};
    float oo[4];
    const float invN = 1.0f / (float)NN;
#pragma unroll
    for (int c = 0; c < 4; ++c) {
        int col = c0 + c;              // PI-space column
        int ct  = PIINV(col);          // true column for gamma/beta
        float mu  = stats[col] * invN;
        float var = stats[64+col] * invN - mu*mu;
        float is  = rsqrtf(var + EPSBN);
        float nv  = (vv[c] - mu) * is * gamma[ct] + beta[ct];
        oo[c] = sp1(nv) + rr[c];
    }
    ((float4*)h)[idx] = make_float4(oo[0], oo[1], oo[2], oo[3]);
}

// ---------- global mean pool (batch sorted -> run-accumulate; PI cols throughout) ----------
__global__ __launch_bounds__(256) void pool_kernel(
    const float* __restrict__ h, const int* __restrict__ batch,
    float* __restrict__ gsum, float* __restrict__ gcnt)
{
    const int col = threadIdx.x & 63, rg = threadIdx.x >> 6;
    int n0 = blockIdx.x*1024 + rg*256;
    if (n0 >= NN) return;
    int n1 = n0 + 256; if (n1 > NN) n1 = NN;
    float s = 0.f;
    int cur = batch[n0];
    int cnt = 0;
    for (int n = n0; n < n1; ++n) {
        int g = batch[n];
        if (g != cur) {
            atomAddF(&gsum[cur*64 + col], s);
            if (col == 0) atomAddF(&gcnt[cur], (float)cnt);
            s = 0.f; cnt = 0; cur = g;
        }
        s += h[(size_t)n*64 + col];
        ++cnt;
    }
    atomAddF(&gsum[cur*64 + col], s);
    if (col == 0) atomAddF(&gcnt[cur], (float)cnt);
}

// ---------- predictor MLP (gsum PI-stored -> remap p_W1 rows) ----------
__global__ __launch_bounds__(128) void predictor_kernel(
    const float* __restrict__ gsum, const float* __restrict__ gcnt,
    const float* __restrict__ W1, const float* __restrict__ b1,
    const float* __restrict__ W2, const float* __restrict__ b2,
    const float* __restrict__ W3, const float* __restrict__ b3,
    float* __restrict__ out)
{
    int g = blockIdx.x, t = threadIdx.x;
    __shared__ float gr[64];
    __shared__ float z1[128];
    __shared__ float z2[128];
    __shared__ float red[128];
    if (t < 64) gr[t] = gsum[g*64 + t] / fmaxf(gcnt[g], 1.0f);
    __syncthreads();
    float s = b1[t];
#pragma unroll
    for (int k = 0; k < 64; ++k) s += gr[k] * W1[PIINV(k)*128 + t];
    z1[t] = sp1(s);
    __syncthreads();
    s = b2[t];
    for (int k = 0; k < 128; ++k) s += z1[k] * W2[k*128 + t];
    z2[t] = sp1(s);
    __syncthreads();
    red[t] = z2[t] * W3[t];
    __syncthreads();
    for (int off = 64; off > 0; off >>= 1) {
        if (t < off) red[t] += red[t + off];
        __syncthreads();
    }
    if (t == 0) out[g] = red[0] + b3[0];
}

// ---------- launch ----------
extern "C" void kernel_launch(void* const* d_in, const int* in_sizes, int n_in,
                              void* d_out, int out_size, void* d_ws, size_t ws_size,
                              hipStream_t stream)
{
    const float* x         = (const float*)d_in[0];
    const float* edge_attr = (const float*)d_in[1];
    const float* charge    = (const float*)d_in[2];
    const int*   edge_index= (const int*)d_in[3];
    const int*   batch     = (const int*)d_in[4];
    const float* W_charge  = (const float*)d_in[5];
    const float* b_charge  = (const float*)d_in[6];
    const float* W_atom    = (const float*)d_in[7];
    const float* b_atom    = (const float*)d_in[8];
    const float* W_bond    = (const float*)d_in[9];
    const float* b_bond    = (const float*)d_in[10];
    const float* nu_W1     = (const float*)d_in[11];
    const float* nu_b1     = (const float*)d_in[12];
    const float* nu_W2     = (const float*)d_in[13];
    const float* nu_b2     = (const float*)d_in[14];
    const float* eu_W1     = (const float*)d_in[15];
    const float* eu_b1     = (const float*)d_in[16];
    const float* eu_W2     = (const float*)d_in[17];
    const float* eu_b2     = (const float*)d_in[18];
    const float* bn_gamma  = (const float*)d_in[19];
    const float* bn_beta   = (const float*)d_in[20];
    const float* p_W1      = (const float*)d_in[21];
    const float* p_b1      = (const float*)d_in[22];
    const float* p_W2      = (const float*)d_in[23];
    const float* p_b2      = (const float*)d_in[24];
    const float* p_W3      = (const float*)d_in[25];
    const float* p_b3      = (const float*)d_in[26];

    const int* rowi = edge_index;
    const int* coli = edge_index + EE;

    char* ws = (char*)d_ws;
    unsigned short* ea  = (unsigned short*)ws;  ws += (size_t)EE*64*2;
    unsigned short* msg = (unsigned short*)ws;  ws += (size_t)EE*64*2;
    float* h     = (float*)ws;                  ws += (size_t)NN*64*4;
    float* P1    = (float*)ws;                  ws += (size_t)NN*64*4;
    float* P2    = (float*)ws;                  ws += (size_t)NN*64*4;
    float* P3    = (float*)ws;                  ws += (size_t)NN*64*4;
    float* h_new = (float*)ws;                  ws += (size_t)NN*64*4;
    float* gsum  = (float*)ws;                  ws += (size_t)GG*64*4;
    float* gcnt  = (float*)ws;                  ws += (size_t)GG*4;
    float* stats = (float*)ws;                  ws += 128*4;
    float* Qtab  = (float*)ws;                  ws += (size_t)GG*64*4;
    int*   cnt   = (int*)ws;                    ws += (size_t)NN*4;
    int*   offi  = (int*)ws;                    ws += (size_t)NN*4;
    int*   perm  = (int*)ws;                    ws += (size_t)EE*4;
    int*   rowp  = (int*)ws;                    ws += (size_t)EE*4;
    int*   colp  = (int*)ws;                    ws += (size_t)EE*4;

    float* out = (float*)d_out;

    hipMemsetAsync(cnt, 0, (size_t)NN*4, stream);
    hist_kernel<<<(EE + 255)/256, 256, 0, stream>>>(coli, cnt);
    scan_kernel<<<1, 1024, 0, stream>>>(cnt, offi);
    scatter_kernel<<<(EE + 255)/256, 256, 0, stream>>>(rowi, coli, offi, perm, rowp, colp);

    qfeat_kernel<<<(GG*64 + 255)/256, 256, 0, stream>>>(charge, W_charge, b_charge, W_atom, b_atom, Qtab);
    embed_node_kernel<<<512, 256, 0, stream>>>(x, batch, W_atom, Qtab, h);
    embed_edge_kernel<<<512, 256, 0, stream>>>(edge_attr, perm, W_bond, b_bond, ea);
    hipMemsetAsync(gsum, 0, (size_t)(GG*64 + GG)*4, stream);

    for (int l = 0; l < NL; ++l) {
        const float* euW1 = eu_W1 + (size_t)l*192*64;
        const float* nuW1 = nu_W1 + (size_t)l*128*64;
        precompute_kernel<<<256, 256, 0, stream>>>(
            h, euW1, euW1 + 64*64, nuW1,
            eu_b1 + l*64, nu_b1 + l*64, P1, P2, P3);
        hipMemsetAsync(stats, 0, 128*4, stream);
        layer_edge_kernel<<<512, 512, 0, stream>>>(
            ea, P1, P2, P3, msg, rowp, colp,
            euW1 + 128*64, eu_W2 + (size_t)l*64*64,
            nuW1 + 64*64,  nu_W2 + (size_t)l*64*64,
            eu_b2 + l*64, nu_b2 + l*64);
        reduce_kernel<<<(NN + 15)/16, 256, 0, stream>>>(msg, offi, h_new, stats);
        bn_apply_kernel<<<(NN*16 + 255)/256, 256, 0, stream>>>(
            h_new, h, stats, bn_gamma + l*64, bn_beta + l*64);
    }

    pool_kernel<<<(NN + 1023)/1024, 256, 0, stream>>>(h, batch, gsum, gcnt);
    predictor_kernel<<<GG, 128, 0, stream>>>(gsum, gcnt, p_W1, p_b1, p_W2, p_b2, p_W3, p_b3, out);
}

// Round 7
// 1025.478 us; speedup vs baseline: 6.5784x; 1.0516x over previous
//
#include <hip/hip_runtime.h>
#include <cmath>

#define NN 50000
#define EE 500000
#define GG 256
#define FA 92
#define FB 41
#define DD 64
#define HH 128
#define CQdim 16
#define NL 3
#define EPSBN 1e-5f

// Global column permutation: activations stored with col' = PI(col).
// PI(c)  = (c&15)*4 + (c>>4)   ; PIINV(c') = (c'&3)*16 + (c'>>2)
#define PIINV(cp) ((((cp) & 3) << 4) | ((cp) >> 2))

typedef __attribute__((ext_vector_type(8))) short short8;
typedef __attribute__((ext_vector_type(4))) float f32x4;

// ---------- helpers ----------
__device__ __forceinline__ float sp1(float x) {
    float e = __expf(-fabsf(x));
    return fmaxf(x, 0.0f) + __logf(1.0f + e);
}
__device__ __forceinline__ void atomAddF(float* p, float v) {
    unsafeAtomicAdd(p, v);
}
__device__ __forceinline__ unsigned short f2bf(float f) {
    unsigned int u = __float_as_uint(f);
    unsigned int r = u + 0x7FFFu + ((u >> 16) & 1u);
    return (unsigned short)(r >> 16);
}
__device__ __forceinline__ float bf2f(unsigned short s) {
    return __uint_as_float(((unsigned int)s) << 16);
}

// ---------- counting sort of edges by col ----------
__global__ __launch_bounds__(256) void hist_kernel(const int* __restrict__ coli, int* __restrict__ cnt)
{
    int e = blockIdx.x*256 + threadIdx.x;
    if (e < EE) atomicAdd(&cnt[coli[e]], 1);
}

// single-dispatch scan: serial chunk + one block scan + serial write-back
__global__ __launch_bounds__(1024) void scan_kernel(const int* __restrict__ cnt, int* __restrict__ off)
{
    const int CH = (NN + 1023) / 1024;   // 49
    const int t = threadIdx.x;
    int s0 = t*CH, s1 = s0 + CH; if (s1 > NN) s1 = NN; if (s0 > NN) s0 = NN;
    int sum = 0;
    for (int i = s0; i < s1; ++i) sum += cnt[i];
    __shared__ int buf[1024];
    buf[t] = sum;
    __syncthreads();
#pragma unroll
    for (int ofs = 1; ofs < 1024; ofs <<= 1) {
        int v = (t >= ofs) ? buf[t - ofs] : 0;
        __syncthreads();
        buf[t] += v;
        __syncthreads();
    }
    int run = buf[t] - sum;   // exclusive prefix of this chunk
    for (int i = s0; i < s1; ++i) { int v = cnt[i]; off[i] = run; run += v; }
}

// scatter: also emits inverse permutation epos[e] = sorted position
__global__ __launch_bounds__(256) void scatter_kernel(
    const int* __restrict__ rowi, const int* __restrict__ coli, int* __restrict__ off,
    int* __restrict__ epos, int* __restrict__ rowp, int* __restrict__ colp)
{
    int e = blockIdx.x*256 + threadIdx.x;
    if (e >= EE) return;
    int c = coli[e];
    int p = atomicAdd(&off[c], 1);
    epos[e] = p; rowp[p] = rowi[e]; colp[p] = c;
}

// ---------- per-graph charge table (PI-stored) ----------
__global__ __launch_bounds__(256) void qfeat_kernel(
    const float* __restrict__ charge, const float* __restrict__ Wc, const float* __restrict__ bc,
    const float* __restrict__ Wa, const float* __restrict__ ba, float* __restrict__ Q)
{
    int idx = blockIdx.x*256 + threadIdx.x;
    if (idx >= GG*64) return;
    int g = idx >> 6, cp = idx & 63;
    int c = PIINV(cp);
    float ch = charge[g];
    float acc = ba[c];
#pragma unroll
    for (int q = 0; q < CQdim; ++q) {
        float cf = ch*Wc[q] + bc[q];
        acc += cf * Wa[(FA + q)*64 + c];
    }
    Q[idx] = acc;
}

// ---------- node embedding via MFMA: h(PI) = x @ Wa[0:92] + Q[batch] ----------
__global__ __launch_bounds__(256) void embed_node_kernel(
    const float* __restrict__ x, const int* __restrict__ batch,
    const float* __restrict__ Wa, const float* __restrict__ Q,
    float* __restrict__ h)
{
    __shared__ unsigned short sB[3*64*40];    // 15 KB
    __shared__ unsigned short sU[4][16*104];  // 13 KB
    for (int idx = threadIdx.x; idx < 96*64; idx += 256) {
        int k = idx >> 6, n = idx & 63;
        int kb = k >> 5, q8 = k & 31;
        sB[(kb*64 + n)*40 + q8] = f2bf((k < FA) ? Wa[k*64 + n] : 0.f);
    }
    __syncthreads();

    const int lane = threadIdx.x & 63;
    const int wave = threadIdx.x >> 6;
    const int n16  = lane & 15;
    const int quad = lane >> 4;
    unsigned short* U = sU[wave];

    const int sr = lane >> 2;
    const int sseg = lane & 3;

    const int numTiles = NN >> 4;
    for (int tile = blockIdx.x*4 + wave; tile < numTiles; tile += gridDim.x*4) {
        const int base = tile << 4;
        {
            const float* src = &x[(size_t)(base + sr)*FA];
#pragma unroll
            for (int j = 0; j < 6; ++j) {
                int c0 = sseg*24 + j*4;
                ushort4 o = {0,0,0,0};
                if (c0 + 4 <= FA) {
                    float4 f = *(const float4*)&src[c0];
                    o.x = f2bf(f.x); o.y = f2bf(f.y); o.z = f2bf(f.z); o.w = f2bf(f.w);
                }
                *(ushort4*)&U[sr*104 + c0] = o;
            }
        }
        __builtin_amdgcn_wave_barrier();

        short8 a0 = *(const short8*)&U[n16*104 + 0*32 + quad*8];
        short8 a1 = *(const short8*)&U[n16*104 + 1*32 + quad*8];
        short8 a2 = *(const short8*)&U[n16*104 + 2*32 + quad*8];

        int bnode[4];
#pragma unroll
        for (int r = 0; r < 4; ++r) bnode[r] = batch[base + quad*4 + r];

        f32x4 zero = {0.f, 0.f, 0.f, 0.f};
        f32x4 accv[4];
#pragma unroll
        for (int nt = 0; nt < 4; ++nt) {
            f32x4 acc = zero;
            short8 b0 = *(const short8*)&sB[(0*64 + nt*16 + n16)*40 + quad*8];
            short8 b1 = *(const short8*)&sB[(1*64 + nt*16 + n16)*40 + quad*8];
            short8 b2 = *(const short8*)&sB[(2*64 + nt*16 + n16)*40 + quad*8];
            acc = __builtin_amdgcn_mfma_f32_16x16x32_bf16(a0, b0, acc, 0,0,0);
            acc = __builtin_amdgcn_mfma_f32_16x16x32_bf16(a1, b1, acc, 0,0,0);
            acc = __builtin_amdgcn_mfma_f32_16x16x32_bf16(a2, b2, acc, 0,0,0);
            accv[nt] = acc;
        }
#pragma unroll
        for (int r = 0; r < 4; ++r) {
            float4 qv = *(const float4*)&Q[bnode[r]*64 + n16*4];
            float4 o = make_float4(accv[0][r]+qv.x, accv[1][r]+qv.y, accv[2][r]+qv.z, accv[3][r]+qv.w);
            *(float4*)&h[(size_t)(base + quad*4 + r)*64 + n16*4] = o;
        }
        __builtin_amdgcn_wave_barrier();
    }
}

// ---------- edge embedding via MFMA: SEQUENTIAL read, scatter write via epos ----------
__global__ __launch_bounds__(256) void embed_edge_kernel(
    const float* __restrict__ eattr, const int* __restrict__ epos,
    const float* __restrict__ Wb, const float* __restrict__ bbond,
    unsigned short* __restrict__ ea)
{
    __shared__ unsigned short sB[2*64*40];   // 10 KB
    __shared__ unsigned short sU[4][16*72];  // 9 KB
    for (int idx = threadIdx.x; idx < 64*64; idx += 256) {
        int k = idx >> 6, n = idx & 63;
        int kb = k >> 5, q8 = k & 31;
        sB[(kb*64 + n)*40 + q8] = f2bf((k < FB) ? Wb[k*64 + n] : 0.f);
    }
    // zero U once: staging only writes cols < 41 afterwards; cols 41..63 feed
    // zero B rows (and must not be NaN garbage)
    for (int idx = threadIdx.x; idx < 4*16*72; idx += 256) ((unsigned short*)sU)[idx] = 0;
    __syncthreads();

    const int lane = threadIdx.x & 63;
    const int wave = threadIdx.x >> 6;
    const int n16  = lane & 15;
    const int quad = lane >> 4;
    unsigned short* U = sU[wave];

    float bbv[4];
#pragma unroll
    for (int nt = 0; nt < 4; ++nt) bbv[nt] = bbond[nt*16 + n16];

    const int numTiles = EE >> 4;
    for (int tile = blockIdx.x*4 + wave; tile < numTiles; tile += gridDim.x*4) {
        const int base = tile << 4;
        // coalesced staging: 16 rows x 41 floats = 656 contiguous floats
        const float* src = &eattr[(size_t)base*FB];
#pragma unroll
        for (int j = 0; j < 11; ++j) {
            int idx = lane + 64*j;
            if (idx < 16*FB) {
                int r = idx / FB, c = idx - r*FB;
                U[r*72 + c] = f2bf(src[idx]);
            }
        }
        // destination positions (consecutive e -> coalesced epos loads)
        int ep[4];
#pragma unroll
        for (int r = 0; r < 4; ++r) ep[r] = epos[base + quad*4 + r];
        __builtin_amdgcn_wave_barrier();

        short8 a0 = *(const short8*)&U[n16*72 + 0*32 + quad*8];
        short8 a1 = *(const short8*)&U[n16*72 + 1*32 + quad*8];
        f32x4 zero = {0.f, 0.f, 0.f, 0.f};
        f32x4 accv[4];
#pragma unroll
        for (int nt = 0; nt < 4; ++nt) {
            f32x4 acc = zero;
            short8 b0 = *(const short8*)&sB[(0*64 + nt*16 + n16)*40 + quad*8];
            short8 b1 = *(const short8*)&sB[(1*64 + nt*16 + n16)*40 + quad*8];
            acc = __builtin_amdgcn_mfma_f32_16x16x32_bf16(a0, b0, acc, 0,0,0);
            acc = __builtin_amdgcn_mfma_f32_16x16x32_bf16(a1, b1, acc, 0,0,0);
            accv[nt] = acc;
        }
#pragma unroll
        for (int r = 0; r < 4; ++r) {
            ushort4 o;
            o.x = f2bf(accv[0][r] + bbv[0]);
            o.y = f2bf(accv[1][r] + bbv[1]);
            o.z = f2bf(accv[2][r] + bbv[2]);
            o.w = f2bf(accv[3][r] + bbv[3]);
            *(ushort4*)&ea[(size_t)ep[r]*64 + n16*4] = o;   // full 128B row per quad
        }
        __builtin_amdgcn_wave_barrier();
    }
}

// ---------- layer-0 precompute via MFMA (h PI-stored in, P PI-stored out) ----------
__global__ __launch_bounds__(256) void precompute_kernel(
    const float* __restrict__ h,
    const float* __restrict__ W1, const float* __restrict__ W2, const float* __restrict__ W3,
    const float* __restrict__ b1, const float* __restrict__ b3,
    float* __restrict__ P1, float* __restrict__ P2, float* __restrict__ P3)
{
    __shared__ unsigned short sB[3*2*64*40];     // 30 KB
    __shared__ unsigned short sU[4][16*72];      // 9 KB
    for (int idx = threadIdx.x; idx < 3*64*64; idx += 256) {
        int mat = idx >> 12;
        int rem = idx & 4095;
        int kp = rem >> 6, n = rem & 63;
        int kt = PIINV(kp);
        int kb = kp >> 5, q8 = kp & 31;
        const float* W = (mat==0) ? W1 : (mat==1) ? W2 : W3;
        sB[((mat*2 + kb)*64 + n)*40 + q8] = f2bf(W[kt*64 + n]);
    }
    __syncthreads();

    const int lane = threadIdx.x & 63;
    const int wave = threadIdx.x >> 6;
    const int n16  = lane & 15;
    const int quad = lane >> 4;
    unsigned short* U = sU[wave];

    float b1v[4], b3v[4];
#pragma unroll
    for (int nt = 0; nt < 4; ++nt) { b1v[nt] = b1[nt*16 + n16]; b3v[nt] = b3[nt*16 + n16]; }

    const int sr = lane >> 2;
    const int sseg = lane & 3;

    const int numTiles = NN >> 4;
    for (int tile = blockIdx.x*4 + wave; tile < numTiles; tile += gridDim.x*4) {
        const int base = tile << 4;
        {
            const float* src = &h[(size_t)(base + sr)*64 + sseg*16];
            float4 f0 = *(const float4*)(src);
            float4 f1 = *(const float4*)(src + 4);
            float4 f2 = *(const float4*)(src + 8);
            float4 f3 = *(const float4*)(src + 12);
            unsigned short* dst = &U[sr*72 + sseg*16];
            ushort4 o0 = { f2bf(f0.x), f2bf(f0.y), f2bf(f0.z), f2bf(f0.w) };
            ushort4 o1 = { f2bf(f1.x), f2bf(f1.y), f2bf(f1.z), f2bf(f1.w) };
            ushort4 o2 = { f2bf(f2.x), f2bf(f2.y), f2bf(f2.z), f2bf(f2.w) };
            ushort4 o3 = { f2bf(f3.x), f2bf(f3.y), f2bf(f3.z), f2bf(f3.w) };
            *(ushort4*)(dst + 0)  = o0;
            *(ushort4*)(dst + 4)  = o1;
            *(ushort4*)(dst + 8)  = o2;
            *(ushort4*)(dst + 12) = o3;
        }
        __builtin_amdgcn_wave_barrier();

        short8 a0 = *(const short8*)&U[n16*72 + 0*32 + quad*8];
        short8 a1 = *(const short8*)&U[n16*72 + 1*32 + quad*8];
        f32x4 zero = {0.f, 0.f, 0.f, 0.f};

#pragma unroll
        for (int mat = 0; mat < 3; ++mat) {
            f32x4 acc[4];
#pragma unroll
            for (int nt = 0; nt < 4; ++nt) acc[nt] = zero;
#pragma unroll
            for (int nt = 0; nt < 4; ++nt) {
                short8 b0 = *(const short8*)&sB[((mat*2 + 0)*64 + nt*16 + n16)*40 + quad*8];
                short8 bq = *(const short8*)&sB[((mat*2 + 1)*64 + nt*16 + n16)*40 + quad*8];
                acc[nt] = __builtin_amdgcn_mfma_f32_16x16x32_bf16(a0, b0, acc[nt], 0,0,0);
                acc[nt] = __builtin_amdgcn_mfma_f32_16x16x32_bf16(a1, bq, acc[nt], 0,0,0);
            }
            float* P = (mat==0) ? P1 : (mat==1) ? P2 : P3;
#pragma unroll
            for (int r = 0; r < 4; ++r) {
                float4 o;
                if (mat==0)      o = make_float4(acc[0][r]+b1v[0], acc[1][r]+b1v[1], acc[2][r]+b1v[2], acc[3][r]+b1v[3]);
                else if (mat==2) o = make_float4(acc[0][r]+b3v[0], acc[1][r]+b3v[1], acc[2][r]+b3v[2], acc[3][r]+b3v[3]);
                else             o = make_float4(acc[0][r], acc[1][r], acc[2][r], acc[3][r]);
                *(float4*)&P[(size_t)(base + quad*4 + r)*64 + n16*4] = o;
            }
        }
        __builtin_amdgcn_wave_barrier();
    }
}

// ---------- fused BN+softplus+residual + precompute (layers 1..L-1) ----------
// hcur = sp(bn(h_new)) + h  -> written to h, and P1/P2/P3 = f(hcur)
__global__ __launch_bounds__(256) void bnpre_kernel(
    float* __restrict__ h, const float* __restrict__ h_new,
    const float* __restrict__ stats, const float* __restrict__ gamma, const float* __restrict__ beta,
    const float* __restrict__ W1, const float* __restrict__ W2, const float* __restrict__ W3,
    const float* __restrict__ b1, const float* __restrict__ b3,
    float* __restrict__ P1, float* __restrict__ P2, float* __restrict__ P3)
{
    __shared__ unsigned short sB[3*2*64*40];     // 30 KB
    __shared__ unsigned short sU[4][16*72];      // 9 KB
    __shared__ float sMU[64], sISG[64], sBB[64];
    for (int idx = threadIdx.x; idx < 3*64*64; idx += 256) {
        int mat = idx >> 12;
        int rem = idx & 4095;
        int kp = rem >> 6, n = rem & 63;
        int kt = PIINV(kp);
        int kb = kp >> 5, q8 = kp & 31;
        const float* W = (mat==0) ? W1 : (mat==1) ? W2 : W3;
        sB[((mat*2 + kb)*64 + n)*40 + q8] = f2bf(W[kt*64 + n]);
    }
    if (threadIdx.x < 64) {
        int cp = threadIdx.x;
        int ct = PIINV(cp);
        const float invN = 1.0f / (float)NN;
        float mu  = stats[cp] * invN;
        float var = stats[64+cp] * invN - mu*mu;
        float is  = rsqrtf(var + EPSBN);
        sMU[cp]  = mu;
        sISG[cp] = is * gamma[ct];
        sBB[cp]  = beta[ct];
    }
    __syncthreads();

    const int lane = threadIdx.x & 63;
    const int wave = threadIdx.x >> 6;
    const int n16  = lane & 15;
    const int quad = lane >> 4;
    unsigned short* U = sU[wave];

    float b1v[4], b3v[4];
#pragma unroll
    for (int nt = 0; nt < 4; ++nt) { b1v[nt] = b1[nt*16 + n16]; b3v[nt] = b3[nt*16 + n16]; }

    const int sr = lane >> 2;
    const int sseg = lane & 3;
    float mu4[16], isg4[16], bb4[16];
#pragma unroll
    for (int j = 0; j < 16; ++j) {
        int cp = sseg*16 + j;
        mu4[j] = sMU[cp]; isg4[j] = sISG[cp]; bb4[j] = sBB[cp];
    }

    const int numTiles = NN >> 4;
    for (int tile = blockIdx.x*4 + wave; tile < numTiles; tile += gridDim.x*4) {
        const int base = tile << 4;
        {
            float* hrow = &h[(size_t)(base + sr)*64 + sseg*16];
            const float* hnrow = &h_new[(size_t)(base + sr)*64 + sseg*16];
            unsigned short* dst = &U[sr*72 + sseg*16];
#pragma unroll
            for (int q = 0; q < 4; ++q) {
                float4 hn = *(const float4*)(hnrow + q*4);
                float4 ho = *(const float4*)(hrow + q*4);
                float v0 = sp1((hn.x - mu4[q*4+0])*isg4[q*4+0] + bb4[q*4+0]) + ho.x;
                float v1 = sp1((hn.y - mu4[q*4+1])*isg4[q*4+1] + bb4[q*4+1]) + ho.y;
                float v2 = sp1((hn.z - mu4[q*4+2])*isg4[q*4+2] + bb4[q*4+2]) + ho.z;
                float v3 = sp1((hn.w - mu4[q*4+3])*isg4[q*4+3] + bb4[q*4+3]) + ho.w;
                *(float4*)(hrow + q*4) = make_float4(v0, v1, v2, v3);
                ushort4 o = { f2bf(v0), f2bf(v1), f2bf(v2), f2bf(v3) };
                *(ushort4*)(dst + q*4) = o;
            }
        }
        __builtin_amdgcn_wave_barrier();

        short8 a0 = *(const short8*)&U[n16*72 + 0*32 + quad*8];
        short8 a1 = *(const short8*)&U[n16*72 + 1*32 + quad*8];
        f32x4 zero = {0.f, 0.f, 0.f, 0.f};

#pragma unroll
        for (int mat = 0; mat < 3; ++mat) {
            f32x4 acc[4];
#pragma unroll
            for (int nt = 0; nt < 4; ++nt) acc[nt] = zero;
#pragma unroll
            for (int nt = 0; nt < 4; ++nt) {
                short8 b0 = *(const short8*)&sB[((mat*2 + 0)*64 + nt*16 + n16)*40 + quad*8];
                short8 bq = *(const short8*)&sB[((mat*2 + 1)*64 + nt*16 + n16)*40 + quad*8];
                acc[nt] = __builtin_amdgcn_mfma_f32_16x16x32_bf16(a0, b0, acc[nt], 0,0,0);
                acc[nt] = __builtin_amdgcn_mfma_f32_16x16x32_bf16(a1, bq, acc[nt], 0,0,0);
            }
            float* P = (mat==0) ? P1 : (mat==1) ? P2 : P3;
#pragma unroll
            for (int r = 0; r < 4; ++r) {
                float4 o;
                if (mat==0)      o = make_float4(acc[0][r]+b1v[0], acc[1][r]+b1v[1], acc[2][r]+b1v[2], acc[3][r]+b1v[3]);
                else if (mat==2) o = make_float4(acc[0][r]+b3v[0], acc[1][r]+b3v[1], acc[2][r]+b3v[2], acc[3][r]+b3v[3]);
                else             o = make_float4(acc[0][r], acc[1][r], acc[2][r], acc[3][r]);
                *(float4*)&P[(size_t)(base + quad*4 + r)*64 + n16*4] = o;
            }
        }
        __builtin_amdgcn_wave_barrier();
    }
}

// ---------- MFMA fused per-edge kernel over col-sorted edges (all tensors PI-stored) ----------
__global__ __launch_bounds__(512, 2) void layer_edge_kernel(
    unsigned short* __restrict__ ea,
    const float* __restrict__ P1, const float* __restrict__ P2, const float* __restrict__ P3,
    unsigned short* __restrict__ msg,
    const int* __restrict__ rowp, const int* __restrict__ colp,
    const float* __restrict__ WA, const float* __restrict__ WB,
    const float* __restrict__ WC, const float* __restrict__ WD,
    const float* __restrict__ eb2, const float* __restrict__ nb2)
{
    __shared__ unsigned short sB[20480];          // 40 KB
    __shared__ unsigned short sU[8][16*72];       // 18 KB
    for (int idx = threadIdx.x; idx < 4*64*64; idx += 512) {
        int mat = idx >> 12;
        int rem = idx & 4095;
        int kp = rem >> 6, n = rem & 63;
        int kt = PIINV(kp);
        int kb = kp >> 5, q8 = kp & 31;
        const float* W = (mat==0) ? WA : (mat==1) ? WB : (mat==2) ? WC : WD;
        sB[((mat*2 + kb)*64 + n)*40 + q8] = f2bf(W[kt*64 + n]);
    }
    __syncthreads();

    const int lane = threadIdx.x & 63;
    const int wave = threadIdx.x >> 6;
    const int n16  = lane & 15;
    const int quad = lane >> 4;
    unsigned short* U = sU[wave];

    float eb2v[4], nb2v[4];
#pragma unroll
    for (int nt = 0; nt < 4; ++nt) { eb2v[nt] = eb2[nt*16 + n16]; nb2v[nt] = nb2[nt*16 + n16]; }

    const int sr = lane >> 2;
    const int sseg = lane & 3;

    const int numTiles = EE >> 4;
    for (int tile = blockIdx.x*8 + wave; tile < numTiles; tile += gridDim.x*8) {
        const int base = tile << 4;
        int rid[4], cid[4];
#pragma unroll
        for (int r = 0; r < 4; ++r) {
            rid[r] = rowp[base + quad*4 + r];
            cid[r] = colp[base + quad*4 + r];
        }
        float4 g12v[4];
#pragma unroll
        for (int r = 0; r < 4; ++r) {
            float4 a = *(const float4*)&P1[(size_t)rid[r]*64 + n16*4];
            float4 b = *(const float4*)&P2[(size_t)cid[r]*64 + n16*4];
            g12v[r] = make_float4(a.x+b.x, a.y+b.y, a.z+b.z, a.w+b.w);
        }
        {
            const unsigned short* src = &ea[(size_t)(base + sr)*64 + sseg*16];
            uint4 q0 = *(const uint4*)(src);
            uint4 q1 = *(const uint4*)(src + 8);
            *(uint4*)&U[sr*72 + sseg*16]     = q0;
            *(uint4*)&U[sr*72 + sseg*16 + 8] = q1;
        }
        __builtin_amdgcn_wave_barrier();

        f32x4 zero = {0.f, 0.f, 0.f, 0.f};

#define RUN_MM(MAT, ACC)                                                          \
        {                                                                         \
            short8 a0 = *(const short8*)&U[n16*72 + 0*32 + quad*8];               \
            short8 a1 = *(const short8*)&U[n16*72 + 1*32 + quad*8];               \
            _Pragma("unroll")                                                     \
            for (int nt = 0; nt < 4; ++nt) {                                      \
                short8 b0 = *(const short8*)&sB[(((MAT)*2+0)*64 + nt*16 + n16)*40 + quad*8]; \
                short8 b1 = *(const short8*)&sB[(((MAT)*2+1)*64 + nt*16 + n16)*40 + quad*8]; \
                ACC[nt] = __builtin_amdgcn_mfma_f32_16x16x32_bf16(a0, b0, ACC[nt], 0,0,0);   \
                ACC[nt] = __builtin_amdgcn_mfma_f32_16x16x32_bf16(a1, b1, ACC[nt], 0,0,0);   \
            }                                                                     \
        }

        // ---- phase 1: t1 = sp(P1[row]+P2[col] + ea@WA) ----
        f32x4 acc[4];
#pragma unroll
        for (int nt = 0; nt < 4; ++nt) acc[nt] = zero;
        RUN_MM(0, acc);
#pragma unroll
        for (int r = 0; r < 4; ++r) {
            ushort4 o;
            o.x = f2bf(sp1(acc[0][r] + g12v[r].x));
            o.y = f2bf(sp1(acc[1][r] + g12v[r].y));
            o.z = f2bf(sp1(acc[2][r] + g12v[r].z));
            o.w = f2bf(sp1(acc[3][r] + g12v[r].w));
            *(ushort4*)&U[(quad*4 + r)*72 + n16*4] = o;
        }
        __builtin_amdgcn_wave_barrier();

        // ---- phase 2: ea' = t1@WB + eb2 ----
#pragma unroll
        for (int nt = 0; nt < 4; ++nt) acc[nt] = zero;
        RUN_MM(1, acc);
#pragma unroll
        for (int r = 0; r < 4; ++r) {
            ushort4 o;
            o.x = f2bf(acc[0][r] + eb2v[0]);
            o.y = f2bf(acc[1][r] + eb2v[1]);
            o.z = f2bf(acc[2][r] + eb2v[2]);
            o.w = f2bf(acc[3][r] + eb2v[3]);
            *(ushort4*)&ea[(size_t)(base + quad*4 + r)*64 + n16*4] = o;
            *(ushort4*)&U[(quad*4 + r)*72 + n16*4] = o;
        }
        float4 g3v[4];
#pragma unroll
        for (int r = 0; r < 4; ++r)
            g3v[r] = *(const float4*)&P3[(size_t)rid[r]*64 + n16*4];
        __builtin_amdgcn_wave_barrier();

        // ---- phase 3: t2 = sp(P3[row] + ea'@WC) ----
#pragma unroll
        for (int nt = 0; nt < 4; ++nt) acc[nt] = zero;
        RUN_MM(2, acc);
#pragma unroll
        for (int r = 0; r < 4; ++r) {
            ushort4 o;
            o.x = f2bf(sp1(acc[0][r] + g3v[r].x));
            o.y = f2bf(sp1(acc[1][r] + g3v[r].y));
            o.z = f2bf(sp1(acc[2][r] + g3v[r].z));
            o.w = f2bf(sp1(acc[3][r] + g3v[r].w));
            *(ushort4*)&U[(quad*4 + r)*72 + n16*4] = o;
        }
        __builtin_amdgcn_wave_barrier();

        // ---- phase 4: msg = t2@WD + nb2 ----
#pragma unroll
        for (int nt = 0; nt < 4; ++nt) acc[nt] = zero;
        RUN_MM(3, acc);
#pragma unroll
        for (int r = 0; r < 4; ++r) {
            ushort4 o;
            o.x = f2bf(acc[0][r] + nb2v[0]);
            o.y = f2bf(acc[1][r] + nb2v[1]);
            o.z = f2bf(acc[2][r] + nb2v[2]);
            o.w = f2bf(acc[3][r] + nb2v[3]);
            *(ushort4*)&msg[(size_t)(base + quad*4 + r)*64 + n16*4] = o;
        }
        __builtin_amdgcn_wave_barrier();
#undef RUN_MM
    }
}

// ---------- CSR segment-sum of msg -> h_new (PI cols), fused BN statistics ----------
__global__ __launch_bounds__(256) void reduce_kernel(
    const unsigned short* __restrict__ msg, const int* __restrict__ offi,
    float* __restrict__ h_new, float* __restrict__ stats)
{
    const int t = threadIdx.x;
    const int nl = t >> 4;
    const int n  = blockIdx.x*16 + nl;
    const int c0 = (t & 15)*4;
    float a0=0.f, a1=0.f, a2=0.f, a3=0.f;
    if (n < NN) {
        int s = (n == 0) ? 0 : offi[n-1];
        int e = offi[n];
        for (int p = s; p < e; ++p) {
            uint2 q = *(const uint2*)&msg[(size_t)p*64 + c0];
            a0 += bf2f((unsigned short)(q.x & 0xffff));
            a1 += bf2f((unsigned short)(q.x >> 16));
            a2 += bf2f((unsigned short)(q.y & 0xffff));
            a3 += bf2f((unsigned short)(q.y >> 16));
        }
        *(float4*)&h_new[(size_t)n*64 + c0] = make_float4(a0,a1,a2,a3);
    }
    __shared__ float Ss[16][64];
    __shared__ float Sq[16][64];
    Ss[nl][c0+0]=a0; Ss[nl][c0+1]=a1; Ss[nl][c0+2]=a2; Ss[nl][c0+3]=a3;
    Sq[nl][c0+0]=a0*a0; Sq[nl][c0+1]=a1*a1; Sq[nl][c0+2]=a2*a2; Sq[nl][c0+3]=a3*a3;
    __syncthreads();
    if (t < 64) {
        float s = 0.f, q = 0.f;
#pragma unroll
        for (int r = 0; r < 16; ++r) { s += Ss[r][t]; q += Sq[r][t]; }
        atomAddF(&stats[t], s);
        atomAddF(&stats[64 + t], q);
    }
}

// ---------- final bn apply + softplus + residual (PI cols) ----------
__global__ __launch_bounds__(256) void bn_apply_kernel(
    const float* __restrict__ hn, float* __restrict__ h,
    const float* __restrict__ stats, const float* __restrict__ gamma, const float* __restrict__ beta)
{
    size_t idx = (size_t)blockIdx.x*256 + threadIdx.x;
    if (idx >= (size_t)NN*16) return;
    int c0 = (int)(idx & 15) << 2;
    float4 v = ((const float4*)hn)[idx];
    float4 r = ((const float4*)h)[idx];
    float vv[4] = {v.x, v.y, v.z, v.w};
    float rr[4] = {r.x, r.y, r.z, r.w};
    float oo[4];
    const float invN = 1.0f / (float)NN;
#pragma unroll
    for (int c = 0; c < 4; ++c) {
        int col = c0 + c;
        int ct  = PIINV(col);
        float mu  = stats[col] * invN;
        float var = stats[64+col] * invN - mu*mu;
        float is  = rsqrtf(var + EPSBN);
        float nv  = (vv[c] - mu) * is * gamma[ct] + beta[ct];
        oo[c] = sp1(nv) + rr[c];
    }
    ((float4*)h)[idx] = make_float4(oo[0], oo[1], oo[2], oo[3]);
}

// ---------- global mean pool (batch sorted -> run-accumulate; PI cols) ----------
__global__ __launch_bounds__(256) void pool_kernel(
    const float* __restrict__ h, const int* __restrict__ batch,
    float* __restrict__ gsum, float* __restrict__ gcnt)
{
    const int col = threadIdx.x & 63, rg = threadIdx.x >> 6;
    int n0 = blockIdx.x*1024 + rg*256;
    if (n0 >= NN) return;
    int n1 = n0 + 256; if (n1 > NN) n1 = NN;
    float s = 0.f;
    int cur = batch[n0];
    int cnt = 0;
    for (int n = n0; n < n1; ++n) {
        int g = batch[n];
        if (g != cur) {
            atomAddF(&gsum[cur*64 + col], s);
            if (col == 0) atomAddF(&gcnt[cur], (float)cnt);
            s = 0.f; cnt = 0; cur = g;
        }
        s += h[(size_t)n*64 + col];
        ++cnt;
    }
    atomAddF(&gsum[cur*64 + col], s);
    if (col == 0) atomAddF(&gcnt[cur], (float)cnt);
}

// ---------- predictor MLP (gsum PI-stored -> remap p_W1 rows) ----------
__global__ __launch_bounds__(128) void predictor_kernel(
    const float* __restrict__ gsum, const float* __restrict__ gcnt,
    const float* __restrict__ W1, const float* __restrict__ b1,
    const float* __restrict__ W2, const float* __restrict__ b2,
    const float* __restrict__ W3, const float* __restrict__ b3,
    float* __restrict__ out)
{
    int g = blockIdx.x, t = threadIdx.x;
    __shared__ float gr[64];
    __shared__ float z1[128];
    __shared__ float z2[128];
    __shared__ float red[128];
    if (t < 64) gr[t] = gsum[g*64 + t] / fmaxf(gcnt[g], 1.0f);
    __syncthreads();
    float s = b1[t];
#pragma unroll
    for (int k = 0; k < 64; ++k) s += gr[k] * W1[PIINV(k)*128 + t];
    z1[t] = sp1(s);
    __syncthreads();
    s = b2[t];
    for (int k = 0; k < 128; ++k) s += z1[k] * W2[k*128 + t];
    z2[t] = sp1(s);
    __syncthreads();
    red[t] = z2[t] * W3[t];
    __syncthreads();
    for (int off = 64; off > 0; off >>= 1) {
        if (t < off) red[t] += red[t + off];
        __syncthreads();
    }
    if (t == 0) out[g] = red[0] + b3[0];
}

// ---------- launch ----------
extern "C" void kernel_launch(void* const* d_in, const int* in_sizes, int n_in,
                              void* d_out, int out_size, void* d_ws, size_t ws_size,
                              hipStream_t stream)
{
    const float* x         = (const float*)d_in[0];
    const float* edge_attr = (const float*)d_in[1];
    const float* charge    = (const float*)d_in[2];
    const int*   edge_index= (const int*)d_in[3];
    const int*   batch     = (const int*)d_in[4];
    const float* W_charge  = (const float*)d_in[5];
    const float* b_charge  = (const float*)d_in[6];
    const float* W_atom    = (const float*)d_in[7];
    const float* b_atom    = (const float*)d_in[8];
    const float* W_bond    = (const float*)d_in[9];
    const float* b_bond    = (const float*)d_in[10];
    const float* nu_W1     = (const float*)d_in[11];
    const float* nu_b1     = (const float*)d_in[12];
    const float* nu_W2     = (const float*)d_in[13];
    const float* nu_b2     = (const float*)d_in[14];
    const float* eu_W1     = (const float*)d_in[15];
    const float* eu_b1     = (const float*)d_in[16];
    const float* eu_W2     = (const float*)d_in[17];
    const float* eu_b2     = (const float*)d_in[18];
    const float* bn_gamma  = (const float*)d_in[19];
    const float* bn_beta   = (const float*)d_in[20];
    const float* p_W1      = (const float*)d_in[21];
    const float* p_b1      = (const float*)d_in[22];
    const float* p_W2      = (const float*)d_in[23];
    const float* p_b2      = (const float*)d_in[24];
    const float* p_W3      = (const float*)d_in[25];
    const float* p_b3      = (const float*)d_in[26];

    const int* rowi = edge_index;
    const int* coli = edge_index + EE;

    char* ws = (char*)d_ws;
    unsigned short* ea  = (unsigned short*)ws;  ws += (size_t)EE*64*2;
    unsigned short* msg = (unsigned short*)ws;  ws += (size_t)EE*64*2;
    float* h     = (float*)ws;                  ws += (size_t)NN*64*4;
    float* P1    = (float*)ws;                  ws += (size_t)NN*64*4;
    float* P2    = (float*)ws;                  ws += (size_t)NN*64*4;
    float* P3    = (float*)ws;                  ws += (size_t)NN*64*4;
    float* h_new = (float*)ws;                  ws += (size_t)NN*64*4;
    float* gsum  = (float*)ws;                  ws += (size_t)GG*64*4;
    float* gcnt  = (float*)ws;                  ws += (size_t)GG*4;
    float* stats = (float*)ws;                  ws += 128*4;
    float* Qtab  = (float*)ws;                  ws += (size_t)GG*64*4;
    int*   cnt   = (int*)ws;                    ws += (size_t)NN*4;
    int*   offi  = (int*)ws;                    ws += (size_t)NN*4;
    int*   epos  = (int*)ws;                    ws += (size_t)EE*4;
    int*   rowp  = (int*)ws;                    ws += (size_t)EE*4;
    int*   colp  = (int*)ws;                    ws += (size_t)EE*4;

    float* out = (float*)d_out;

    hipMemsetAsync(cnt, 0, (size_t)NN*4, stream);
    hist_kernel<<<(EE + 255)/256, 256, 0, stream>>>(coli, cnt);
    scan_kernel<<<1, 1024, 0, stream>>>(cnt, offi);
    scatter_kernel<<<(EE + 255)/256, 256, 0, stream>>>(rowi, coli, offi, epos, rowp, colp);

    qfeat_kernel<<<(GG*64 + 255)/256, 256, 0, stream>>>(charge, W_charge, b_charge, W_atom, b_atom, Qtab);
    embed_node_kernel<<<512, 256, 0, stream>>>(x, batch, W_atom, Qtab, h);
    embed_edge_kernel<<<1024, 256, 0, stream>>>(edge_attr, epos, W_bond, b_bond, ea);
    hipMemsetAsync(gsum, 0, (size_t)(GG*64 + GG)*4, stream);

    for (int l = 0; l < NL; ++l) {
        const float* euW1 = eu_W1 + (size_t)l*192*64;
        const float* nuW1 = nu_W1 + (size_t)l*128*64;
        if (l == 0) {
            precompute_kernel<<<256, 256, 0, stream>>>(
                h, euW1, euW1 + 64*64, nuW1,
                eu_b1 + l*64, nu_b1 + l*64, P1, P2, P3);
        } else {
            bnpre_kernel<<<256, 256, 0, stream>>>(
                h, h_new, stats, bn_gamma + (l-1)*64, bn_beta + (l-1)*64,
                euW1, euW1 + 64*64, nuW1,
                eu_b1 + l*64, nu_b1 + l*64, P1, P2, P3);
        }
        hipMemsetAsync(stats, 0, 128*4, stream);
        layer_edge_kernel<<<512, 512, 0, stream>>>(
            ea, P1, P2, P3, msg, rowp, colp,
            euW1 + 128*64, eu_W2 + (size_t)l*64*64,
            nuW1 + 64*64,  nu_W2 + (size_t)l*64*64,
            eu_b2 + l*64, nu_b2 + l*64);
        reduce_kernel<<<(NN + 15)/16, 256, 0, stream>>>(msg, offi, h_new, stats);
    }
    bn_apply_kernel<<<(NN*16 + 255)/256, 256, 0, stream>>>(
        h_new, h, stats, bn_gamma + (NL-1)*64, bn_beta + (NL-1)*64);

    pool_kernel<<<(NN + 1023)/1024, 256, 0, stream>>>(h, batch, gsum, gcnt);
    predictor_kernel<<<GG, 128, 0, stream>>>(gsum, gcnt, p_W1, p_b1, p_W2, p_b2, p_W3, p_b3, out);
}

// Round 8
// 948.137 us; speedup vs baseline: 7.1150x; 1.0816x over previous
//
#include <hip/hip_runtime.h>
#include <cmath>

#define NN 50000
#define EE 500000
#define GG 256
#define FA 92
#define FB 41
#define DD 64
#define HH 128
#define CQdim 16
#define NL 3
#define EPSBN 1e-5f

// Global column permutation: activations stored with col' = PI(col).
// PI(c)  = (c&15)*4 + (c>>4)   ; PIINV(c') = (c'&3)*16 + (c'>>2)
#define PIINV(cp) ((((cp) & 3) << 4) | ((cp) >> 2))

typedef __attribute__((ext_vector_type(8))) short short8;
typedef __attribute__((ext_vector_type(4))) float f32x4;

// ---------- helpers ----------
__device__ __forceinline__ float sp1(float x) {
    float e = __expf(-fabsf(x));
    return fmaxf(x, 0.0f) + __logf(1.0f + e);
}
__device__ __forceinline__ void atomAddF(float* p, float v) {
    unsafeAtomicAdd(p, v);
}
__device__ __forceinline__ unsigned short f2bf(float f) {
    unsigned int u = __float_as_uint(f);
    unsigned int r = u + 0x7FFFu + ((u >> 16) & 1u);
    return (unsigned short)(r >> 16);
}
__device__ __forceinline__ float bf2f(unsigned short s) {
    return __uint_as_float(((unsigned int)s) << 16);
}

// ---------- counting sort of edges by col ----------
__global__ __launch_bounds__(256) void hist_kernel(const int* __restrict__ coli, int* __restrict__ cnt)
{
    int e = blockIdx.x*256 + threadIdx.x;
    if (e < EE) atomicAdd(&cnt[coli[e]], 1);
}

__global__ __launch_bounds__(1024) void scan_kernel(const int* __restrict__ cnt, int* __restrict__ off)
{
    const int CH = (NN + 1023) / 1024;   // 49
    const int t = threadIdx.x;
    int s0 = t*CH, s1 = s0 + CH; if (s1 > NN) s1 = NN; if (s0 > NN) s0 = NN;
    int sum = 0;
    for (int i = s0; i < s1; ++i) sum += cnt[i];
    __shared__ int buf[1024];
    buf[t] = sum;
    __syncthreads();
#pragma unroll
    for (int ofs = 1; ofs < 1024; ofs <<= 1) {
        int v = (t >= ofs) ? buf[t - ofs] : 0;
        __syncthreads();
        buf[t] += v;
        __syncthreads();
    }
    int run = buf[t] - sum;
    for (int i = s0; i < s1; ++i) { int v = cnt[i]; off[i] = run; run += v; }
}

__global__ __launch_bounds__(256) void scatter_kernel(
    const int* __restrict__ rowi, const int* __restrict__ coli, int* __restrict__ off,
    int* __restrict__ epos, int* __restrict__ rowp, int* __restrict__ colp)
{
    int e = blockIdx.x*256 + threadIdx.x;
    if (e >= EE) return;
    int c = coli[e];
    int p = atomicAdd(&off[c], 1);
    epos[e] = p; rowp[p] = rowi[e]; colp[p] = c;
}

// ---------- per-graph charge table (PI-stored) ----------
__global__ __launch_bounds__(256) void qfeat_kernel(
    const float* __restrict__ charge, const float* __restrict__ Wc, const float* __restrict__ bc,
    const float* __restrict__ Wa, const float* __restrict__ ba, float* __restrict__ Q)
{
    int idx = blockIdx.x*256 + threadIdx.x;
    if (idx >= GG*64) return;
    int g = idx >> 6, cp = idx & 63;
    int c = PIINV(cp);
    float ch = charge[g];
    float acc = ba[c];
#pragma unroll
    for (int q = 0; q < CQdim; ++q) {
        float cf = ch*Wc[q] + bc[q];
        acc += cf * Wa[(FA + q)*64 + c];
    }
    Q[idx] = acc;
}

// ---------- node embedding via MFMA: h(PI) = x @ Wa[0:92] + Q[batch] ----------
__global__ __launch_bounds__(256) void embed_node_kernel(
    const float* __restrict__ x, const int* __restrict__ batch,
    const float* __restrict__ Wa, const float* __restrict__ Q,
    float* __restrict__ h)
{
    __shared__ unsigned short sB[3*64*40];    // 15 KB
    __shared__ unsigned short sU[4][16*104];  // 13 KB
    for (int idx = threadIdx.x; idx < 96*64; idx += 256) {
        int k = idx >> 6, n = idx & 63;
        int kb = k >> 5, q8 = k & 31;
        sB[(kb*64 + n)*40 + q8] = f2bf((k < FA) ? Wa[k*64 + n] : 0.f);
    }
    __syncthreads();

    const int lane = threadIdx.x & 63;
    const int wave = threadIdx.x >> 6;
    const int n16  = lane & 15;
    const int quad = lane >> 4;
    unsigned short* U = sU[wave];

    const int sr = lane >> 2;
    const int sseg = lane & 3;

    const int numTiles = NN >> 4;
    for (int tile = blockIdx.x*4 + wave; tile < numTiles; tile += gridDim.x*4) {
        const int base = tile << 4;
        {
            const float* src = &x[(size_t)(base + sr)*FA];
#pragma unroll
            for (int j = 0; j < 6; ++j) {
                int c0 = sseg*24 + j*4;
                ushort4 o = {0,0,0,0};
                if (c0 + 4 <= FA) {
                    float4 f = *(const float4*)&src[c0];
                    o.x = f2bf(f.x); o.y = f2bf(f.y); o.z = f2bf(f.z); o.w = f2bf(f.w);
                }
                *(ushort4*)&U[sr*104 + c0] = o;
            }
        }
        __builtin_amdgcn_wave_barrier();

        short8 a0 = *(const short8*)&U[n16*104 + 0*32 + quad*8];
        short8 a1 = *(const short8*)&U[n16*104 + 1*32 + quad*8];
        short8 a2 = *(const short8*)&U[n16*104 + 2*32 + quad*8];

        int bnode[4];
#pragma unroll
        for (int r = 0; r < 4; ++r) bnode[r] = batch[base + quad*4 + r];

        f32x4 zero = {0.f, 0.f, 0.f, 0.f};
        f32x4 accv[4];
#pragma unroll
        for (int nt = 0; nt < 4; ++nt) {
            f32x4 acc = zero;
            short8 b0 = *(const short8*)&sB[(0*64 + nt*16 + n16)*40 + quad*8];
            short8 b1 = *(const short8*)&sB[(1*64 + nt*16 + n16)*40 + quad*8];
            short8 b2 = *(const short8*)&sB[(2*64 + nt*16 + n16)*40 + quad*8];
            acc = __builtin_amdgcn_mfma_f32_16x16x32_bf16(a0, b0, acc, 0,0,0);
            acc = __builtin_amdgcn_mfma_f32_16x16x32_bf16(a1, b1, acc, 0,0,0);
            acc = __builtin_amdgcn_mfma_f32_16x16x32_bf16(a2, b2, acc, 0,0,0);
            accv[nt] = acc;
        }
#pragma unroll
        for (int r = 0; r < 4; ++r) {
            float4 qv = *(const float4*)&Q[bnode[r]*64 + n16*4];
            float4 o = make_float4(accv[0][r]+qv.x, accv[1][r]+qv.y, accv[2][r]+qv.z, accv[3][r]+qv.w);
            *(float4*)&h[(size_t)(base + quad*4 + r)*64 + n16*4] = o;
        }
        __builtin_amdgcn_wave_barrier();
    }
}

// ---------- edge embedding via MFMA: SEQUENTIAL read, scatter write via epos ----------
__global__ __launch_bounds__(256) void embed_edge_kernel(
    const float* __restrict__ eattr, const int* __restrict__ epos,
    const float* __restrict__ Wb, const float* __restrict__ bbond,
    unsigned short* __restrict__ ea)
{
    __shared__ unsigned short sB[2*64*40];   // 10 KB
    __shared__ unsigned short sU[4][16*72];  // 9 KB
    for (int idx = threadIdx.x; idx < 64*64; idx += 256) {
        int k = idx >> 6, n = idx & 63;
        int kb = k >> 5, q8 = k & 31;
        sB[(kb*64 + n)*40 + q8] = f2bf((k < FB) ? Wb[k*64 + n] : 0.f);
    }
    for (int idx = threadIdx.x; idx < 4*16*72; idx += 256) ((unsigned short*)sU)[idx] = 0;
    __syncthreads();

    const int lane = threadIdx.x & 63;
    const int wave = threadIdx.x >> 6;
    const int n16  = lane & 15;
    const int quad = lane >> 4;
    unsigned short* U = sU[wave];

    float bbv[4];
#pragma unroll
    for (int nt = 0; nt < 4; ++nt) bbv[nt] = bbond[nt*16 + n16];

    const int numTiles = EE >> 4;
    for (int tile = blockIdx.x*4 + wave; tile < numTiles; tile += gridDim.x*4) {
        const int base = tile << 4;
        const float* src = &eattr[(size_t)base*FB];
#pragma unroll
        for (int j = 0; j < 11; ++j) {
            int idx = lane + 64*j;
            if (idx < 16*FB) {
                int r = idx / FB, c = idx - r*FB;
                U[r*72 + c] = f2bf(src[idx]);
            }
        }
        int ep[4];
#pragma unroll
        for (int r = 0; r < 4; ++r) ep[r] = epos[base + quad*4 + r];
        __builtin_amdgcn_wave_barrier();

        short8 a0 = *(const short8*)&U[n16*72 + 0*32 + quad*8];
        short8 a1 = *(const short8*)&U[n16*72 + 1*32 + quad*8];
        f32x4 zero = {0.f, 0.f, 0.f, 0.f};
        f32x4 accv[4];
#pragma unroll
        for (int nt = 0; nt < 4; ++nt) {
            f32x4 acc = zero;
            short8 b0 = *(const short8*)&sB[(0*64 + nt*16 + n16)*40 + quad*8];
            short8 b1 = *(const short8*)&sB[(1*64 + nt*16 + n16)*40 + quad*8];
            acc = __builtin_amdgcn_mfma_f32_16x16x32_bf16(a0, b0, acc, 0,0,0);
            acc = __builtin_amdgcn_mfma_f32_16x16x32_bf16(a1, b1, acc, 0,0,0);
            accv[nt] = acc;
        }
#pragma unroll
        for (int r = 0; r < 4; ++r) {
            ushort4 o;
            o.x = f2bf(accv[0][r] + bbv[0]);
            o.y = f2bf(accv[1][r] + bbv[1]);
            o.z = f2bf(accv[2][r] + bbv[2]);
            o.w = f2bf(accv[3][r] + bbv[3]);
            *(ushort4*)&ea[(size_t)ep[r]*64 + n16*4] = o;
        }
        __builtin_amdgcn_wave_barrier();
    }
}

// ---------- layer-0 precompute via MFMA ----------
__global__ __launch_bounds__(256) void precompute_kernel(
    const float* __restrict__ h,
    const float* __restrict__ W1, const float* __restrict__ W2, const float* __restrict__ W3,
    const float* __restrict__ b1, const float* __restrict__ b3,
    float* __restrict__ P1, float* __restrict__ P2, float* __restrict__ P3)
{
    __shared__ unsigned short sB[3*2*64*40];     // 30 KB
    __shared__ unsigned short sU[4][16*72];      // 9 KB
    for (int idx = threadIdx.x; idx < 3*64*64; idx += 256) {
        int mat = idx >> 12;
        int rem = idx & 4095;
        int kp = rem >> 6, n = rem & 63;
        int kt = PIINV(kp);
        int kb = kp >> 5, q8 = kp & 31;
        const float* W = (mat==0) ? W1 : (mat==1) ? W2 : W3;
        sB[((mat*2 + kb)*64 + n)*40 + q8] = f2bf(W[kt*64 + n]);
    }
    __syncthreads();

    const int lane = threadIdx.x & 63;
    const int wave = threadIdx.x >> 6;
    const int n16  = lane & 15;
    const int quad = lane >> 4;
    unsigned short* U = sU[wave];

    float b1v[4], b3v[4];
#pragma unroll
    for (int nt = 0; nt < 4; ++nt) { b1v[nt] = b1[nt*16 + n16]; b3v[nt] = b3[nt*16 + n16]; }

    const int sr = lane >> 2;
    const int sseg = lane & 3;

    const int numTiles = NN >> 4;
    for (int tile = blockIdx.x*4 + wave; tile < numTiles; tile += gridDim.x*4) {
        const int base = tile << 4;
        {
            const float* src = &h[(size_t)(base + sr)*64 + sseg*16];
            float4 f0 = *(const float4*)(src);
            float4 f1 = *(const float4*)(src + 4);
            float4 f2 = *(const float4*)(src + 8);
            float4 f3 = *(const float4*)(src + 12);
            unsigned short* dst = &U[sr*72 + sseg*16];
            ushort4 o0 = { f2bf(f0.x), f2bf(f0.y), f2bf(f0.z), f2bf(f0.w) };
            ushort4 o1 = { f2bf(f1.x), f2bf(f1.y), f2bf(f1.z), f2bf(f1.w) };
            ushort4 o2 = { f2bf(f2.x), f2bf(f2.y), f2bf(f2.z), f2bf(f2.w) };
            ushort4 o3 = { f2bf(f3.x), f2bf(f3.y), f2bf(f3.z), f2bf(f3.w) };
            *(ushort4*)(dst + 0)  = o0;
            *(ushort4*)(dst + 4)  = o1;
            *(ushort4*)(dst + 8)  = o2;
            *(ushort4*)(dst + 12) = o3;
        }
        __builtin_amdgcn_wave_barrier();

        short8 a0 = *(const short8*)&U[n16*72 + 0*32 + quad*8];
        short8 a1 = *(const short8*)&U[n16*72 + 1*32 + quad*8];
        f32x4 zero = {0.f, 0.f, 0.f, 0.f};

#pragma unroll
        for (int mat = 0; mat < 3; ++mat) {
            f32x4 acc[4];
#pragma unroll
            for (int nt = 0; nt < 4; ++nt) acc[nt] = zero;
#pragma unroll
            for (int nt = 0; nt < 4; ++nt) {
                short8 b0 = *(const short8*)&sB[((mat*2 + 0)*64 + nt*16 + n16)*40 + quad*8];
                short8 bq = *(const short8*)&sB[((mat*2 + 1)*64 + nt*16 + n16)*40 + quad*8];
                acc[nt] = __builtin_amdgcn_mfma_f32_16x16x32_bf16(a0, b0, acc[nt], 0,0,0);
                acc[nt] = __builtin_amdgcn_mfma_f32_16x16x32_bf16(a1, bq, acc[nt], 0,0,0);
            }
            float* P = (mat==0) ? P1 : (mat==1) ? P2 : P3;
#pragma unroll
            for (int r = 0; r < 4; ++r) {
                float4 o;
                if (mat==0)      o = make_float4(acc[0][r]+b1v[0], acc[1][r]+b1v[1], acc[2][r]+b1v[2], acc[3][r]+b1v[3]);
                else if (mat==2) o = make_float4(acc[0][r]+b3v[0], acc[1][r]+b3v[1], acc[2][r]+b3v[2], acc[3][r]+b3v[3]);
                else             o = make_float4(acc[0][r], acc[1][r], acc[2][r], acc[3][r]);
                *(float4*)&P[(size_t)(base + quad*4 + r)*64 + n16*4] = o;
            }
        }
        __builtin_amdgcn_wave_barrier();
    }
}

// ---------- fused BN+softplus+residual + precompute (layers 1..L-1) ----------
__global__ __launch_bounds__(256) void bnpre_kernel(
    float* __restrict__ h, const float* __restrict__ h_new,
    const float* __restrict__ stats, const float* __restrict__ gamma, const float* __restrict__ beta,
    const float* __restrict__ W1, const float* __restrict__ W2, const float* __restrict__ W3,
    const float* __restrict__ b1, const float* __restrict__ b3,
    float* __restrict__ P1, float* __restrict__ P2, float* __restrict__ P3)
{
    __shared__ unsigned short sB[3*2*64*40];     // 30 KB
    __shared__ unsigned short sU[4][16*72];      // 9 KB
    __shared__ float sMU[64], sISG[64], sBB[64];
    for (int idx = threadIdx.x; idx < 3*64*64; idx += 256) {
        int mat = idx >> 12;
        int rem = idx & 4095;
        int kp = rem >> 6, n = rem & 63;
        int kt = PIINV(kp);
        int kb = kp >> 5, q8 = kp & 31;
        const float* W = (mat==0) ? W1 : (mat==1) ? W2 : W3;
        sB[((mat*2 + kb)*64 + n)*40 + q8] = f2bf(W[kt*64 + n]);
    }
    if (threadIdx.x < 64) {
        int cp = threadIdx.x;
        int ct = PIINV(cp);
        const float invN = 1.0f / (float)NN;
        float mu  = stats[cp] * invN;
        float var = stats[64+cp] * invN - mu*mu;
        float is  = rsqrtf(var + EPSBN);
        sMU[cp]  = mu;
        sISG[cp] = is * gamma[ct];
        sBB[cp]  = beta[ct];
    }
    __syncthreads();

    const int lane = threadIdx.x & 63;
    const int wave = threadIdx.x >> 6;
    const int n16  = lane & 15;
    const int quad = lane >> 4;
    unsigned short* U = sU[wave];

    float b1v[4], b3v[4];
#pragma unroll
    for (int nt = 0; nt < 4; ++nt) { b1v[nt] = b1[nt*16 + n16]; b3v[nt] = b3[nt*16 + n16]; }

    const int sr = lane >> 2;
    const int sseg = lane & 3;
    float mu4[16], isg4[16], bb4[16];
#pragma unroll
    for (int j = 0; j < 16; ++j) {
        int cp = sseg*16 + j;
        mu4[j] = sMU[cp]; isg4[j] = sISG[cp]; bb4[j] = sBB[cp];
    }

    const int numTiles = NN >> 4;
    for (int tile = blockIdx.x*4 + wave; tile < numTiles; tile += gridDim.x*4) {
        const int base = tile << 4;
        {
            float* hrow = &h[(size_t)(base + sr)*64 + sseg*16];
            const float* hnrow = &h_new[(size_t)(base + sr)*64 + sseg*16];
            unsigned short* dst = &U[sr*72 + sseg*16];
#pragma unroll
            for (int q = 0; q < 4; ++q) {
                float4 hn = *(const float4*)(hnrow + q*4);
                float4 ho = *(const float4*)(hrow + q*4);
                float v0 = sp1((hn.x - mu4[q*4+0])*isg4[q*4+0] + bb4[q*4+0]) + ho.x;
                float v1 = sp1((hn.y - mu4[q*4+1])*isg4[q*4+1] + bb4[q*4+1]) + ho.y;
                float v2 = sp1((hn.z - mu4[q*4+2])*isg4[q*4+2] + bb4[q*4+2]) + ho.z;
                float v3 = sp1((hn.w - mu4[q*4+3])*isg4[q*4+3] + bb4[q*4+3]) + ho.w;
                *(float4*)(hrow + q*4) = make_float4(v0, v1, v2, v3);
                ushort4 o = { f2bf(v0), f2bf(v1), f2bf(v2), f2bf(v3) };
                *(ushort4*)(dst + q*4) = o;
            }
        }
        __builtin_amdgcn_wave_barrier();

        short8 a0 = *(const short8*)&U[n16*72 + 0*32 + quad*8];
        short8 a1 = *(const short8*)&U[n16*72 + 1*32 + quad*8];
        f32x4 zero = {0.f, 0.f, 0.f, 0.f};

#pragma unroll
        for (int mat = 0; mat < 3; ++mat) {
            f32x4 acc[4];
#pragma unroll
            for (int nt = 0; nt < 4; ++nt) acc[nt] = zero;
#pragma unroll
            for (int nt = 0; nt < 4; ++nt) {
                short8 b0 = *(const short8*)&sB[((mat*2 + 0)*64 + nt*16 + n16)*40 + quad*8];
                short8 bq = *(const short8*)&sB[((mat*2 + 1)*64 + nt*16 + n16)*40 + quad*8];
                acc[nt] = __builtin_amdgcn_mfma_f32_16x16x32_bf16(a0, b0, acc[nt], 0,0,0);
                acc[nt] = __builtin_amdgcn_mfma_f32_16x16x32_bf16(a1, bq, acc[nt], 0,0,0);
            }
            float* P = (mat==0) ? P1 : (mat==1) ? P2 : P3;
#pragma unroll
            for (int r = 0; r < 4; ++r) {
                float4 o;
                if (mat==0)      o = make_float4(acc[0][r]+b1v[0], acc[1][r]+b1v[1], acc[2][r]+b1v[2], acc[3][r]+b1v[3]);
                else if (mat==2) o = make_float4(acc[0][r]+b3v[0], acc[1][r]+b3v[1], acc[2][r]+b3v[2], acc[3][r]+b3v[3]);
                else             o = make_float4(acc[0][r], acc[1][r], acc[2][r], acc[3][r]);
                *(float4*)&P[(size_t)(base + quad*4 + r)*64 + n16*4] = o;
            }
        }
        __builtin_amdgcn_wave_barrier();
    }
}

// ---------- MFMA fused per-edge kernel over col-sorted edges ----------
__global__ __launch_bounds__(512, 2) void layer_edge_kernel(
    unsigned short* __restrict__ ea,
    const float* __restrict__ P1, const float* __restrict__ P2, const float* __restrict__ P3,
    unsigned short* __restrict__ msg,
    const int* __restrict__ rowp, const int* __restrict__ colp,
    const float* __restrict__ WA, const float* __restrict__ WB,
    const float* __restrict__ WC, const float* __restrict__ WD,
    const float* __restrict__ eb2, const float* __restrict__ nb2)
{
    __shared__ unsigned short sB[20480];          // 40 KB
    __shared__ unsigned short sU[8][16*72];       // 18 KB
    for (int idx = threadIdx.x; idx < 4*64*64; idx += 512) {
        int mat = idx >> 12;
        int rem = idx & 4095;
        int kp = rem >> 6, n = rem & 63;
        int kt = PIINV(kp);
        int kb = kp >> 5, q8 = kp & 31;
        const float* W = (mat==0) ? WA : (mat==1) ? WB : (mat==2) ? WC : WD;
        sB[((mat*2 + kb)*64 + n)*40 + q8] = f2bf(W[kt*64 + n]);
    }
    __syncthreads();

    const int lane = threadIdx.x & 63;
    const int wave = threadIdx.x >> 6;
    const int n16  = lane & 15;
    const int quad = lane >> 4;
    unsigned short* U = sU[wave];

    float eb2v[4], nb2v[4];
#pragma unroll
    for (int nt = 0; nt < 4; ++nt) { eb2v[nt] = eb2[nt*16 + n16]; nb2v[nt] = nb2[nt*16 + n16]; }

    const int sr = lane >> 2;
    const int sseg = lane & 3;

    const int numTiles = EE >> 4;
    for (int tile = blockIdx.x*8 + wave; tile < numTiles; tile += gridDim.x*8) {
        const int base = tile << 4;
        int rid[4], cid[4];
#pragma unroll
        for (int r = 0; r < 4; ++r) {
            rid[r] = rowp[base + quad*4 + r];
            cid[r] = colp[base + quad*4 + r];
        }
        float4 g12v[4];
#pragma unroll
        for (int r = 0; r < 4; ++r) {
            float4 a = *(const float4*)&P1[(size_t)rid[r]*64 + n16*4];
            float4 b = *(const float4*)&P2[(size_t)cid[r]*64 + n16*4];
            g12v[r] = make_float4(a.x+b.x, a.y+b.y, a.z+b.z, a.w+b.w);
        }
        {
            const unsigned short* src = &ea[(size_t)(base + sr)*64 + sseg*16];
            uint4 q0 = *(const uint4*)(src);
            uint4 q1 = *(const uint4*)(src + 8);
            *(uint4*)&U[sr*72 + sseg*16]     = q0;
            *(uint4*)&U[sr*72 + sseg*16 + 8] = q1;
        }
        __builtin_amdgcn_wave_barrier();

        f32x4 zero = {0.f, 0.f, 0.f, 0.f};

#define RUN_MM(MAT, ACC)                                                          \
        {                                                                         \
            short8 a0 = *(const short8*)&U[n16*72 + 0*32 + quad*8];               \
            short8 a1 = *(const short8*)&U[n16*72 + 1*32 + quad*8];               \
            _Pragma("unroll")                                                     \
            for (int nt = 0; nt < 4; ++nt) {                                      \
                short8 b0 = *(const short8*)&sB[(((MAT)*2+0)*64 + nt*16 + n16)*40 + quad*8]; \
                short8 b1 = *(const short8*)&sB[(((MAT)*2+1)*64 + nt*16 + n16)*40 + quad*8]; \
                ACC[nt] = __builtin_amdgcn_mfma_f32_16x16x32_bf16(a0, b0, ACC[nt], 0,0,0);   \
                ACC[nt] = __builtin_amdgcn_mfma_f32_16x16x32_bf16(a1, b1, ACC[nt], 0,0,0);   \
            }                                                                     \
        }

        // ---- phase 1 ----
        f32x4 acc[4];
#pragma unroll
        for (int nt = 0; nt < 4; ++nt) acc[nt] = zero;
        RUN_MM(0, acc);
#pragma unroll
        for (int r = 0; r < 4; ++r) {
            ushort4 o;
            o.x = f2bf(sp1(acc[0][r] + g12v[r].x));
            o.y = f2bf(sp1(acc[1][r] + g12v[r].y));
            o.z = f2bf(sp1(acc[2][r] + g12v[r].z));
            o.w = f2bf(sp1(acc[3][r] + g12v[r].w));
            *(ushort4*)&U[(quad*4 + r)*72 + n16*4] = o;
        }
        __builtin_amdgcn_wave_barrier();

        // ---- phase 2 ----
#pragma unroll
        for (int nt = 0; nt < 4; ++nt) acc[nt] = zero;
        RUN_MM(1, acc);
#pragma unroll
        for (int r = 0; r < 4; ++r) {
            ushort4 o;
            o.x = f2bf(acc[0][r] + eb2v[0]);
            o.y = f2bf(acc[1][r] + eb2v[1]);
            o.z = f2bf(acc[2][r] + eb2v[2]);
            o.w = f2bf(acc[3][r] + eb2v[3]);
            *(ushort4*)&ea[(size_t)(base + quad*4 + r)*64 + n16*4] = o;
            *(ushort4*)&U[(quad*4 + r)*72 + n16*4] = o;
        }
        float4 g3v[4];
#pragma unroll
        for (int r = 0; r < 4; ++r)
            g3v[r] = *(const float4*)&P3[(size_t)rid[r]*64 + n16*4];
        __builtin_amdgcn_wave_barrier();

        // ---- phase 3 ----
#pragma unroll
        for (int nt = 0; nt < 4; ++nt) acc[nt] = zero;
        RUN_MM(2, acc);
#pragma unroll
        for (int r = 0; r < 4; ++r) {
            ushort4 o;
            o.x = f2bf(sp1(acc[0][r] + g3v[r].x));
            o.y = f2bf(sp1(acc[1][r] + g3v[r].y));
            o.z = f2bf(sp1(acc[2][r] + g3v[r].z));
            o.w = f2bf(sp1(acc[3][r] + g3v[r].w));
            *(ushort4*)&U[(quad*4 + r)*72 + n16*4] = o;
        }
        __builtin_amdgcn_wave_barrier();

        // ---- phase 4 ----
#pragma unroll
        for (int nt = 0; nt < 4; ++nt) acc[nt] = zero;
        RUN_MM(3, acc);
#pragma unroll
        for (int r = 0; r < 4; ++r) {
            ushort4 o;
            o.x = f2bf(acc[0][r] + nb2v[0]);
            o.y = f2bf(acc[1][r] + nb2v[1]);
            o.z = f2bf(acc[2][r] + nb2v[2]);
            o.w = f2bf(acc[3][r] + nb2v[3]);
            *(ushort4*)&msg[(size_t)(base + quad*4 + r)*64 + n16*4] = o;
        }
        __builtin_amdgcn_wave_barrier();
#undef RUN_MM
    }
}

// ---------- CSR segment-sum of msg -> h_new (PI cols), fused BN statistics ----------
__global__ __launch_bounds__(256) void reduce_kernel(
    const unsigned short* __restrict__ msg, const int* __restrict__ offi,
    float* __restrict__ h_new, float* __restrict__ stats)
{
    const int t = threadIdx.x;
    const int nl = t >> 4;
    const int n  = blockIdx.x*16 + nl;
    const int c0 = (t & 15)*4;
    float a0=0.f, a1=0.f, a2=0.f, a3=0.f;
    if (n < NN) {
        int s = (n == 0) ? 0 : offi[n-1];
        int e = offi[n];
        for (int p = s; p < e; ++p) {
            uint2 q = *(const uint2*)&msg[(size_t)p*64 + c0];
            a0 += bf2f((unsigned short)(q.x & 0xffff));
            a1 += bf2f((unsigned short)(q.x >> 16));
            a2 += bf2f((unsigned short)(q.y & 0xffff));
            a3 += bf2f((unsigned short)(q.y >> 16));
        }
        *(float4*)&h_new[(size_t)n*64 + c0] = make_float4(a0,a1,a2,a3);
    }
    __shared__ float Ss[16][64];
    __shared__ float Sq[16][64];
    Ss[nl][c0+0]=a0; Ss[nl][c0+1]=a1; Ss[nl][c0+2]=a2; Ss[nl][c0+3]=a3;
    Sq[nl][c0+0]=a0*a0; Sq[nl][c0+1]=a1*a1; Sq[nl][c0+2]=a2*a2; Sq[nl][c0+3]=a3*a3;
    __syncthreads();
    if (t < 64) {
        float s = 0.f, q = 0.f;
#pragma unroll
        for (int r = 0; r < 16; ++r) { s += Ss[r][t]; q += Sq[r][t]; }
        atomAddF(&stats[t], s);
        atomAddF(&stats[64 + t], q);
    }
}

// ---------- fused final BN + softplus + residual + mean pool ----------
// Each wave owns 16 nodes; all loads prefetched (independent); run-accumulate
// over sorted batch; one atomic per run per column.
__global__ __launch_bounds__(256) void bnpool_kernel(
    const float* __restrict__ hn, const float* __restrict__ h,
    const float* __restrict__ stats, const float* __restrict__ gamma, const float* __restrict__ beta,
    const int* __restrict__ batch,
    float* __restrict__ gsum, float* __restrict__ gcnt)
{
    const int col = threadIdx.x & 63, rg = threadIdx.x >> 6;
    int n0 = blockIdx.x*64 + rg*16;
    if (n0 >= NN) return;          // NN % 16 == 0, so full 16-node segments only
    // BN constants for this column (wave-uniform per lane)
    const float invN = 1.0f / (float)NN;
    float mu  = stats[col] * invN;
    float var = stats[64+col] * invN - mu*mu;
    float isg = rsqrtf(var + EPSBN) * gamma[PIINV(col)];
    float bb  = beta[PIINV(col)];
    // prefetch 16 rows (independent loads)
    float vn[16], vh[16];
    int b[16];
#pragma unroll
    for (int j = 0; j < 16; ++j) vn[j] = hn[(size_t)(n0+j)*64 + col];
#pragma unroll
    for (int j = 0; j < 16; ++j) vh[j] = h[(size_t)(n0+j)*64 + col];
#pragma unroll
    for (int j = 0; j < 16; ++j) b[j] = batch[n0+j];
    float v[16];
#pragma unroll
    for (int j = 0; j < 16; ++j) v[j] = sp1((vn[j] - mu)*isg + bb) + vh[j];
    // run-accumulate over sorted batch ids
    float s = v[0]; int cur = b[0]; int c = 1;
#pragma unroll
    for (int j = 1; j < 16; ++j) {
        if (b[j] != cur) {
            atomAddF(&gsum[cur*64 + col], s);
            if (col == 0) atomAddF(&gcnt[cur], (float)c);
            cur = b[j]; s = 0.f; c = 0;
        }
        s += v[j]; ++c;
    }
    atomAddF(&gsum[cur*64 + col], s);
    if (col == 0) atomAddF(&gcnt[cur], (float)c);
}

// ---------- predictor MLP (gsum PI-stored -> remap p_W1 rows) ----------
__global__ __launch_bounds__(128) void predictor_kernel(
    const float* __restrict__ gsum, const float* __restrict__ gcnt,
    const float* __restrict__ W1, const float* __restrict__ b1,
    const float* __restrict__ W2, const float* __restrict__ b2,
    const float* __restrict__ W3, const float* __restrict__ b3,
    float* __restrict__ out)
{
    int g = blockIdx.x, t = threadIdx.x;
    __shared__ float gr[64];
    __shared__ float z1[128];
    __shared__ float z2[128];
    __shared__ float red[128];
    if (t < 64) gr[t] = gsum[g*64 + t] / fmaxf(gcnt[g], 1.0f);
    __syncthreads();
    float s = b1[t];
#pragma unroll
    for (int k = 0; k < 64; ++k) s += gr[k] * W1[PIINV(k)*128 + t];
    z1[t] = sp1(s);
    __syncthreads();
    s = b2[t];
    for (int k = 0; k < 128; ++k) s += z1[k] * W2[k*128 + t];
    z2[t] = sp1(s);
    __syncthreads();
    red[t] = z2[t] * W3[t];
    __syncthreads();
    for (int off = 64; off > 0; off >>= 1) {
        if (t < off) red[t] += red[t + off];
        __syncthreads();
    }
    if (t == 0) out[g] = red[0] + b3[0];
}

// ---------- launch ----------
extern "C" void kernel_launch(void* const* d_in, const int* in_sizes, int n_in,
                              void* d_out, int out_size, void* d_ws, size_t ws_size,
                              hipStream_t stream)
{
    const float* x         = (const float*)d_in[0];
    const float* edge_attr = (const float*)d_in[1];
    const float* charge    = (const float*)d_in[2];
    const int*   edge_index= (const int*)d_in[3];
    const int*   batch     = (const int*)d_in[4];
    const float* W_charge  = (const float*)d_in[5];
    const float* b_charge  = (const float*)d_in[6];
    const float* W_atom    = (const float*)d_in[7];
    const float* b_atom    = (const float*)d_in[8];
    const float* W_bond    = (const float*)d_in[9];
    const float* b_bond    = (const float*)d_in[10];
    const float* nu_W1     = (const float*)d_in[11];
    const float* nu_b1     = (const float*)d_in[12];
    const float* nu_W2     = (const float*)d_in[13];
    const float* nu_b2     = (const float*)d_in[14];
    const float* eu_W1     = (const float*)d_in[15];
    const float* eu_b1     = (const float*)d_in[16];
    const float* eu_W2     = (const float*)d_in[17];
    const float* eu_b2     = (const float*)d_in[18];
    const float* bn_gamma  = (const float*)d_in[19];
    const float* bn_beta   = (const float*)d_in[20];
    const float* p_W1      = (const float*)d_in[21];
    const float* p_b1      = (const float*)d_in[22];
    const float* p_W2      = (const float*)d_in[23];
    const float* p_b2      = (const float*)d_in[24];
    const float* p_W3      = (const float*)d_in[25];
    const float* p_b3      = (const float*)d_in[26];

    const int* rowi = edge_index;
    const int* coli = edge_index + EE;

    char* ws = (char*)d_ws;
    unsigned short* ea  = (unsigned short*)ws;  ws += (size_t)EE*64*2;
    unsigned short* msg = (unsigned short*)ws;  ws += (size_t)EE*64*2;
    float* h     = (float*)ws;                  ws += (size_t)NN*64*4;
    float* P1    = (float*)ws;                  ws += (size_t)NN*64*4;
    float* P2    = (float*)ws;                  ws += (size_t)NN*64*4;
    float* P3    = (float*)ws;                  ws += (size_t)NN*64*4;
    float* h_new = (float*)ws;                  ws += (size_t)NN*64*4;
    float* gsum  = (float*)ws;                  ws += (size_t)GG*64*4;
    float* gcnt  = (float*)ws;                  ws += (size_t)GG*4;
    float* stats = (float*)ws;                  ws += 128*4;
    float* Qtab  = (float*)ws;                  ws += (size_t)GG*64*4;
    int*   cnt   = (int*)ws;                    ws += (size_t)NN*4;
    int*   offi  = (int*)ws;                    ws += (size_t)NN*4;
    int*   epos  = (int*)ws;                    ws += (size_t)EE*4;
    int*   rowp  = (int*)ws;                    ws += (size_t)EE*4;
    int*   colp  = (int*)ws;                    ws += (size_t)EE*4;

    float* out = (float*)d_out;

    hipMemsetAsync(cnt, 0, (size_t)NN*4, stream);
    hist_kernel<<<(EE + 255)/256, 256, 0, stream>>>(coli, cnt);
    scan_kernel<<<1, 1024, 0, stream>>>(cnt, offi);
    scatter_kernel<<<(EE + 255)/256, 256, 0, stream>>>(rowi, coli, offi, epos, rowp, colp);

    qfeat_kernel<<<(GG*64 + 255)/256, 256, 0, stream>>>(charge, W_charge, b_charge, W_atom, b_atom, Qtab);
    embed_node_kernel<<<512, 256, 0, stream>>>(x, batch, W_atom, Qtab, h);
    embed_edge_kernel<<<1024, 256, 0, stream>>>(edge_attr, epos, W_bond, b_bond, ea);
    hipMemsetAsync(gsum, 0, (size_t)(GG*64 + GG)*4, stream);

    for (int l = 0; l < NL; ++l) {
        const float* euW1 = eu_W1 + (size_t)l*192*64;
        const float* nuW1 = nu_W1 + (size_t)l*128*64;
        if (l == 0) {
            precompute_kernel<<<256, 256, 0, stream>>>(
                h, euW1, euW1 + 64*64, nuW1,
                eu_b1 + l*64, nu_b1 + l*64, P1, P2, P3);
        } else {
            bnpre_kernel<<<256, 256, 0, stream>>>(
                h, h_new, stats, bn_gamma + (l-1)*64, bn_beta + (l-1)*64,
                euW1, euW1 + 64*64, nuW1,
                eu_b1 + l*64, nu_b1 + l*64, P1, P2, P3);
        }
        hipMemsetAsync(stats, 0, 128*4, stream);
        layer_edge_kernel<<<512, 512, 0, stream>>>(
            ea, P1, P2, P3, msg, rowp, colp,
            euW1 + 128*64, eu_W2 + (size_t)l*64*64,
            nuW1 + 64*64,  nu_W2 + (size_t)l*64*64,
            eu_b2 + l*64, nu_b2 + l*64);
        reduce_kernel<<<(NN + 15)/16, 256, 0, stream>>>(msg, offi, h_new, stats);
    }

    // fused final BN + residual + mean pool
    bnpool_kernel<<<(NN + 63)/64, 256, 0, stream>>>(
        h_new, h, stats, bn_gamma + (NL-1)*64, bn_beta + (NL-1)*64,
        batch, gsum, gcnt);
    predictor_kernel<<<GG, 128, 0, stream>>>(gsum, gcnt, p_W1, p_b1, p_W2, p_b2, p_W3, p_b3, out);
}

// Round 9
// 845.259 us; speedup vs baseline: 7.9809x; 1.1217x over previous
//
#include <hip/hip_runtime.h>
#include <cmath>

#define NN 50000
#define EE 500000
#define GG 256
#define FA 92
#define FB 41
#define DD 64
#define HH 128
#define CQdim 16
#define NL 3
#define EPSBN 1e-5f

// Global column permutation: activations stored with col' = PI(col).
// PI(c)  = (c&15)*4 + (c>>4)   ; PIINV(c') = (c'&3)*16 + (c'>>2)
#define PIINV(cp) ((((cp) & 3) << 4) | ((cp) >> 2))

typedef __attribute__((ext_vector_type(8))) short short8;
typedef __attribute__((ext_vector_type(4))) float f32x4;

// ---------- helpers ----------
__device__ __forceinline__ float sp1(float x) {
    float e = __expf(-fabsf(x));
    return fmaxf(x, 0.0f) + __logf(1.0f + e);
}
__device__ __forceinline__ void atomAddF(float* p, float v) {
    unsafeAtomicAdd(p, v);
}
__device__ __forceinline__ unsigned short f2bf(float f) {
    unsigned int u = __float_as_uint(f);
    unsigned int r = u + 0x7FFFu + ((u >> 16) & 1u);
    return (unsigned short)(r >> 16);
}
__device__ __forceinline__ float bf2f(unsigned short s) {
    return __uint_as_float(((unsigned int)s) << 16);
}
__device__ __forceinline__ void acc8(float* a, uint4 q) {
    a[0] += bf2f((unsigned short)(q.x & 0xffff)); a[1] += bf2f((unsigned short)(q.x >> 16));
    a[2] += bf2f((unsigned short)(q.y & 0xffff)); a[3] += bf2f((unsigned short)(q.y >> 16));
    a[4] += bf2f((unsigned short)(q.z & 0xffff)); a[5] += bf2f((unsigned short)(q.z >> 16));
    a[6] += bf2f((unsigned short)(q.w & 0xffff)); a[7] += bf2f((unsigned short)(q.w >> 16));
}

// ---------- counting sort of edges by col ----------
__global__ __launch_bounds__(256) void hist_kernel(const int* __restrict__ coli, int* __restrict__ cnt)
{
    int e = blockIdx.x*256 + threadIdx.x;
    if (e < EE) atomicAdd(&cnt[coli[e]], 1);
}

__global__ __launch_bounds__(1024) void scan_kernel(const int* __restrict__ cnt, int* __restrict__ off)
{
    const int CH = (NN + 1023) / 1024;   // 49
    const int t = threadIdx.x;
    int s0 = t*CH, s1 = s0 + CH; if (s1 > NN) s1 = NN; if (s0 > NN) s0 = NN;
    int sum = 0;
    for (int i = s0; i < s1; ++i) sum += cnt[i];
    __shared__ int buf[1024];
    buf[t] = sum;
    __syncthreads();
#pragma unroll
    for (int ofs = 1; ofs < 1024; ofs <<= 1) {
        int v = (t >= ofs) ? buf[t - ofs] : 0;
        __syncthreads();
        buf[t] += v;
        __syncthreads();
    }
    int run = buf[t] - sum;
    for (int i = s0; i < s1; ++i) { int v = cnt[i]; off[i] = run; run += v; }
}

__global__ __launch_bounds__(256) void scatter_kernel(
    const int* __restrict__ rowi, const int* __restrict__ coli, int* __restrict__ off,
    int* __restrict__ epos, int* __restrict__ rowp, int* __restrict__ colp)
{
    int e = blockIdx.x*256 + threadIdx.x;
    if (e >= EE) return;
    int c = coli[e];
    int p = atomicAdd(&off[c], 1);
    epos[e] = p; rowp[p] = rowi[e]; colp[p] = c;
}

// ---------- per-graph charge table (PI-stored) ----------
__global__ __launch_bounds__(256) void qfeat_kernel(
    const float* __restrict__ charge, const float* __restrict__ Wc, const float* __restrict__ bc,
    const float* __restrict__ Wa, const float* __restrict__ ba, float* __restrict__ Q)
{
    int idx = blockIdx.x*256 + threadIdx.x;
    if (idx >= GG*64) return;
    int g = idx >> 6, cp = idx & 63;
    int c = PIINV(cp);
    float ch = charge[g];
    float acc = ba[c];
#pragma unroll
    for (int q = 0; q < CQdim; ++q) {
        float cf = ch*Wc[q] + bc[q];
        acc += cf * Wa[(FA + q)*64 + c];
    }
    Q[idx] = acc;
}

// ---------- node embedding via MFMA: h(PI) = x @ Wa[0:92] + Q[batch] ----------
__global__ __launch_bounds__(256) void embed_node_kernel(
    const float* __restrict__ x, const int* __restrict__ batch,
    const float* __restrict__ Wa, const float* __restrict__ Q,
    float* __restrict__ h)
{
    __shared__ unsigned short sB[3*64*40];    // 15 KB
    __shared__ unsigned short sU[4][16*104];  // 13 KB
    for (int idx = threadIdx.x; idx < 96*64; idx += 256) {
        int k = idx >> 6, n = idx & 63;
        int kb = k >> 5, q8 = k & 31;
        sB[(kb*64 + n)*40 + q8] = f2bf((k < FA) ? Wa[k*64 + n] : 0.f);
    }
    __syncthreads();

    const int lane = threadIdx.x & 63;
    const int wave = threadIdx.x >> 6;
    const int n16  = lane & 15;
    const int quad = lane >> 4;
    unsigned short* U = sU[wave];

    const int sr = lane >> 2;
    const int sseg = lane & 3;

    const int numTiles = NN >> 4;
    for (int tile = blockIdx.x*4 + wave; tile < numTiles; tile += gridDim.x*4) {
        const int base = tile << 4;
        {
            const float* src = &x[(size_t)(base + sr)*FA];
#pragma unroll
            for (int j = 0; j < 6; ++j) {
                int c0 = sseg*24 + j*4;
                ushort4 o = {0,0,0,0};
                if (c0 + 4 <= FA) {
                    float4 f = *(const float4*)&src[c0];
                    o.x = f2bf(f.x); o.y = f2bf(f.y); o.z = f2bf(f.z); o.w = f2bf(f.w);
                }
                *(ushort4*)&U[sr*104 + c0] = o;
            }
        }
        __builtin_amdgcn_wave_barrier();

        short8 a0 = *(const short8*)&U[n16*104 + 0*32 + quad*8];
        short8 a1 = *(const short8*)&U[n16*104 + 1*32 + quad*8];
        short8 a2 = *(const short8*)&U[n16*104 + 2*32 + quad*8];

        int bnode[4];
#pragma unroll
        for (int r = 0; r < 4; ++r) bnode[r] = batch[base + quad*4 + r];

        f32x4 zero = {0.f, 0.f, 0.f, 0.f};
        f32x4 accv[4];
#pragma unroll
        for (int nt = 0; nt < 4; ++nt) {
            f32x4 acc = zero;
            short8 b0 = *(const short8*)&sB[(0*64 + nt*16 + n16)*40 + quad*8];
            short8 b1 = *(const short8*)&sB[(1*64 + nt*16 + n16)*40 + quad*8];
            short8 b2 = *(const short8*)&sB[(2*64 + nt*16 + n16)*40 + quad*8];
            acc = __builtin_amdgcn_mfma_f32_16x16x32_bf16(a0, b0, acc, 0,0,0);
            acc = __builtin_amdgcn_mfma_f32_16x16x32_bf16(a1, b1, acc, 0,0,0);
            acc = __builtin_amdgcn_mfma_f32_16x16x32_bf16(a2, b2, acc, 0,0,0);
            accv[nt] = acc;
        }
#pragma unroll
        for (int r = 0; r < 4; ++r) {
            float4 qv = *(const float4*)&Q[bnode[r]*64 + n16*4];
            float4 o = make_float4(accv[0][r]+qv.x, accv[1][r]+qv.y, accv[2][r]+qv.z, accv[3][r]+qv.w);
            *(float4*)&h[(size_t)(base + quad*4 + r)*64 + n16*4] = o;
        }
        __builtin_amdgcn_wave_barrier();
    }
}

// ---------- edge embedding via MFMA: SEQUENTIAL read, scatter write via epos ----------
__global__ __launch_bounds__(256) void embed_edge_kernel(
    const float* __restrict__ eattr, const int* __restrict__ epos,
    const float* __restrict__ Wb, const float* __restrict__ bbond,
    unsigned short* __restrict__ ea)
{
    __shared__ unsigned short sB[2*64*40];   // 10 KB
    __shared__ unsigned short sU[4][16*72];  // 9 KB
    for (int idx = threadIdx.x; idx < 64*64; idx += 256) {
        int k = idx >> 6, n = idx & 63;
        int kb = k >> 5, q8 = k & 31;
        sB[(kb*64 + n)*40 + q8] = f2bf((k < FB) ? Wb[k*64 + n] : 0.f);
    }
    for (int idx = threadIdx.x; idx < 4*16*72; idx += 256) ((unsigned short*)sU)[idx] = 0;
    __syncthreads();

    const int lane = threadIdx.x & 63;
    const int wave = threadIdx.x >> 6;
    const int n16  = lane & 15;
    const int quad = lane >> 4;
    unsigned short* U = sU[wave];

    float bbv[4];
#pragma unroll
    for (int nt = 0; nt < 4; ++nt) bbv[nt] = bbond[nt*16 + n16];

    const int numTiles = EE >> 4;
    for (int tile = blockIdx.x*4 + wave; tile < numTiles; tile += gridDim.x*4) {
        const int base = tile << 4;
        const float* src = &eattr[(size_t)base*FB];
#pragma unroll
        for (int j = 0; j < 11; ++j) {
            int idx = lane + 64*j;
            if (idx < 16*FB) {
                int r = idx / FB, c = idx - r*FB;
                U[r*72 + c] = f2bf(src[idx]);
            }
        }
        int ep[4];
#pragma unroll
        for (int r = 0; r < 4; ++r) ep[r] = epos[base + quad*4 + r];
        __builtin_amdgcn_wave_barrier();

        short8 a0 = *(const short8*)&U[n16*72 + 0*32 + quad*8];
        short8 a1 = *(const short8*)&U[n16*72 + 1*32 + quad*8];
        f32x4 zero = {0.f, 0.f, 0.f, 0.f};
        f32x4 accv[4];
#pragma unroll
        for (int nt = 0; nt < 4; ++nt) {
            f32x4 acc = zero;
            short8 b0 = *(const short8*)&sB[(0*64 + nt*16 + n16)*40 + quad*8];
            short8 b1 = *(const short8*)&sB[(1*64 + nt*16 + n16)*40 + quad*8];
            acc = __builtin_amdgcn_mfma_f32_16x16x32_bf16(a0, b0, acc, 0,0,0);
            acc = __builtin_amdgcn_mfma_f32_16x16x32_bf16(a1, b1, acc, 0,0,0);
            accv[nt] = acc;
        }
#pragma unroll
        for (int r = 0; r < 4; ++r) {
            ushort4 o;
            o.x = f2bf(accv[0][r] + bbv[0]);
            o.y = f2bf(accv[1][r] + bbv[1]);
            o.z = f2bf(accv[2][r] + bbv[2]);
            o.w = f2bf(accv[3][r] + bbv[3]);
            *(ushort4*)&ea[(size_t)ep[r]*64 + n16*4] = o;
        }
        __builtin_amdgcn_wave_barrier();
    }
}

// ---------- layer-0 precompute via MFMA ----------
__global__ __launch_bounds__(256) void precompute_kernel(
    const float* __restrict__ h,
    const float* __restrict__ W1, const float* __restrict__ W2, const float* __restrict__ W3,
    const float* __restrict__ b1, const float* __restrict__ b3,
    float* __restrict__ P1, float* __restrict__ P2, float* __restrict__ P3)
{
    __shared__ unsigned short sB[3*2*64*40];     // 30 KB
    __shared__ unsigned short sU[4][16*72];      // 9 KB
    for (int idx = threadIdx.x; idx < 3*64*64; idx += 256) {
        int mat = idx >> 12;
        int rem = idx & 4095;
        int kp = rem >> 6, n = rem & 63;
        int kt = PIINV(kp);
        int kb = kp >> 5, q8 = kp & 31;
        const float* W = (mat==0) ? W1 : (mat==1) ? W2 : W3;
        sB[((mat*2 + kb)*64 + n)*40 + q8] = f2bf(W[kt*64 + n]);
    }
    __syncthreads();

    const int lane = threadIdx.x & 63;
    const int wave = threadIdx.x >> 6;
    const int n16  = lane & 15;
    const int quad = lane >> 4;
    unsigned short* U = sU[wave];

    float b1v[4], b3v[4];
#pragma unroll
    for (int nt = 0; nt < 4; ++nt) { b1v[nt] = b1[nt*16 + n16]; b3v[nt] = b3[nt*16 + n16]; }

    const int sr = lane >> 2;
    const int sseg = lane & 3;

    const int numTiles = NN >> 4;
    for (int tile = blockIdx.x*4 + wave; tile < numTiles; tile += gridDim.x*4) {
        const int base = tile << 4;
        {
            const float* src = &h[(size_t)(base + sr)*64 + sseg*16];
            float4 f0 = *(const float4*)(src);
            float4 f1 = *(const float4*)(src + 4);
            float4 f2 = *(const float4*)(src + 8);
            float4 f3 = *(const float4*)(src + 12);
            unsigned short* dst = &U[sr*72 + sseg*16];
            ushort4 o0 = { f2bf(f0.x), f2bf(f0.y), f2bf(f0.z), f2bf(f0.w) };
            ushort4 o1 = { f2bf(f1.x), f2bf(f1.y), f2bf(f1.z), f2bf(f1.w) };
            ushort4 o2 = { f2bf(f2.x), f2bf(f2.y), f2bf(f2.z), f2bf(f2.w) };
            ushort4 o3 = { f2bf(f3.x), f2bf(f3.y), f2bf(f3.z), f2bf(f3.w) };
            *(ushort4*)(dst + 0)  = o0;
            *(ushort4*)(dst + 4)  = o1;
            *(ushort4*)(dst + 8)  = o2;
            *(ushort4*)(dst + 12) = o3;
        }
        __builtin_amdgcn_wave_barrier();

        short8 a0 = *(const short8*)&U[n16*72 + 0*32 + quad*8];
        short8 a1 = *(const short8*)&U[n16*72 + 1*32 + quad*8];
        f32x4 zero = {0.f, 0.f, 0.f, 0.f};

#pragma unroll
        for (int mat = 0; mat < 3; ++mat) {
            f32x4 acc[4];
#pragma unroll
            for (int nt = 0; nt < 4; ++nt) acc[nt] = zero;
#pragma unroll
            for (int nt = 0; nt < 4; ++nt) {
                short8 b0 = *(const short8*)&sB[((mat*2 + 0)*64 + nt*16 + n16)*40 + quad*8];
                short8 bq = *(const short8*)&sB[((mat*2 + 1)*64 + nt*16 + n16)*40 + quad*8];
                acc[nt] = __builtin_amdgcn_mfma_f32_16x16x32_bf16(a0, b0, acc[nt], 0,0,0);
                acc[nt] = __builtin_amdgcn_mfma_f32_16x16x32_bf16(a1, bq, acc[nt], 0,0,0);
            }
            float* P = (mat==0) ? P1 : (mat==1) ? P2 : P3;
#pragma unroll
            for (int r = 0; r < 4; ++r) {
                float4 o;
                if (mat==0)      o = make_float4(acc[0][r]+b1v[0], acc[1][r]+b1v[1], acc[2][r]+b1v[2], acc[3][r]+b1v[3]);
                else if (mat==2) o = make_float4(acc[0][r]+b3v[0], acc[1][r]+b3v[1], acc[2][r]+b3v[2], acc[3][r]+b3v[3]);
                else             o = make_float4(acc[0][r], acc[1][r], acc[2][r], acc[3][r]);
                *(float4*)&P[(size_t)(base + quad*4 + r)*64 + n16*4] = o;
            }
        }
        __builtin_amdgcn_wave_barrier();
    }
}

// ---------- fused BN+softplus+residual + precompute (layers 1..L-1) ----------
__global__ __launch_bounds__(256) void bnpre_kernel(
    float* __restrict__ h, const float* __restrict__ h_new,
    const float* __restrict__ stats, const float* __restrict__ gamma, const float* __restrict__ beta,
    const float* __restrict__ W1, const float* __restrict__ W2, const float* __restrict__ W3,
    const float* __restrict__ b1, const float* __restrict__ b3,
    float* __restrict__ P1, float* __restrict__ P2, float* __restrict__ P3)
{
    __shared__ unsigned short sB[3*2*64*40];     // 30 KB
    __shared__ unsigned short sU[4][16*72];      // 9 KB
    __shared__ float sMU[64], sISG[64], sBB[64];
    for (int idx = threadIdx.x; idx < 3*64*64; idx += 256) {
        int mat = idx >> 12;
        int rem = idx & 4095;
        int kp = rem >> 6, n = rem & 63;
        int kt = PIINV(kp);
        int kb = kp >> 5, q8 = kp & 31;
        const float* W = (mat==0) ? W1 : (mat==1) ? W2 : W3;
        sB[((mat*2 + kb)*64 + n)*40 + q8] = f2bf(W[kt*64 + n]);
    }
    if (threadIdx.x < 64) {
        int cp = threadIdx.x;
        int ct = PIINV(cp);
        const float invN = 1.0f / (float)NN;
        float mu  = stats[cp] * invN;
        float var = stats[64+cp] * invN - mu*mu;
        float is  = rsqrtf(var + EPSBN);
        sMU[cp]  = mu;
        sISG[cp] = is * gamma[ct];
        sBB[cp]  = beta[ct];
    }
    __syncthreads();

    const int lane = threadIdx.x & 63;
    const int wave = threadIdx.x >> 6;
    const int n16  = lane & 15;
    const int quad = lane >> 4;
    unsigned short* U = sU[wave];

    float b1v[4], b3v[4];
#pragma unroll
    for (int nt = 0; nt < 4; ++nt) { b1v[nt] = b1[nt*16 + n16]; b3v[nt] = b3[nt*16 + n16]; }

    const int sr = lane >> 2;
    const int sseg = lane & 3;
    float mu4[16], isg4[16], bb4[16];
#pragma unroll
    for (int j = 0; j < 16; ++j) {
        int cp = sseg*16 + j;
        mu4[j] = sMU[cp]; isg4[j] = sISG[cp]; bb4[j] = sBB[cp];
    }

    const int numTiles = NN >> 4;
    for (int tile = blockIdx.x*4 + wave; tile < numTiles; tile += gridDim.x*4) {
        const int base = tile << 4;
        {
            float* hrow = &h[(size_t)(base + sr)*64 + sseg*16];
            const float* hnrow = &h_new[(size_t)(base + sr)*64 + sseg*16];
            unsigned short* dst = &U[sr*72 + sseg*16];
#pragma unroll
            for (int q = 0; q < 4; ++q) {
                float4 hn = *(const float4*)(hnrow + q*4);
                float4 ho = *(const float4*)(hrow + q*4);
                float v0 = sp1((hn.x - mu4[q*4+0])*isg4[q*4+0] + bb4[q*4+0]) + ho.x;
                float v1 = sp1((hn.y - mu4[q*4+1])*isg4[q*4+1] + bb4[q*4+1]) + ho.y;
                float v2 = sp1((hn.z - mu4[q*4+2])*isg4[q*4+2] + bb4[q*4+2]) + ho.z;
                float v3 = sp1((hn.w - mu4[q*4+3])*isg4[q*4+3] + bb4[q*4+3]) + ho.w;
                *(float4*)(hrow + q*4) = make_float4(v0, v1, v2, v3);
                ushort4 o = { f2bf(v0), f2bf(v1), f2bf(v2), f2bf(v3) };
                *(ushort4*)(dst + q*4) = o;
            }
        }
        __builtin_amdgcn_wave_barrier();

        short8 a0 = *(const short8*)&U[n16*72 + 0*32 + quad*8];
        short8 a1 = *(const short8*)&U[n16*72 + 1*32 + quad*8];
        f32x4 zero = {0.f, 0.f, 0.f, 0.f};

#pragma unroll
        for (int mat = 0; mat < 3; ++mat) {
            f32x4 acc[4];
#pragma unroll
            for (int nt = 0; nt < 4; ++nt) acc[nt] = zero;
#pragma unroll
            for (int nt = 0; nt < 4; ++nt) {
                short8 b0 = *(const short8*)&sB[((mat*2 + 0)*64 + nt*16 + n16)*40 + quad*8];
                short8 bq = *(const short8*)&sB[((mat*2 + 1)*64 + nt*16 + n16)*40 + quad*8];
                acc[nt] = __builtin_amdgcn_mfma_f32_16x16x32_bf16(a0, b0, acc[nt], 0,0,0);
                acc[nt] = __builtin_amdgcn_mfma_f32_16x16x32_bf16(a1, bq, acc[nt], 0,0,0);
            }
            float* P = (mat==0) ? P1 : (mat==1) ? P2 : P3;
#pragma unroll
            for (int r = 0; r < 4; ++r) {
                float4 o;
                if (mat==0)      o = make_float4(acc[0][r]+b1v[0], acc[1][r]+b1v[1], acc[2][r]+b1v[2], acc[3][r]+b1v[3]);
                else if (mat==2) o = make_float4(acc[0][r]+b3v[0], acc[1][r]+b3v[1], acc[2][r]+b3v[2], acc[3][r]+b3v[3]);
                else             o = make_float4(acc[0][r], acc[1][r], acc[2][r], acc[3][r]);
                *(float4*)&P[(size_t)(base + quad*4 + r)*64 + n16*4] = o;
            }
        }
        __builtin_amdgcn_wave_barrier();
    }
}

// ---------- MFMA fused per-edge kernel over col-sorted edges ----------
__global__ __launch_bounds__(512, 2) void layer_edge_kernel(
    unsigned short* __restrict__ ea,
    const float* __restrict__ P1, const float* __restrict__ P2, const float* __restrict__ P3,
    unsigned short* __restrict__ msg,
    const int* __restrict__ rowp, const int* __restrict__ colp,
    const float* __restrict__ WA, const float* __restrict__ WB,
    const float* __restrict__ WC, const float* __restrict__ WD,
    const float* __restrict__ eb2, const float* __restrict__ nb2)
{
    __shared__ unsigned short sB[20480];          // 40 KB
    __shared__ unsigned short sU[8][16*72];       // 18 KB
    for (int idx = threadIdx.x; idx < 4*64*64; idx += 512) {
        int mat = idx >> 12;
        int rem = idx & 4095;
        int kp = rem >> 6, n = rem & 63;
        int kt = PIINV(kp);
        int kb = kp >> 5, q8 = kp & 31;
        const float* W = (mat==0) ? WA : (mat==1) ? WB : (mat==2) ? WC : WD;
        sB[((mat*2 + kb)*64 + n)*40 + q8] = f2bf(W[kt*64 + n]);
    }
    __syncthreads();

    const int lane = threadIdx.x & 63;
    const int wave = threadIdx.x >> 6;
    const int n16  = lane & 15;
    const int quad = lane >> 4;
    unsigned short* U = sU[wave];

    float eb2v[4], nb2v[4];
#pragma unroll
    for (int nt = 0; nt < 4; ++nt) { eb2v[nt] = eb2[nt*16 + n16]; nb2v[nt] = nb2[nt*16 + n16]; }

    const int sr = lane >> 2;
    const int sseg = lane & 3;

    const int numTiles = EE >> 4;
    for (int tile = blockIdx.x*8 + wave; tile < numTiles; tile += gridDim.x*8) {
        const int base = tile << 4;
        int rid[4], cid[4];
#pragma unroll
        for (int r = 0; r < 4; ++r) {
            rid[r] = rowp[base + quad*4 + r];
            cid[r] = colp[base + quad*4 + r];
        }
        float4 g12v[4];
#pragma unroll
        for (int r = 0; r < 4; ++r) {
            float4 a = *(const float4*)&P1[(size_t)rid[r]*64 + n16*4];
            float4 b = *(const float4*)&P2[(size_t)cid[r]*64 + n16*4];
            g12v[r] = make_float4(a.x+b.x, a.y+b.y, a.z+b.z, a.w+b.w);
        }
        {
            const unsigned short* src = &ea[(size_t)(base + sr)*64 + sseg*16];
            uint4 q0 = *(const uint4*)(src);
            uint4 q1 = *(const uint4*)(src + 8);
            *(uint4*)&U[sr*72 + sseg*16]     = q0;
            *(uint4*)&U[sr*72 + sseg*16 + 8] = q1;
        }
        __builtin_amdgcn_wave_barrier();

        f32x4 zero = {0.f, 0.f, 0.f, 0.f};

#define RUN_MM(MAT, ACC)                                                          \
        {                                                                         \
            short8 a0 = *(const short8*)&U[n16*72 + 0*32 + quad*8];               \
            short8 a1 = *(const short8*)&U[n16*72 + 1*32 + quad*8];               \
            _Pragma("unroll")                                                     \
            for (int nt = 0; nt < 4; ++nt) {                                      \
                short8 b0 = *(const short8*)&sB[(((MAT)*2+0)*64 + nt*16 + n16)*40 + quad*8]; \
                short8 b1 = *(const short8*)&sB[(((MAT)*2+1)*64 + nt*16 + n16)*40 + quad*8]; \
                ACC[nt] = __builtin_amdgcn_mfma_f32_16x16x32_bf16(a0, b0, ACC[nt], 0,0,0);   \
                ACC[nt] = __builtin_amdgcn_mfma_f32_16x16x32_bf16(a1, b1, ACC[nt], 0,0,0);   \
            }                                                                     \
        }

        // ---- phase 1 ----
        f32x4 acc[4];
#pragma unroll
        for (int nt = 0; nt < 4; ++nt) acc[nt] = zero;
        RUN_MM(0, acc);
#pragma unroll
        for (int r = 0; r < 4; ++r) {
            ushort4 o;
            o.x = f2bf(sp1(acc[0][r] + g12v[r].x));
            o.y = f2bf(sp1(acc[1][r] + g12v[r].y));
            o.z = f2bf(sp1(acc[2][r] + g12v[r].z));
            o.w = f2bf(sp1(acc[3][r] + g12v[r].w));
            *(ushort4*)&U[(quad*4 + r)*72 + n16*4] = o;
        }
        __builtin_amdgcn_wave_barrier();

        // ---- phase 2 ----
#pragma unroll
        for (int nt = 0; nt < 4; ++nt) acc[nt] = zero;
        RUN_MM(1, acc);
#pragma unroll
        for (int r = 0; r < 4; ++r) {
            ushort4 o;
            o.x = f2bf(acc[0][r] + eb2v[0]);
            o.y = f2bf(acc[1][r] + eb2v[1]);
            o.z = f2bf(acc[2][r] + eb2v[2]);
            o.w = f2bf(acc[3][r] + eb2v[3]);
            *(ushort4*)&ea[(size_t)(base + quad*4 + r)*64 + n16*4] = o;
            *(ushort4*)&U[(quad*4 + r)*72 + n16*4] = o;
        }
        float4 g3v[4];
#pragma unroll
        for (int r = 0; r < 4; ++r)
            g3v[r] = *(const float4*)&P3[(size_t)rid[r]*64 + n16*4];
        __builtin_amdgcn_wave_barrier();

        // ---- phase 3 ----
#pragma unroll
        for (int nt = 0; nt < 4; ++nt) acc[nt] = zero;
        RUN_MM(2, acc);
#pragma unroll
        for (int r = 0; r < 4; ++r) {
            ushort4 o;
            o.x = f2bf(sp1(acc[0][r] + g3v[r].x));
            o.y = f2bf(sp1(acc[1][r] + g3v[r].y));
            o.z = f2bf(sp1(acc[2][r] + g3v[r].z));
            o.w = f2bf(sp1(acc[3][r] + g3v[r].w));
            *(ushort4*)&U[(quad*4 + r)*72 + n16*4] = o;
        }
        __builtin_amdgcn_wave_barrier();

        // ---- phase 4 ----
#pragma unroll
        for (int nt = 0; nt < 4; ++nt) acc[nt] = zero;
        RUN_MM(3, acc);
#pragma unroll
        for (int r = 0; r < 4; ++r) {
            ushort4 o;
            o.x = f2bf(acc[0][r] + nb2v[0]);
            o.y = f2bf(acc[1][r] + nb2v[1]);
            o.z = f2bf(acc[2][r] + nb2v[2]);
            o.w = f2bf(acc[3][r] + nb2v[3]);
            *(ushort4*)&msg[(size_t)(base + quad*4 + r)*64 + n16*4] = o;
        }
        __builtin_amdgcn_wave_barrier();
#undef RUN_MM
    }
}

// ---------- CSR segment-sum of msg -> h_new (PI cols), fused BN statistics ----------
// 32 nodes/block, 8 lanes per node (uint4 = 8 cols each), 4-way edge unroll for MLP.
__global__ __launch_bounds__(256) void reduce_kernel(
    const unsigned short* __restrict__ msg, const int* __restrict__ offi,
    float* __restrict__ h_new, float* __restrict__ stats)
{
    const int t = threadIdx.x;
    const int nl = t >> 3;               // node within block 0..31
    const int n  = blockIdx.x*32 + nl;
    const int c0 = (t & 7)*8;            // 8 columns per lane
    float a[8] = {0.f,0.f,0.f,0.f,0.f,0.f,0.f,0.f};
    if (n < NN) {
        int s = (n == 0) ? 0 : offi[n-1];
        int e = offi[n];
        int p = s;
        for (; p + 4 <= e; p += 4) {
            uint4 q0 = *(const uint4*)&msg[(size_t)(p+0)*64 + c0];
            uint4 q1 = *(const uint4*)&msg[(size_t)(p+1)*64 + c0];
            uint4 q2 = *(const uint4*)&msg[(size_t)(p+2)*64 + c0];
            uint4 q3 = *(const uint4*)&msg[(size_t)(p+3)*64 + c0];
            acc8(a, q0); acc8(a, q1); acc8(a, q2); acc8(a, q3);
        }
        for (; p < e; ++p) {
            uint4 q = *(const uint4*)&msg[(size_t)p*64 + c0];
            acc8(a, q);
        }
        *(float4*)&h_new[(size_t)n*64 + c0]     = make_float4(a[0],a[1],a[2],a[3]);
        *(float4*)&h_new[(size_t)n*64 + c0 + 4] = make_float4(a[4],a[5],a[6],a[7]);
    }
    __shared__ float Ss[32][64];
    __shared__ float Sq[32][64];
#pragma unroll
    for (int j = 0; j < 8; ++j) { Ss[nl][c0+j] = a[j]; Sq[nl][c0+j] = a[j]*a[j]; }
    __syncthreads();
    if (t < 64) {
        float s = 0.f, q = 0.f;
#pragma unroll
        for (int r = 0; r < 32; ++r) { s += Ss[r][t]; q += Sq[r][t]; }
        atomAddF(&stats[t], s);
        atomAddF(&stats[64 + t], q);
    }
}

// ---------- fused final BN + softplus + residual + mean pool ----------
__global__ __launch_bounds__(256) void bnpool_kernel(
    const float* __restrict__ hn, const float* __restrict__ h,
    const float* __restrict__ stats, const float* __restrict__ gamma, const float* __restrict__ beta,
    const int* __restrict__ batch,
    float* __restrict__ gsum, float* __restrict__ gcnt)
{
    const int col = threadIdx.x & 63, rg = threadIdx.x >> 6;
    int n0 = blockIdx.x*64 + rg*16;
    if (n0 >= NN) return;
    const float invN = 1.0f / (float)NN;
    float mu  = stats[col] * invN;
    float var = stats[64+col] * invN - mu*mu;
    float isg = rsqrtf(var + EPSBN) * gamma[PIINV(col)];
    float bb  = beta[PIINV(col)];
    float vn[16], vh[16];
    int b[16];
#pragma unroll
    for (int j = 0; j < 16; ++j) vn[j] = hn[(size_t)(n0+j)*64 + col];
#pragma unroll
    for (int j = 0; j < 16; ++j) vh[j] = h[(size_t)(n0+j)*64 + col];
#pragma unroll
    for (int j = 0; j < 16; ++j) b[j] = batch[n0+j];
    float v[16];
#pragma unroll
    for (int j = 0; j < 16; ++j) v[j] = sp1((vn[j] - mu)*isg + bb) + vh[j];
    float s = v[0]; int cur = b[0]; int c = 1;
#pragma unroll
    for (int j = 1; j < 16; ++j) {
        if (b[j] != cur) {
            atomAddF(&gsum[cur*64 + col], s);
            if (col == 0) atomAddF(&gcnt[cur], (float)c);
            cur = b[j]; s = 0.f; c = 0;
        }
        s += v[j]; ++c;
    }
    atomAddF(&gsum[cur*64 + col], s);
    if (col == 0) atomAddF(&gcnt[cur], (float)c);
}

// ---------- predictor MLP (gsum PI-stored -> remap p_W1 rows) ----------
__global__ __launch_bounds__(128) void predictor_kernel(
    const float* __restrict__ gsum, const float* __restrict__ gcnt,
    const float* __restrict__ W1, const float* __restrict__ b1,
    const float* __restrict__ W2, const float* __restrict__ b2,
    const float* __restrict__ W3, const float* __restrict__ b3,
    float* __restrict__ out)
{
    int g = blockIdx.x, t = threadIdx.x;
    __shared__ float gr[64];
    __shared__ float z1[128];
    __shared__ float z2[128];
    __shared__ float red[128];
    if (t < 64) gr[t] = gsum[g*64 + t] / fmaxf(gcnt[g], 1.0f);
    __syncthreads();
    float s = b1[t];
#pragma unroll
    for (int k = 0; k < 64; ++k) s += gr[k] * W1[PIINV(k)*128 + t];
    z1[t] = sp1(s);
    __syncthreads();
    s = b2[t];
    for (int k = 0; k < 128; ++k) s += z1[k] * W2[k*128 + t];
    z2[t] = sp1(s);
    __syncthreads();
    red[t] = z2[t] * W3[t];
    __syncthreads();
    for (int off = 64; off > 0; off >>= 1) {
        if (t < off) red[t] += red[t + off];
        __syncthreads();
    }
    if (t == 0) out[g] = red[0] + b3[0];
}

// ---------- launch ----------
extern "C" void kernel_launch(void* const* d_in, const int* in_sizes, int n_in,
                              void* d_out, int out_size, void* d_ws, size_t ws_size,
                              hipStream_t stream)
{
    const float* x         = (const float*)d_in[0];
    const float* edge_attr = (const float*)d_in[1];
    const float* charge    = (const float*)d_in[2];
    const int*   edge_index= (const int*)d_in[3];
    const int*   batch     = (const int*)d_in[4];
    const float* W_charge  = (const float*)d_in[5];
    const float* b_charge  = (const float*)d_in[6];
    const float* W_atom    = (const float*)d_in[7];
    const float* b_atom    = (const float*)d_in[8];
    const float* W_bond    = (const float*)d_in[9];
    const float* b_bond    = (const float*)d_in[10];
    const float* nu_W1     = (const float*)d_in[11];
    const float* nu_b1     = (const float*)d_in[12];
    const float* nu_W2     = (const float*)d_in[13];
    const float* nu_b2     = (const float*)d_in[14];
    const float* eu_W1     = (const float*)d_in[15];
    const float* eu_b1     = (const float*)d_in[16];
    const float* eu_W2     = (const float*)d_in[17];
    const float* eu_b2     = (const float*)d_in[18];
    const float* bn_gamma  = (const float*)d_in[19];
    const float* bn_beta   = (const float*)d_in[20];
    const float* p_W1      = (const float*)d_in[21];
    const float* p_b1      = (const float*)d_in[22];
    const float* p_W2      = (const float*)d_in[23];
    const float* p_b2      = (const float*)d_in[24];
    const float* p_W3      = (const float*)d_in[25];
    const float* p_b3      = (const float*)d_in[26];

    const int* rowi = edge_index;
    const int* coli = edge_index + EE;

    char* ws = (char*)d_ws;
    unsigned short* ea  = (unsigned short*)ws;  ws += (size_t)EE*64*2;
    unsigned short* msg = (unsigned short*)ws;  ws += (size_t)EE*64*2;
    float* h     = (float*)ws;                  ws += (size_t)NN*64*4;
    float* P1    = (float*)ws;                  ws += (size_t)NN*64*4;
    float* P2    = (float*)ws;                  ws += (size_t)NN*64*4;
    float* P3    = (float*)ws;                  ws += (size_t)NN*64*4;
    float* h_new = (float*)ws;                  ws += (size_t)NN*64*4;
    float* gsum  = (float*)ws;                  ws += (size_t)GG*64*4;
    float* gcnt  = (float*)ws;                  ws += (size_t)GG*4;
    float* stats = (float*)ws;                  ws += 128*4;
    float* Qtab  = (float*)ws;                  ws += (size_t)GG*64*4;
    int*   cnt   = (int*)ws;                    ws += (size_t)NN*4;
    int*   offi  = (int*)ws;                    ws += (size_t)NN*4;
    int*   epos  = (int*)ws;                    ws += (size_t)EE*4;
    int*   rowp  = (int*)ws;                    ws += (size_t)EE*4;
    int*   colp  = (int*)ws;                    ws += (size_t)EE*4;

    float* out = (float*)d_out;

    hipMemsetAsync(cnt, 0, (size_t)NN*4, stream);
    hist_kernel<<<(EE + 255)/256, 256, 0, stream>>>(coli, cnt);
    scan_kernel<<<1, 1024, 0, stream>>>(cnt, offi);
    scatter_kernel<<<(EE + 255)/256, 256, 0, stream>>>(rowi, coli, offi, epos, rowp, colp);

    qfeat_kernel<<<(GG*64 + 255)/256, 256, 0, stream>>>(charge, W_charge, b_charge, W_atom, b_atom, Qtab);
    embed_node_kernel<<<512, 256, 0, stream>>>(x, batch, W_atom, Qtab, h);
    embed_edge_kernel<<<1024, 256, 0, stream>>>(edge_attr, epos, W_bond, b_bond, ea);
    hipMemsetAsync(gsum, 0, (size_t)(GG*64 + GG)*4, stream);

    for (int l = 0; l < NL; ++l) {
        const float* euW1 = eu_W1 + (size_t)l*192*64;
        const float* nuW1 = nu_W1 + (size_t)l*128*64;
        if (l == 0) {
            precompute_kernel<<<256, 256, 0, stream>>>(
                h, euW1, euW1 + 64*64, nuW1,
                eu_b1 + l*64, nu_b1 + l*64, P1, P2, P3);
        } else {
            bnpre_kernel<<<256, 256, 0, stream>>>(
                h, h_new, stats, bn_gamma + (l-1)*64, bn_beta + (l-1)*64,
                euW1, euW1 + 64*64, nuW1,
                eu_b1 + l*64, nu_b1 + l*64, P1, P2, P3);
        }
        hipMemsetAsync(stats, 0, 128*4, stream);
        layer_edge_kernel<<<512, 512, 0, stream>>>(
            ea, P1, P2, P3, msg, rowp, colp,
            euW1 + 128*64, eu_W2 + (size_t)l*64*64,
            nuW1 + 64*64,  nu_W2 + (size_t)l*64*64,
            eu_b2 + l*64, nu_b2 + l*64);
        reduce_kernel<<<(NN + 31)/32, 256, 0, stream>>>(msg, offi, h_new, stats);
    }

    // fused final BN + residual + mean pool
    bnpool_kernel<<<(NN + 63)/64, 256, 0, stream>>>(
        h_new, h, stats, bn_gamma + (NL-1)*64, bn_beta + (NL-1)*64,
        batch, gsum, gcnt);
    predictor_kernel<<<GG, 128, 0, stream>>>(gsum, gcnt, p_W1, p_b1, p_W2, p_b2, p_W3, p_b3, out);
}